// Round 1
// baseline (4520.751 us; speedup 1.0000x reference)
//
#include <hip/hip_runtime.h>
#include <math.h>

#define TT   1024
#define HH   4096
#define NHH  32
#define DNN  128
#define DRR  64
#define DVV  128
#define QLL  1536
#define KLL  512
#define INHH 32
#define IHDD 128
#define TOPKK 512

static __device__ __constant__ float kScaling = 0.07216878364870322f;  // (DN+DR)^-0.5
static __device__ __constant__ float kWtsScale = 0.015625f;            // IHD^-.5 * INH^-.5 = 1/64

// ---------------- fp32 GEMM: C[M,N] = A[M,K] @ B[K,N] ----------------
// BM=64, BN=128, BK=8, 256 threads, 4x8 micro-tile. K must be %8, N %4.
__global__ __launch_bounds__(256) void gemm_f32(const float* __restrict__ A,
                                                const float* __restrict__ B,
                                                float* __restrict__ C,
                                                int M, int N, int K) {
  __shared__ float As[8][64];
  __shared__ float Bs[8][128];
  const int tid = threadIdx.x;
  const int tx = tid & 15, ty = tid >> 4;
  const int bm = blockIdx.y * 64, bn = blockIdx.x * 128;
  float acc[4][8];
#pragma unroll
  for (int i = 0; i < 4; ++i)
#pragma unroll
    for (int j = 0; j < 8; ++j) acc[i][j] = 0.f;

  const int am = tid >> 1;         // 0..127 (threads <128 stage A)
  const int aj = (tid & 1) * 4;
  const int bk = tid >> 5;         // 0..7
  const int bnn = (tid & 31) * 4;

  for (int k0 = 0; k0 < K; k0 += 8) {
    if (tid < 128) {
      int gm = bm + am;
      float4 av = make_float4(0.f, 0.f, 0.f, 0.f);
      if (gm < M) av = *(const float4*)(A + (size_t)gm * K + k0 + aj);
      As[aj + 0][am] = av.x; As[aj + 1][am] = av.y;
      As[aj + 2][am] = av.z; As[aj + 3][am] = av.w;
    }
    {
      int gn = bn + bnn;
      const float* brow = B + (size_t)(k0 + bk) * N;
      float4 bv = make_float4(0.f, 0.f, 0.f, 0.f);
      if (gn + 3 < N) bv = *(const float4*)(brow + gn);
      else {
        if (gn + 0 < N) bv.x = brow[gn + 0];
        if (gn + 1 < N) bv.y = brow[gn + 1];
        if (gn + 2 < N) bv.z = brow[gn + 2];
      }
      *(float4*)&Bs[bk][bnn] = bv;
    }
    __syncthreads();
#pragma unroll
    for (int p = 0; p < 8; ++p) {
      float4 a4 = *(const float4*)&As[p][ty * 4];
      float4 b0 = *(const float4*)&Bs[p][tx * 8];
      float4 b1 = *(const float4*)&Bs[p][tx * 8 + 4];
      float av[4] = {a4.x, a4.y, a4.z, a4.w};
      float bb[8] = {b0.x, b0.y, b0.z, b0.w, b1.x, b1.y, b1.z, b1.w};
#pragma unroll
      for (int i = 0; i < 4; ++i)
#pragma unroll
        for (int j = 0; j < 8; ++j) acc[i][j] = fmaf(av[i], bb[j], acc[i][j]);
    }
    __syncthreads();
  }
#pragma unroll
  for (int i = 0; i < 4; ++i) {
    int gm = bm + ty * 4 + i;
    if (gm >= M) continue;
    float* crow = C + (size_t)gm * N;
    int gn = bn + tx * 8;
    if (gn + 7 < N) {
      *(float4*)(crow + gn)     = make_float4(acc[i][0], acc[i][1], acc[i][2], acc[i][3]);
      *(float4*)(crow + gn + 4) = make_float4(acc[i][4], acc[i][5], acc[i][6], acc[i][7]);
    } else {
#pragma unroll
      for (int j = 0; j < 8; ++j) if (gn + j < N) crow[gn + j] = acc[i][j];
    }
  }
}

// ---------------- RMSNorm: out = x * rsqrt(mean(x^2)+eps) * w ----------------
__global__ __launch_bounds__(256) void rms_kernel(const float* __restrict__ in, int in_stride,
                                                  const float* __restrict__ w,
                                                  float* __restrict__ out, int out_stride, int C) {
  const int t = blockIdx.x, tid = threadIdx.x;
  const float* x = in + (size_t)t * in_stride;
  float ss = 0.f;
  for (int i = tid; i < C; i += 256) { float v = x[i]; ss = fmaf(v, v, ss); }
#pragma unroll
  for (int o = 32; o > 0; o >>= 1) ss += __shfl_xor(ss, o);
  __shared__ float red[4];
  if ((tid & 63) == 0) red[tid >> 6] = ss;
  __syncthreads();
  const float tot = red[0] + red[1] + red[2] + red[3];
  const float r = rsqrtf(tot / (float)C + 1e-6f);
  for (int i = tid; i < C; i += 256) out[(size_t)t * out_stride + i] = x[i] * r * w[i];
}

// ---------------- LayerNorm in-place on (T,128) ----------------
__global__ __launch_bounds__(128) void ln_kernel(float* __restrict__ x,
                                                 const float* __restrict__ w,
                                                 const float* __restrict__ b) {
  const int t = blockIdx.x, i = threadIdx.x;  // 128 threads
  float v = x[(size_t)t * 128 + i];
  float s = v;
#pragma unroll
  for (int o = 32; o > 0; o >>= 1) s += __shfl_xor(s, o);
  __shared__ float r1[2], r2[2];
  if ((i & 63) == 0) r1[i >> 6] = s;
  __syncthreads();
  const float m = (r1[0] + r1[1]) * (1.f / 128.f);
  const float dv = v - m;
  float sq = dv * dv;
#pragma unroll
  for (int o = 32; o > 0; o >>= 1) sq += __shfl_xor(sq, o);
  if ((i & 63) == 0) r2[i >> 6] = sq;
  __syncthreads();
  const float var = (r2[0] + r2[1]) * (1.f / 128.f);
  x[(size_t)t * 128 + i] = dv * rsqrtf(var + 1e-6f) * w[i] + b[i];
}

// ---------------- RoPE (interleaved pairs), 32 pairs per (t,h) ----------------
__global__ void rope_kernel(const float* __restrict__ src, int s_ts, int s_hs,
                            float* __restrict__ dst, int d_ts, int d_hs,
                            const int* __restrict__ pos) {
  const int t = blockIdx.x, h = blockIdx.y, i = threadIdx.x;  // 32 threads
  const float* s = src + (size_t)t * s_ts + (size_t)h * s_hs;
  float* d = dst + (size_t)t * d_ts + (size_t)h * d_hs;
  const float x1 = s[2 * i], x2 = s[2 * i + 1];
  const float inv = powf(10000.f, -(float)i * (1.f / 32.f));
  const float ang = (float)pos[t] * inv;
  float sn, cs;
  sincosf(ang, &sn, &cs);
  d[2 * i]     = x1 * cs - x2 * sn;
  d[2 * i + 1] = x1 * sn + x2 * cs;
}

// ---------------- Indexer logits (per head-group partial) ----------------
// part[g][q][k] = sum_{h in group g} wts[q,h]/64 * relu(qi[q,h,:] . ki[k,:])
__global__ __launch_bounds__(256) void logits_kernel(const float* __restrict__ qi,
                                                     const float* __restrict__ ki,
                                                     const float* __restrict__ wts,
                                                     float* __restrict__ part) {
  const int bk = blockIdx.x, bq = blockIdx.y, g = blockIdx.z;
  if (bk > bq) return;  // fully non-causal tile
  __shared__ float Qs[16][64];
  __shared__ float Ks[16][64];
  const int tid = threadIdx.x;
  const int tx = tid & 15, ty = tid >> 4;
  const int srow = tid >> 2;        // 0..63
  const int sj = (tid & 3) * 4;     // 0,4,8,12
  float lacc[4][4];
#pragma unroll
  for (int i = 0; i < 4; ++i)
#pragma unroll
    for (int j = 0; j < 4; ++j) lacc[i][j] = 0.f;

  for (int h = g * 8; h < g * 8 + 8; ++h) {
    float hacc[4][4];
#pragma unroll
    for (int i = 0; i < 4; ++i)
#pragma unroll
      for (int j = 0; j < 4; ++j) hacc[i][j] = 0.f;
    for (int kc = 0; kc < 128; kc += 16) {
      float4 qv = *(const float4*)(qi + ((size_t)(bq * 64 + srow) * 32 + h) * 128 + kc + sj);
      float4 kv4 = *(const float4*)(ki + (size_t)(bk * 64 + srow) * 128 + kc + sj);
      __syncthreads();  // previous iteration's reads done before overwrite
      Qs[sj + 0][srow] = qv.x;  Qs[sj + 1][srow] = qv.y;
      Qs[sj + 2][srow] = qv.z;  Qs[sj + 3][srow] = qv.w;
      Ks[sj + 0][srow] = kv4.x; Ks[sj + 1][srow] = kv4.y;
      Ks[sj + 2][srow] = kv4.z; Ks[sj + 3][srow] = kv4.w;
      __syncthreads();
#pragma unroll
      for (int p = 0; p < 16; ++p) {
        float4 a4 = *(const float4*)&Qs[p][ty * 4];
        float4 b4 = *(const float4*)&Ks[p][tx * 4];
        float av[4] = {a4.x, a4.y, a4.z, a4.w};
        float bv[4] = {b4.x, b4.y, b4.z, b4.w};
#pragma unroll
        for (int i = 0; i < 4; ++i)
#pragma unroll
          for (int j = 0; j < 4; ++j) hacc[i][j] = fmaf(av[i], bv[j], hacc[i][j]);
      }
    }
#pragma unroll
    for (int i = 0; i < 4; ++i) {
      const float w = wts[(size_t)(bq * 64 + ty * 4 + i) * 32 + h] * kWtsScale;
#pragma unroll
      for (int j = 0; j < 4; ++j) lacc[i][j] = fmaf(w, fmaxf(hacc[i][j], 0.f), lacc[i][j]);
    }
  }
#pragma unroll
  for (int i = 0; i < 4; ++i)
#pragma unroll
    for (int j = 0; j < 4; ++j)
      part[(size_t)g * TT * TT + (size_t)(bq * 64 + ty * 4 + i) * TT + (bk * 64 + tx * 4 + j)] =
          lacc[i][j];
}

// ---------------- sum 4 head-group partials ----------------
__global__ __launch_bounds__(256) void reduce4(float* __restrict__ dst, const float* __restrict__ part) {
  const size_t i = ((size_t)blockIdx.x * 256 + threadIdx.x) * 4;
  const size_t N = (size_t)TT * TT;
  float4 a = *(const float4*)(part + i);
  float4 b = *(const float4*)(part + N + i);
  float4 c = *(const float4*)(part + 2 * N + i);
  float4 d = *(const float4*)(part + 3 * N + i);
  *(float4*)(dst + i) =
      make_float4(a.x + b.x + c.x + d.x, a.y + b.y + c.y + d.y,
                  a.z + b.z + c.z + d.z, a.w + b.w + c.w + d.w);
}

// ---------------- exact causal top-512 per row (stable ties, low index first) --------
__global__ __launch_bounds__(256) void topk_kernel(const float* __restrict__ lg,
                                                   int* __restrict__ selidx,
                                                   int* __restrict__ selcnt) {
  const int q = blockIdx.x;
  const int tid = threadIdx.x;
  __shared__ unsigned int u[TT];
  __shared__ int redi[4];
  for (int k = tid; k < TT; k += 256) {
    unsigned int uv = 0u;
    if (k <= q) {
      unsigned int bb = __float_as_uint(lg[(size_t)q * TT + k]);
      uv = (bb & 0x80000000u) ? ~bb : (bb | 0x80000000u);  // order-preserving key, >0 for finite
    }
    u[k] = uv;
  }
  __syncthreads();
  const int n = q + 1;
  if (n <= TOPKK) {
    for (int k = tid; k < n; k += 256) selidx[(size_t)q * TOPKK + k] = k;
    if (tid == 0) selcnt[q] = n;
    return;
  }
  unsigned int lo = 1u, hi = 0xFFFFFFFFu;
  while (lo < hi) {
    const unsigned int mid = lo + ((hi - lo) >> 1) + ((hi - lo) & 1u);  // ceil
    int c = 0;
    for (int k = tid; k < TT; k += 256) c += (u[k] >= mid) ? 1 : 0;
#pragma unroll
    for (int o = 32; o > 0; o >>= 1) c += __shfl_down(c, o);
    if ((tid & 63) == 0) redi[tid >> 6] = c;
    __syncthreads();
    const int ctot = redi[0] + redi[1] + redi[2] + redi[3];
    __syncthreads();
    if (ctot >= TOPKK) lo = mid; else hi = mid - 1u;
  }
  const unsigned int ustar = lo;
  int c = 0;
  for (int k = tid; k < TT; k += 256) c += (u[k] > ustar) ? 1 : 0;
#pragma unroll
  for (int o = 32; o > 0; o >>= 1) c += __shfl_down(c, o);
  if ((tid & 63) == 0) redi[tid >> 6] = c;
  __syncthreads();
  const int nGreater = redi[0] + redi[1] + redi[2] + redi[3];
  if (tid == 0) {
    int need = TOPKK - nGreater;
    int cnt = 0;
    for (int k = 0; k <= q; ++k) {
      const unsigned int v = u[k];
      if (v > ustar) selidx[(size_t)q * TOPKK + (cnt++)] = k;
      else if (v == ustar && need > 0) { selidx[(size_t)q * TOPKK + (cnt++)] = k; --need; }
    }
    selcnt[q] = cnt;
  }
}

// ---------------- sparse attention over selected keys ----------------
__global__ __launch_bounds__(256) void attn_kernel(const float* __restrict__ qb,
                                                   const float* __restrict__ kvb,
                                                   const float* __restrict__ kpe,
                                                   const int* __restrict__ selidx,
                                                   const int* __restrict__ selcnt,
                                                   float* __restrict__ ao) {
  const int h = blockIdx.x, q = blockIdx.y;
  const int tid = threadIdx.x, lane = tid & 63, wv = tid >> 6;
  __shared__ float sc[TOPKK];
  __shared__ int sk[TOPKK];
  __shared__ float redf[4];
  __shared__ float pacc[128];
  const int cnt = selcnt[q];
  const float* qp = qb + (size_t)q * (NHH * 192) + h * 192;
  const float qa = qp[lane], qv2 = qp[64 + lane], qc = qp[128 + lane];
  float wmax = -INFINITY;
  for (int j = wv; j < cnt; j += 4) {
    const int k = selidx[(size_t)q * TOPKK + j];
    const float* kp = kvb + ((size_t)k * NHH + h) * 256;
    float p = qa * kp[lane] + qv2 * kp[64 + lane] + qc * kpe[(size_t)k * 64 + lane];
#pragma unroll
    for (int o = 32; o > 0; o >>= 1) p += __shfl_xor(p, o);
    p *= kScaling;
    if (lane == 0) { sc[j] = p; sk[j] = k; }
    wmax = fmaxf(wmax, p);
  }
  if (lane == 0) redf[wv] = wmax;
  __syncthreads();
  const float m = fmaxf(fmaxf(redf[0], redf[1]), fmaxf(redf[2], redf[3]));
  __syncthreads();  // everyone has read redf before it is overwritten
  float ls = 0.f;
  for (int j = tid; j < cnt; j += 256) {
    const float e = expf(sc[j] - m);
    sc[j] = e;
    ls += e;
  }
#pragma unroll
  for (int o = 32; o > 0; o >>= 1) ls += __shfl_xor(ls, o);
  if (lane == 0) redf[wv] = ls;
  __syncthreads();
  const float Z = redf[0] + redf[1] + redf[2] + redf[3];
  const int d = tid & 127, half = tid >> 7;
  float acc = 0.f;
  for (int j = half; j < cnt; j += 2)
    acc = fmaf(sc[j], kvb[((size_t)sk[j] * NHH + h) * 256 + 128 + d], acc);
  if (half == 1) pacc[d] = acc;
  __syncthreads();
  if (half == 0) ao[(size_t)q * (NHH * DVV) + h * DVV + d] = (acc + pacc[d]) / Z;
}

// ============================================================================
extern "C" void kernel_launch(void* const* d_in, const int* in_sizes, int n_in,
                              void* d_out, int out_size, void* d_ws, size_t ws_size,
                              hipStream_t stream) {
  const float* hidden     = (const float*)d_in[0];
  const int*   positions  = (const int*)d_in[1];
  const float* w_qkv_a    = (const float*)d_in[2];
  const float* q_a_ln_w   = (const float*)d_in[3];
  const float* w_q_b      = (const float*)d_in[4];
  const float* kv_a_ln_w  = (const float*)d_in[5];
  const float* w_kv_b     = (const float*)d_in[6];
  const float* w_o        = (const float*)d_in[7];
  const float* w_idx_qb   = (const float*)d_in[8];
  const float* w_idx_k    = (const float*)d_in[9];
  const float* idx_k_ln_w = (const float*)d_in[10];
  const float* idx_k_ln_b = (const float*)d_in[11];
  const float* w_idx_w    = (const float*)d_in[12];
  float* out = (float*)d_out;

  float* ws = (float*)d_ws;
  size_t off = 0;
  auto take = [&](size_t n) { float* p = ws + off; off += n; return p; };
  float* qkv   = take((size_t)TT * 2112);
  float* qcn   = take((size_t)TT * QLL);
  float* kvn   = take((size_t)TT * KLL);
  float* qbuf  = take((size_t)TT * NHH * 192);
  float* kvbuf = take((size_t)TT * NHH * 256);
  float* kpe   = take((size_t)TT * 64);
  float* qib   = take((size_t)TT * INHH * IHDD);
  float* kib   = take((size_t)TT * IHDD);
  float* wtsb  = take((size_t)TT * INHH);
  float* part  = take((size_t)4 * TT * TT);
  int* selidx  = (int*)take((size_t)TT * TOPKK);
  int* selcnt  = (int*)take(TT);
  float* lg = qcn;   // alias: qcn dead after q_b / idx_qb GEMMs
  float* ao = part;  // alias: part dead after reduce4

  const dim3 blk(256);
  // qkv_a projection (fp32 — feeds indexer-critical path)
  gemm_f32<<<dim3(17, 16), blk, 0, stream>>>(hidden, w_qkv_a, qkv, TT, 2112, HH);
  // RMS norms
  rms_kernel<<<TT, 256, 0, stream>>>(qkv, 2112, q_a_ln_w, qcn, QLL, QLL);
  rms_kernel<<<TT, 256, 0, stream>>>(qkv + 1536, 2112, kv_a_ln_w, kvn, KLL, KLL);
  // projections
  gemm_f32<<<dim3(48, 16), blk, 0, stream>>>(qcn, w_q_b, qbuf, TT, 6144, QLL);
  gemm_f32<<<dim3(64, 16), blk, 0, stream>>>(kvn, w_kv_b, kvbuf, TT, 8192, KLL);
  gemm_f32<<<dim3(32, 16), blk, 0, stream>>>(qcn, w_idx_qb, qib, TT, 4096, QLL);
  gemm_f32<<<dim3(1, 16),  blk, 0, stream>>>(hidden, w_idx_k, kib, TT, 128, HH);
  gemm_f32<<<dim3(1, 16),  blk, 0, stream>>>(hidden, w_idx_w, wtsb, TT, 32, HH);
  // indexer K layernorm, then RoPE everywhere
  ln_kernel<<<TT, 128, 0, stream>>>(kib, idx_k_ln_w, idx_k_ln_b);
  rope_kernel<<<dim3(TT, NHH), 32, 0, stream>>>(qbuf + 128, NHH * 192, 192,
                                                qbuf + 128, NHH * 192, 192, positions);
  rope_kernel<<<dim3(TT, 1), 32, 0, stream>>>(qkv + 2048, 2112, 0, kpe, 64, 0, positions);
  rope_kernel<<<dim3(TT, INHH), 32, 0, stream>>>(qib, INHH * IHDD, IHDD,
                                                 qib, INHH * IHDD, IHDD, positions);
  rope_kernel<<<dim3(TT, 1), 32, 0, stream>>>(kib, IHDD, 0, kib, IHDD, 0, positions);
  // indexer logits (quantization skipped: relu(x/s)*(w*s) == relu(x)*w for s=2^k>0)
  logits_kernel<<<dim3(16, 16, 4), blk, 0, stream>>>(qib, kib, wtsb, part);
  reduce4<<<dim3(1024), blk, 0, stream>>>(lg, part);
  // exact causal top-512
  topk_kernel<<<dim3(TT), blk, 0, stream>>>(lg, selidx, selcnt);
  // sparse attention
  attn_kernel<<<dim3(NHH, TT), blk, 0, stream>>>(qbuf, kvbuf, kpe, selidx, selcnt, ao);
  // output projection
  gemm_f32<<<dim3(32, 16), blk, 0, stream>>>(ao, w_o, out, TT, HH, NHH * DVV);
}

// Round 2
// 3434.505 us; speedup vs baseline: 1.3163x; 1.3163x over previous
//
#include <hip/hip_runtime.h>
#include <hip/hip_bf16.h>
#include <math.h>
#include <type_traits>

#define TT   1024
#define HH   4096
#define NHH  32
#define DNN  128
#define DRR  64
#define DVV  128
#define QLL  1536
#define KLL  512
#define INHH 32
#define IHDD 128
#define TOPKK 512

typedef __attribute__((ext_vector_type(8))) short short8;
typedef __attribute__((ext_vector_type(4))) float f32x4;

static __device__ __constant__ float kScaling = 0.07216878364870322f;  // (DN+DR)^-0.5
static __device__ __constant__ float kWtsScale = 0.015625f;            // IHD^-.5 * INH^-.5 = 1/64

static __device__ __forceinline__ short f2bf(float f) {
  unsigned u = __float_as_uint(f);
  unsigned r = (u + 0x7fffu + ((u >> 16) & 1u)) >> 16;  // RNE
  return (short)r;
}
static __device__ __forceinline__ float bf2f(short s) {
  return __uint_as_float(((unsigned)(unsigned short)s) << 16);
}

// ---------------- fp32 GEMM: C[M,N] = A[M,K] @ B[K,N] (indexer path) ----------------
__global__ __launch_bounds__(256) void gemm_f32(const float* __restrict__ A,
                                                const float* __restrict__ B,
                                                float* __restrict__ C,
                                                int M, int N, int K) {
  __shared__ float As[8][64];
  __shared__ float Bs[8][128];
  const int tid = threadIdx.x;
  const int tx = tid & 15, ty = tid >> 4;
  const int bm = blockIdx.y * 64, bn = blockIdx.x * 128;
  float acc[4][8];
#pragma unroll
  for (int i = 0; i < 4; ++i)
#pragma unroll
    for (int j = 0; j < 8; ++j) acc[i][j] = 0.f;

  const int am = tid >> 1;
  const int aj = (tid & 1) * 4;
  const int bk = tid >> 5;
  const int bnn = (tid & 31) * 4;

  for (int k0 = 0; k0 < K; k0 += 8) {
    if (tid < 128) {
      int gm = bm + am;
      float4 av = make_float4(0.f, 0.f, 0.f, 0.f);
      if (gm < M) av = *(const float4*)(A + (size_t)gm * K + k0 + aj);
      As[aj + 0][am] = av.x; As[aj + 1][am] = av.y;
      As[aj + 2][am] = av.z; As[aj + 3][am] = av.w;
    }
    {
      int gn = bn + bnn;
      const float* brow = B + (size_t)(k0 + bk) * N;
      float4 bv = make_float4(0.f, 0.f, 0.f, 0.f);
      if (gn + 3 < N) bv = *(const float4*)(brow + gn);
      else {
        if (gn + 0 < N) bv.x = brow[gn + 0];
        if (gn + 1 < N) bv.y = brow[gn + 1];
        if (gn + 2 < N) bv.z = brow[gn + 2];
      }
      *(float4*)&Bs[bk][bnn] = bv;
    }
    __syncthreads();
#pragma unroll
    for (int p = 0; p < 8; ++p) {
      float4 a4 = *(const float4*)&As[p][ty * 4];
      float4 b0 = *(const float4*)&Bs[p][tx * 8];
      float4 b1 = *(const float4*)&Bs[p][tx * 8 + 4];
      float av[4] = {a4.x, a4.y, a4.z, a4.w};
      float bb[8] = {b0.x, b0.y, b0.z, b0.w, b1.x, b1.y, b1.z, b1.w};
#pragma unroll
      for (int i = 0; i < 4; ++i)
#pragma unroll
        for (int j = 0; j < 8; ++j) acc[i][j] = fmaf(av[i], bb[j], acc[i][j]);
    }
    __syncthreads();
  }
#pragma unroll
  for (int i = 0; i < 4; ++i) {
    int gm = bm + ty * 4 + i;
    if (gm >= M) continue;
    float* crow = C + (size_t)gm * N;
    int gn = bn + tx * 8;
    if (gn + 7 < N) {
      *(float4*)(crow + gn)     = make_float4(acc[i][0], acc[i][1], acc[i][2], acc[i][3]);
      *(float4*)(crow + gn + 4) = make_float4(acc[i][4], acc[i][5], acc[i][6], acc[i][7]);
    } else {
#pragma unroll
      for (int j = 0; j < 8; ++j) if (gn + j < N) crow[gn + j] = acc[i][j];
    }
  }
}

// ---------------- bf16 MFMA GEMM: C[M,N] = A[M,K] @ Bt[N,K]^T ----------------
// M%128==0, N%128==0, K%64==0. 128x128 tile, BK=64, 4 waves (2x2), 16x16x32 mfma.
// LDS rows padded to 72 shorts (144 B pitch -> conflict-free b128 access).
template <typename CT>
__global__ __launch_bounds__(256) void gemm_bf16(const short* __restrict__ A,
                                                 const short* __restrict__ Bt,
                                                 CT* __restrict__ C,
                                                 int M, int N, int K) {
  __shared__ short As[128 * 72];
  __shared__ short Bs[128 * 72];
  const int tid = threadIdx.x;
  const int lane = tid & 63, wv = tid >> 6;
  const int wr = (wv >> 1) * 64, wc = (wv & 1) * 64;
  const int bm = blockIdx.y * 128, bn = blockIdx.x * 128;
  const int l15 = lane & 15, l4 = lane >> 4;
  f32x4 acc[4][4];
#pragma unroll
  for (int i = 0; i < 4; ++i)
#pragma unroll
    for (int j = 0; j < 4; ++j) acc[i][j] = f32x4{0.f, 0.f, 0.f, 0.f};

  for (int k0 = 0; k0 < K; k0 += 64) {
    __syncthreads();  // previous iteration's frag reads complete
#pragma unroll
    for (int i = 0; i < 4; ++i) {
      const int c = i * 256 + tid;
      const int m = c >> 3, kc = c & 7;
      short8 va = *(const short8*)(A + (size_t)(bm + m) * K + k0 + kc * 8);
      *(short8*)(&As[m * 72 + kc * 8]) = va;
      short8 vb = *(const short8*)(Bt + (size_t)(bn + m) * K + k0 + kc * 8);
      *(short8*)(&Bs[m * 72 + kc * 8]) = vb;
    }
    __syncthreads();
    short8 fa[4][2], fb[4][2];
#pragma unroll
    for (int f = 0; f < 4; ++f)
#pragma unroll
      for (int kk = 0; kk < 2; ++kk) {
        fa[f][kk] = *(const short8*)(&As[(wr + f * 16 + l15) * 72 + kk * 32 + l4 * 8]);
        fb[f][kk] = *(const short8*)(&Bs[(wc + f * 16 + l15) * 72 + kk * 32 + l4 * 8]);
      }
#pragma unroll
    for (int kk = 0; kk < 2; ++kk)
#pragma unroll
      for (int i = 0; i < 4; ++i)
#pragma unroll
        for (int j = 0; j < 4; ++j)
          acc[i][j] = __builtin_amdgcn_mfma_f32_16x16x32_bf16(fa[i][kk], fb[j][kk], acc[i][j], 0, 0, 0);
  }
#pragma unroll
  for (int i = 0; i < 4; ++i)
#pragma unroll
    for (int j = 0; j < 4; ++j)
#pragma unroll
      for (int r = 0; r < 4; ++r) {
        const int row = bm + wr + i * 16 + l4 * 4 + r;
        const int col = bn + wc + j * 16 + l15;
        const float v = acc[i][j][r];
        if constexpr (std::is_same<CT, float>::value) C[(size_t)row * N + col] = v;
        else C[(size_t)row * N + col] = __float2bfloat16(v);
      }
}

// ---------------- transpose + cast: B[K][N] f32 -> Bt[N][K] bf16 ----------------
// grid (N/64, K/64)
__global__ __launch_bounds__(256) void transpose_cast(const float* __restrict__ B,
                                                      short* __restrict__ Bt,
                                                      int K, int N) {
  __shared__ float tile[64][65];
  const int tid = threadIdx.x;
  const int k0 = blockIdx.y * 64, n0 = blockIdx.x * 64;
  const int r = tid >> 4, c4 = (tid & 15) * 4;
#pragma unroll
  for (int i = 0; i < 4; ++i) {
    float4 v = *(const float4*)(B + (size_t)(k0 + r + i * 16) * N + n0 + c4);
    tile[r + i * 16][c4 + 0] = v.x;
    tile[r + i * 16][c4 + 1] = v.y;
    tile[r + i * 16][c4 + 2] = v.z;
    tile[r + i * 16][c4 + 3] = v.w;
  }
  __syncthreads();
  const int nl = tid >> 3, kc = (tid & 7) * 8;
#pragma unroll
  for (int i = 0; i < 2; ++i) {
    const int n = nl + i * 32;
    short8 o;
#pragma unroll
    for (int e = 0; e < 8; ++e) o[e] = f2bf(tile[kc + e][n]);
    *(short8*)(Bt + (size_t)(n0 + n) * K + k0 + kc) = o;
  }
}

// ---------------- flat f32 -> bf16 cast ----------------
__global__ void cast_bf(const float* __restrict__ in, short* __restrict__ out, int n) {
  const int i = blockIdx.x * 256 + threadIdx.x;
  if (i < n) out[i] = f2bf(in[i]);
}

// ---------------- RMSNorm: fp32 + bf16 outputs ----------------
__global__ __launch_bounds__(256) void rms_kernel(const float* __restrict__ in, int in_stride,
                                                  const float* __restrict__ w,
                                                  float* __restrict__ out,
                                                  short* __restrict__ out_bf, int C) {
  const int t = blockIdx.x, tid = threadIdx.x;
  const float* x = in + (size_t)t * in_stride;
  float ss = 0.f;
  for (int i = tid; i < C; i += 256) { float v = x[i]; ss = fmaf(v, v, ss); }
#pragma unroll
  for (int o = 32; o > 0; o >>= 1) ss += __shfl_xor(ss, o);
  __shared__ float red[4];
  if ((tid & 63) == 0) red[tid >> 6] = ss;
  __syncthreads();
  const float tot = red[0] + red[1] + red[2] + red[3];
  const float r = rsqrtf(tot / (float)C + 1e-6f);
  for (int i = tid; i < C; i += 256) {
    const float v = x[i] * r * w[i];
    out[(size_t)t * C + i] = v;
    out_bf[(size_t)t * C + i] = f2bf(v);
  }
}

// ---------------- LayerNorm in-place on (T,128) ----------------
__global__ __launch_bounds__(128) void ln_kernel(float* __restrict__ x,
                                                 const float* __restrict__ w,
                                                 const float* __restrict__ b) {
  const int t = blockIdx.x, i = threadIdx.x;
  float v = x[(size_t)t * 128 + i];
  float s = v;
#pragma unroll
  for (int o = 32; o > 0; o >>= 1) s += __shfl_xor(s, o);
  __shared__ float r1[2], r2[2];
  if ((i & 63) == 0) r1[i >> 6] = s;
  __syncthreads();
  const float m = (r1[0] + r1[1]) * (1.f / 128.f);
  const float dv = v - m;
  float sq = dv * dv;
#pragma unroll
  for (int o = 32; o > 0; o >>= 1) sq += __shfl_xor(sq, o);
  if ((i & 63) == 0) r2[i >> 6] = sq;
  __syncthreads();
  const float var = (r2[0] + r2[1]) * (1.f / 128.f);
  x[(size_t)t * 128 + i] = dv * rsqrtf(var + 1e-6f) * w[i] + b[i];
}

// ---------------- RoPE (interleaved pairs), 32 pairs per (t,h) ----------------
__global__ void rope_kernel(const float* __restrict__ src, int s_ts, int s_hs,
                            float* __restrict__ dst, int d_ts, int d_hs,
                            const int* __restrict__ pos) {
  const int t = blockIdx.x, h = blockIdx.y, i = threadIdx.x;  // 32 threads
  const float* s = src + (size_t)t * s_ts + (size_t)h * s_hs;
  float* d = dst + (size_t)t * d_ts + (size_t)h * d_hs;
  const float x1 = s[2 * i], x2 = s[2 * i + 1];
  const float inv = powf(10000.f, -(float)i * (1.f / 32.f));
  const float ang = (float)pos[t] * inv;
  float sn, cs;
  sincosf(ang, &sn, &cs);
  d[2 * i]     = x1 * cs - x2 * sn;
  d[2 * i + 1] = x1 * sn + x2 * cs;
}

// ---------------- Indexer logits (per head-group partial, fp32) ----------------
__global__ __launch_bounds__(256) void logits_kernel(const float* __restrict__ qi,
                                                     const float* __restrict__ ki,
                                                     const float* __restrict__ wts,
                                                     float* __restrict__ part) {
  const int bk = blockIdx.x, bq = blockIdx.y, g = blockIdx.z;
  if (bk > bq) return;
  __shared__ float Qs[16][64];
  __shared__ float Ks[16][64];
  const int tid = threadIdx.x;
  const int tx = tid & 15, ty = tid >> 4;
  const int srow = tid >> 2;
  const int sj = (tid & 3) * 4;
  float lacc[4][4];
#pragma unroll
  for (int i = 0; i < 4; ++i)
#pragma unroll
    for (int j = 0; j < 4; ++j) lacc[i][j] = 0.f;

  for (int h = g * 8; h < g * 8 + 8; ++h) {
    float hacc[4][4];
#pragma unroll
    for (int i = 0; i < 4; ++i)
#pragma unroll
      for (int j = 0; j < 4; ++j) hacc[i][j] = 0.f;
    for (int kc = 0; kc < 128; kc += 16) {
      float4 qv = *(const float4*)(qi + ((size_t)(bq * 64 + srow) * 32 + h) * 128 + kc + sj);
      float4 kv4 = *(const float4*)(ki + (size_t)(bk * 64 + srow) * 128 + kc + sj);
      __syncthreads();
      Qs[sj + 0][srow] = qv.x;  Qs[sj + 1][srow] = qv.y;
      Qs[sj + 2][srow] = qv.z;  Qs[sj + 3][srow] = qv.w;
      Ks[sj + 0][srow] = kv4.x; Ks[sj + 1][srow] = kv4.y;
      Ks[sj + 2][srow] = kv4.z; Ks[sj + 3][srow] = kv4.w;
      __syncthreads();
#pragma unroll
      for (int p = 0; p < 16; ++p) {
        float4 a4 = *(const float4*)&Qs[p][ty * 4];
        float4 b4 = *(const float4*)&Ks[p][tx * 4];
        float av[4] = {a4.x, a4.y, a4.z, a4.w};
        float bv[4] = {b4.x, b4.y, b4.z, b4.w};
#pragma unroll
        for (int i = 0; i < 4; ++i)
#pragma unroll
          for (int j = 0; j < 4; ++j) hacc[i][j] = fmaf(av[i], bv[j], hacc[i][j]);
      }
    }
#pragma unroll
    for (int i = 0; i < 4; ++i) {
      const float w = wts[(size_t)(bq * 64 + ty * 4 + i) * 32 + h] * kWtsScale;
#pragma unroll
      for (int j = 0; j < 4; ++j) lacc[i][j] = fmaf(w, fmaxf(hacc[i][j], 0.f), lacc[i][j]);
    }
  }
#pragma unroll
  for (int i = 0; i < 4; ++i)
#pragma unroll
    for (int j = 0; j < 4; ++j)
      part[(size_t)g * TT * TT + (size_t)(bq * 64 + ty * 4 + i) * TT + (bk * 64 + tx * 4 + j)] =
          lacc[i][j];
}

// ---------------- sum 4 head-group partials ----------------
__global__ __launch_bounds__(256) void reduce4(float* __restrict__ dst, const float* __restrict__ part) {
  const size_t i = ((size_t)blockIdx.x * 256 + threadIdx.x) * 4;
  const size_t N = (size_t)TT * TT;
  float4 a = *(const float4*)(part + i);
  float4 b = *(const float4*)(part + N + i);
  float4 c = *(const float4*)(part + 2 * N + i);
  float4 d = *(const float4*)(part + 3 * N + i);
  *(float4*)(dst + i) =
      make_float4(a.x + b.x + c.x + d.x, a.y + b.y + c.y + d.y,
                  a.z + b.z + c.z + d.z, a.w + b.w + c.w + d.w);
}

// ---------------- exact causal top-512 per row ----------------
__global__ __launch_bounds__(256) void topk_kernel(const float* __restrict__ lg,
                                                   int* __restrict__ selidx,
                                                   int* __restrict__ selcnt) {
  const int q = blockIdx.x;
  const int tid = threadIdx.x;
  __shared__ unsigned int u[TT];
  __shared__ int redi[4];
  for (int k = tid; k < TT; k += 256) {
    unsigned int uv = 0u;
    if (k <= q) {
      unsigned int bb = __float_as_uint(lg[(size_t)q * TT + k]);
      uv = (bb & 0x80000000u) ? ~bb : (bb | 0x80000000u);
    }
    u[k] = uv;
  }
  __syncthreads();
  const int n = q + 1;
  if (n <= TOPKK) {
    for (int k = tid; k < n; k += 256) selidx[(size_t)q * TOPKK + k] = k;
    if (tid == 0) selcnt[q] = n;
    return;
  }
  unsigned int lo = 1u, hi = 0xFFFFFFFFu;
  while (lo < hi) {
    const unsigned int mid = lo + ((hi - lo) >> 1) + ((hi - lo) & 1u);
    int c = 0;
    for (int k = tid; k < TT; k += 256) c += (u[k] >= mid) ? 1 : 0;
#pragma unroll
    for (int o = 32; o > 0; o >>= 1) c += __shfl_down(c, o);
    if ((tid & 63) == 0) redi[tid >> 6] = c;
    __syncthreads();
    const int ctot = redi[0] + redi[1] + redi[2] + redi[3];
    __syncthreads();
    if (ctot >= TOPKK) lo = mid; else hi = mid - 1u;
  }
  const unsigned int ustar = lo;
  int c = 0;
  for (int k = tid; k < TT; k += 256) c += (u[k] > ustar) ? 1 : 0;
#pragma unroll
  for (int o = 32; o > 0; o >>= 1) c += __shfl_down(c, o);
  if ((tid & 63) == 0) redi[tid >> 6] = c;
  __syncthreads();
  const int nGreater = redi[0] + redi[1] + redi[2] + redi[3];
  if (tid == 0) {
    int need = TOPKK - nGreater;
    int cnt = 0;
    for (int k = 0; k <= q; ++k) {
      const unsigned int v = u[k];
      if (v > ustar) selidx[(size_t)q * TOPKK + (cnt++)] = k;
      else if (v == ustar && need > 0) { selidx[(size_t)q * TOPKK + (cnt++)] = k; --need; }
    }
    selcnt[q] = cnt;
  }
}

// ---------------- sparse attention: lane-per-key, bf16 K/V ----------------
__global__ __launch_bounds__(256) void attn_kernel(const float* __restrict__ qb,
                                                   const short* __restrict__ kvb,
                                                   const short* __restrict__ kpe_bf,
                                                   const int* __restrict__ selidx,
                                                   const int* __restrict__ selcnt,
                                                   __hip_bfloat16* __restrict__ ao) {
  const int h = blockIdx.x, q = blockIdx.y;
  const int tid = threadIdx.x, lane = tid & 63, wv = tid >> 6;
  __shared__ float qs[192];
  __shared__ float sc[TOPKK];
  __shared__ int sk[TOPKK];
  __shared__ float red[4];
  __shared__ float pacc[128];
  const int cnt = selcnt[q];
  if (tid < 192) qs[tid] = qb[(size_t)q * (NHH * 192) + h * 192 + tid];
  for (int j = tid; j < TOPKK; j += 256) sk[j] = (j < cnt) ? selidx[(size_t)q * TOPKK + j] : 0;
  __syncthreads();

  // ---- scores: one thread = one key ----
  float lmax = -INFINITY;
#pragma unroll
  for (int rep = 0; rep < 2; ++rep) {
    const int j = tid + rep * 256;
    float s = -INFINITY;
    if (j < cnt) {
      const int k = sk[j];
      const short8* kp8 = (const short8*)(kvb + ((size_t)k * NHH + h) * 256);
      float acc = 0.f;
#pragma unroll
      for (int c = 0; c < 16; ++c) {
        short8 kv = kp8[c];
#pragma unroll
        for (int e = 0; e < 8; ++e) acc = fmaf(bf2f(kv[e]), qs[c * 8 + e], acc);
      }
      const short8* pp8 = (const short8*)(kpe_bf + (size_t)k * 64);
#pragma unroll
      for (int c = 0; c < 8; ++c) {
        short8 pv = pp8[c];
#pragma unroll
        for (int e = 0; e < 8; ++e) acc = fmaf(bf2f(pv[e]), qs[128 + c * 8 + e], acc);
      }
      s = acc * kScaling;
    }
    sc[j] = s;
    lmax = fmaxf(lmax, s);
  }
  // ---- block max ----
#pragma unroll
  for (int o = 32; o > 0; o >>= 1) lmax = fmaxf(lmax, __shfl_xor(lmax, o));
  if (lane == 0) red[wv] = lmax;
  __syncthreads();
  const float m = fmaxf(fmaxf(red[0], red[1]), fmaxf(red[2], red[3]));
  __syncthreads();
  // ---- exp + sum ----
  float ls = 0.f;
#pragma unroll
  for (int rep = 0; rep < 2; ++rep) {
    const int j = tid + rep * 256;
    const float e = __expf(sc[j] - m);  // -inf -> 0
    sc[j] = e;
    ls += e;
  }
#pragma unroll
  for (int o = 32; o > 0; o >>= 1) ls += __shfl_xor(ls, o);
  if (lane == 0) red[wv] = ls;
  __syncthreads();
  const float Z = red[0] + red[1] + red[2] + red[3];
  // ---- PV ----
  const int d = tid & 127, half = tid >> 7;
  float acc = 0.f;
  for (int j = half; j < cnt; j += 2)
    acc = fmaf(sc[j], bf2f(kvb[((size_t)sk[j] * NHH + h) * 256 + 128 + d]), acc);
  if (half == 1) pacc[d] = acc;
  __syncthreads();
  if (half == 0)
    ao[(size_t)q * (NHH * DVV) + h * DVV + d] = __float2bfloat16((acc + pacc[d]) / Z);
}

// ============================================================================
extern "C" void kernel_launch(void* const* d_in, const int* in_sizes, int n_in,
                              void* d_out, int out_size, void* d_ws, size_t ws_size,
                              hipStream_t stream) {
  const float* hidden     = (const float*)d_in[0];
  const int*   positions  = (const int*)d_in[1];
  const float* w_qkv_a    = (const float*)d_in[2];
  const float* q_a_ln_w   = (const float*)d_in[3];
  const float* w_q_b      = (const float*)d_in[4];
  const float* kv_a_ln_w  = (const float*)d_in[5];
  const float* w_kv_b     = (const float*)d_in[6];
  const float* w_o        = (const float*)d_in[7];
  const float* w_idx_qb   = (const float*)d_in[8];
  const float* w_idx_k    = (const float*)d_in[9];
  const float* idx_k_ln_w = (const float*)d_in[10];
  const float* idx_k_ln_b = (const float*)d_in[11];
  const float* w_idx_w    = (const float*)d_in[12];
  float* out = (float*)d_out;

  float* ws = (float*)d_ws;
  size_t off = 0;
  auto take = [&](size_t n) { float* p = ws + off; off += n; return p; };
  float* qkv    = take((size_t)TT * 2112);
  float* qcn    = take((size_t)TT * QLL);
  short* qcn_bf = (short*)take((size_t)TT * QLL / 2);
  float* kvn    = take((size_t)TT * KLL);
  short* kvn_bf = (short*)take((size_t)TT * KLL / 2);
  float* qbuf   = take((size_t)TT * NHH * 192);
  short* kvbuf  = (short*)take((size_t)TT * NHH * 256 / 2);  // bf16
  float* kpe    = take((size_t)TT * 64);
  short* kpe_bf = (short*)take((size_t)TT * 32);
  float* qib    = take((size_t)TT * INHH * IHDD);
  float* kib    = take((size_t)TT * IHDD);
  float* wtsb   = take((size_t)TT * INHH);
  float* part   = take((size_t)4 * TT * TT);
  int* selidx   = (int*)take((size_t)TT * TOPKK);
  int* selcnt   = (int*)take(TT);
  short* wqb_t  = (short*)take((size_t)6144 * QLL / 2);
  short* wkvb_t = (short*)take((size_t)8192 * KLL / 2);
  short* wo_t   = (short*)take((size_t)HH * HH / 2);
  float* lg = qcn;                        // alias: qcn fp32 dead after idx_qb GEMM
  __hip_bfloat16* ao = (__hip_bfloat16*)part;  // alias: part dead after reduce4

  const dim3 blk(256);
  // weight transposes (bf16) — independent, launch first
  transpose_cast<<<dim3(6144 / 64, QLL / 64), blk, 0, stream>>>(w_q_b, wqb_t, QLL, 6144);
  transpose_cast<<<dim3(8192 / 64, KLL / 64), blk, 0, stream>>>(w_kv_b, wkvb_t, KLL, 8192);
  transpose_cast<<<dim3(HH / 64, HH / 64), blk, 0, stream>>>(w_o, wo_t, HH, HH);
  // qkv_a projection (fp32 — feeds indexer-critical path)
  gemm_f32<<<dim3(17, 16), blk, 0, stream>>>(hidden, w_qkv_a, qkv, TT, 2112, HH);
  // RMS norms (fp32 + bf16 outputs)
  rms_kernel<<<TT, 256, 0, stream>>>(qkv, 2112, q_a_ln_w, qcn, qcn_bf, QLL);
  rms_kernel<<<TT, 256, 0, stream>>>(qkv + 1536, 2112, kv_a_ln_w, kvn, kvn_bf, KLL);
  // bf16 MFMA projections (smooth path)
  gemm_bf16<float><<<dim3(48, 8), blk, 0, stream>>>(qcn_bf, wqb_t, qbuf, TT, 6144, QLL);
  gemm_bf16<__hip_bfloat16><<<dim3(64, 8), blk, 0, stream>>>(kvn_bf, wkvb_t, (__hip_bfloat16*)kvbuf, TT, 8192, KLL);
  // fp32 projections (indexer path)
  gemm_f32<<<dim3(32, 16), blk, 0, stream>>>(qcn, w_idx_qb, qib, TT, 4096, QLL);
  gemm_f32<<<dim3(1, 16),  blk, 0, stream>>>(hidden, w_idx_k, kib, TT, 128, HH);
  gemm_f32<<<dim3(1, 16),  blk, 0, stream>>>(hidden, w_idx_w, wtsb, TT, 32, HH);
  // indexer K layernorm, RoPE everywhere
  ln_kernel<<<TT, 128, 0, stream>>>(kib, idx_k_ln_w, idx_k_ln_b);
  rope_kernel<<<dim3(TT, NHH), 32, 0, stream>>>(qbuf + 128, NHH * 192, 192,
                                                qbuf + 128, NHH * 192, 192, positions);
  rope_kernel<<<dim3(TT, 1), 32, 0, stream>>>(qkv + 2048, 2112, 0, kpe, 64, 0, positions);
  rope_kernel<<<dim3(TT, INHH), 32, 0, stream>>>(qib, INHH * IHDD, IHDD,
                                                 qib, INHH * IHDD, IHDD, positions);
  rope_kernel<<<dim3(TT, 1), 32, 0, stream>>>(kib, IHDD, 0, kib, IHDD, 0, positions);
  cast_bf<<<dim3(TT * 64 / 256), blk, 0, stream>>>(kpe, kpe_bf, TT * 64);
  // indexer logits (fp32; quantization cancels: relu(x/s)*(w*s) == relu(x)*w)
  logits_kernel<<<dim3(16, 16, 4), blk, 0, stream>>>(qib, kib, wtsb, part);
  reduce4<<<dim3(1024), blk, 0, stream>>>(lg, part);
  topk_kernel<<<dim3(TT), blk, 0, stream>>>(lg, selidx, selcnt);
  // sparse attention (bf16 K/V, lane-per-key)
  attn_kernel<<<dim3(NHH, TT), blk, 0, stream>>>(qbuf, kvbuf, kpe_bf, selidx, selcnt, ao);
  // output projection (bf16 MFMA)
  gemm_bf16<float><<<dim3(32, 8), blk, 0, stream>>>((const short*)ao, wo_t, out, TT, HH, NHH * DVV);
}

// Round 3
// 1818.289 us; speedup vs baseline: 2.4863x; 1.8889x over previous
//
#include <hip/hip_runtime.h>
#include <hip/hip_bf16.h>
#include <math.h>
#include <type_traits>

#define TT   1024
#define HH   4096
#define NHH  32
#define DNN  128
#define DRR  64
#define DVV  128
#define QLL  1536
#define KLL  512
#define INHH 32
#define IHDD 128
#define TOPKK 512

typedef __attribute__((ext_vector_type(8))) short short8;
typedef __attribute__((ext_vector_type(4))) short short4v;
typedef __attribute__((ext_vector_type(4))) float f32x4;

static __device__ __constant__ float kScaling = 0.07216878364870322f;  // (DN+DR)^-0.5
static __device__ __constant__ float kWtsScale = 0.015625f;            // IHD^-.5 * INH^-.5

static __device__ __forceinline__ short f2bf(float f) {
  unsigned u = __float_as_uint(f);
  unsigned r = (u + 0x7fffu + ((u >> 16) & 1u)) >> 16;  // RNE
  return (short)r;
}
static __device__ __forceinline__ float bf2f(short s) {
  return __uint_as_float(((unsigned)(unsigned short)s) << 16);
}

// ---------------- fp32 GEMM (small indexer projections) ----------------
__global__ __launch_bounds__(256) void gemm_f32(const float* __restrict__ A,
                                                const float* __restrict__ B,
                                                float* __restrict__ C,
                                                int M, int N, int K) {
  __shared__ float As[8][64];
  __shared__ float Bs[8][128];
  const int tid = threadIdx.x;
  const int tx = tid & 15, ty = tid >> 4;
  const int bm = blockIdx.y * 64, bn = blockIdx.x * 128;
  float acc[4][8];
#pragma unroll
  for (int i = 0; i < 4; ++i)
#pragma unroll
    for (int j = 0; j < 8; ++j) acc[i][j] = 0.f;
  const int am = tid >> 1;
  const int aj = (tid & 1) * 4;
  const int bk = tid >> 5;
  const int bnn = (tid & 31) * 4;
  for (int k0 = 0; k0 < K; k0 += 8) {
    if (tid < 128) {
      int gm = bm + am;
      float4 av = make_float4(0.f, 0.f, 0.f, 0.f);
      if (gm < M) av = *(const float4*)(A + (size_t)gm * K + k0 + aj);
      As[aj + 0][am] = av.x; As[aj + 1][am] = av.y;
      As[aj + 2][am] = av.z; As[aj + 3][am] = av.w;
    }
    {
      int gn = bn + bnn;
      const float* brow = B + (size_t)(k0 + bk) * N;
      float4 bv = make_float4(0.f, 0.f, 0.f, 0.f);
      if (gn + 3 < N) bv = *(const float4*)(brow + gn);
      else {
        if (gn + 0 < N) bv.x = brow[gn + 0];
        if (gn + 1 < N) bv.y = brow[gn + 1];
        if (gn + 2 < N) bv.z = brow[gn + 2];
      }
      *(float4*)&Bs[bk][bnn] = bv;
    }
    __syncthreads();
#pragma unroll
    for (int p = 0; p < 8; ++p) {
      float4 a4 = *(const float4*)&As[p][ty * 4];
      float4 b0 = *(const float4*)&Bs[p][tx * 8];
      float4 b1 = *(const float4*)&Bs[p][tx * 8 + 4];
      float av[4] = {a4.x, a4.y, a4.z, a4.w};
      float bb[8] = {b0.x, b0.y, b0.z, b0.w, b1.x, b1.y, b1.z, b1.w};
#pragma unroll
      for (int i = 0; i < 4; ++i)
#pragma unroll
        for (int j = 0; j < 8; ++j) acc[i][j] = fmaf(av[i], bb[j], acc[i][j]);
    }
    __syncthreads();
  }
#pragma unroll
  for (int i = 0; i < 4; ++i) {
    int gm = bm + ty * 4 + i;
    if (gm >= M) continue;
    float* crow = C + (size_t)gm * N;
    int gn = bn + tx * 8;
    if (gn + 7 < N) {
      *(float4*)(crow + gn)     = make_float4(acc[i][0], acc[i][1], acc[i][2], acc[i][3]);
      *(float4*)(crow + gn + 4) = make_float4(acc[i][4], acc[i][5], acc[i][6], acc[i][7]);
    } else {
#pragma unroll
      for (int j = 0; j < 8; ++j) if (gn + j < N) crow[gn + j] = acc[i][j];
    }
  }
}

// ---------------- plain bf16 MFMA GEMM: C = A @ Bt^T ----------------
template <typename CT>
__global__ __launch_bounds__(256) void gemm_bf16(const short* __restrict__ A,
                                                 const short* __restrict__ Bt,
                                                 CT* __restrict__ C,
                                                 int M, int N, int K) {
  __shared__ short As[128 * 72];
  __shared__ short Bs[128 * 72];
  const int tid = threadIdx.x;
  const int lane = tid & 63, wv = tid >> 6;
  const int wr = (wv >> 1) * 64, wc = (wv & 1) * 64;
  const int bm = blockIdx.y * 128, bn = blockIdx.x * 128;
  const int l15 = lane & 15, l4 = lane >> 4;
  f32x4 acc[4][4];
#pragma unroll
  for (int i = 0; i < 4; ++i)
#pragma unroll
    for (int j = 0; j < 4; ++j) acc[i][j] = f32x4{0.f, 0.f, 0.f, 0.f};
  for (int k0 = 0; k0 < K; k0 += 64) {
    __syncthreads();
#pragma unroll
    for (int i = 0; i < 4; ++i) {
      const int c = i * 256 + tid;
      const int m = c >> 3, kc = c & 7;
      short8 va = *(const short8*)(A + (size_t)(bm + m) * K + k0 + kc * 8);
      *(short8*)(&As[m * 72 + kc * 8]) = va;
      short8 vb = *(const short8*)(Bt + (size_t)(bn + m) * K + k0 + kc * 8);
      *(short8*)(&Bs[m * 72 + kc * 8]) = vb;
    }
    __syncthreads();
    short8 fa[4][2], fb[4][2];
#pragma unroll
    for (int f = 0; f < 4; ++f)
#pragma unroll
      for (int kk = 0; kk < 2; ++kk) {
        fa[f][kk] = *(const short8*)(&As[(wr + f * 16 + l15) * 72 + kk * 32 + l4 * 8]);
        fb[f][kk] = *(const short8*)(&Bs[(wc + f * 16 + l15) * 72 + kk * 32 + l4 * 8]);
      }
#pragma unroll
    for (int kk = 0; kk < 2; ++kk)
#pragma unroll
      for (int i = 0; i < 4; ++i)
#pragma unroll
        for (int j = 0; j < 4; ++j)
          acc[i][j] = __builtin_amdgcn_mfma_f32_16x16x32_bf16(fa[i][kk], fb[j][kk], acc[i][j], 0, 0, 0);
  }
#pragma unroll
  for (int i = 0; i < 4; ++i)
#pragma unroll
    for (int j = 0; j < 4; ++j)
#pragma unroll
      for (int r = 0; r < 4; ++r) {
        const int row = bm + wr + i * 16 + l4 * 4 + r;
        const int col = bn + wc + j * 16 + l15;
        const float v = acc[i][j][r];
        if constexpr (std::is_same<CT, float>::value) C[(size_t)row * N + col] = v;
        else C[(size_t)row * N + col] = __float2bfloat16(v);
      }
}

// ---------------- bf16x3 split GEMM: C = A(f32) @ Bt^T (hi+lo) ----------------
// BM=64, BN=128, BK=32; error ~2^-16 relative (topk-safe).
__global__ __launch_bounds__(256) void gemm_bf16x3(const float* __restrict__ A,
                                                   const short* __restrict__ Bth,
                                                   const short* __restrict__ Btl,
                                                   float* __restrict__ C,
                                                   int M, int N, int K) {
  __shared__ short Ah[64 * 40], Al[64 * 40], Bh[128 * 40], Bl[128 * 40];
  const int tid = threadIdx.x;
  const int lane = tid & 63, wv = tid >> 6;
  const int wr = (wv >> 1) * 32, wc = (wv & 1) * 64;
  const int l15 = lane & 15, l4 = lane >> 4;
  const int bm = blockIdx.y * 64, bn = blockIdx.x * 128;
  f32x4 acc[2][4];
#pragma unroll
  for (int i = 0; i < 2; ++i)
#pragma unroll
    for (int j = 0; j < 4; ++j) acc[i][j] = f32x4{0.f, 0.f, 0.f, 0.f};
  const int arow = tid >> 2, aseg = (tid & 3) * 8;
  const int brow = tid >> 1, bseg = (tid & 1) * 16;
  const bool bok = (bn + brow) < N;
  for (int k0 = 0; k0 < K; k0 += 32) {
    __syncthreads();
    {
      const float* ap = A + (size_t)(bm + arow) * K + k0 + aseg;
      float4 a0 = *(const float4*)ap;
      float4 a1 = *(const float4*)(ap + 4);
      float av[8] = {a0.x, a0.y, a0.z, a0.w, a1.x, a1.y, a1.z, a1.w};
      short8 h8, l8;
#pragma unroll
      for (int e = 0; e < 8; ++e) {
        h8[e] = f2bf(av[e]);
        l8[e] = f2bf(av[e] - bf2f(h8[e]));
      }
      *(short8*)&Ah[arow * 40 + aseg] = h8;
      *(short8*)&Al[arow * 40 + aseg] = l8;
    }
    if (bok) {
      const short* sh = Bth + (size_t)(bn + brow) * K + k0 + bseg;
      const short* sl = Btl + (size_t)(bn + brow) * K + k0 + bseg;
      *(short8*)&Bh[brow * 40 + bseg]     = *(const short8*)sh;
      *(short8*)&Bh[brow * 40 + bseg + 8] = *(const short8*)(sh + 8);
      *(short8*)&Bl[brow * 40 + bseg]     = *(const short8*)sl;
      *(short8*)&Bl[brow * 40 + bseg + 8] = *(const short8*)(sl + 8);
    }
    __syncthreads();
    short8 fah[2], fal[2], fbh[4], fbl[4];
#pragma unroll
    for (int rt = 0; rt < 2; ++rt) {
      fah[rt] = *(const short8*)&Ah[(wr + rt * 16 + l15) * 40 + l4 * 8];
      fal[rt] = *(const short8*)&Al[(wr + rt * 16 + l15) * 40 + l4 * 8];
    }
#pragma unroll
    for (int ct = 0; ct < 4; ++ct) {
      fbh[ct] = *(const short8*)&Bh[(wc + ct * 16 + l15) * 40 + l4 * 8];
      fbl[ct] = *(const short8*)&Bl[(wc + ct * 16 + l15) * 40 + l4 * 8];
    }
#pragma unroll
    for (int rt = 0; rt < 2; ++rt)
#pragma unroll
      for (int ct = 0; ct < 4; ++ct) {
        acc[rt][ct] = __builtin_amdgcn_mfma_f32_16x16x32_bf16(fah[rt], fbh[ct], acc[rt][ct], 0, 0, 0);
        acc[rt][ct] = __builtin_amdgcn_mfma_f32_16x16x32_bf16(fah[rt], fbl[ct], acc[rt][ct], 0, 0, 0);
        acc[rt][ct] = __builtin_amdgcn_mfma_f32_16x16x32_bf16(fal[rt], fbh[ct], acc[rt][ct], 0, 0, 0);
      }
  }
#pragma unroll
  for (int rt = 0; rt < 2; ++rt)
#pragma unroll
    for (int ct = 0; ct < 4; ++ct)
#pragma unroll
      for (int r = 0; r < 4; ++r) {
        const int row = bm + wr + rt * 16 + l4 * 4 + r;
        const int col = bn + wc + ct * 16 + l15;
        if (col < N) C[(size_t)row * N + col] = acc[rt][ct][r];
      }
}

// ---------------- transpose + cast: B[K][N] f32 -> Bt[N][K] bf16 ----------------
__global__ __launch_bounds__(256) void transpose_cast(const float* __restrict__ B,
                                                      short* __restrict__ Bt,
                                                      int K, int N) {
  __shared__ float tile[64][65];
  const int tid = threadIdx.x;
  const int k0 = blockIdx.y * 64, n0 = blockIdx.x * 64;
  const int r = tid >> 4, c4 = (tid & 15) * 4;
#pragma unroll
  for (int i = 0; i < 4; ++i) {
    float4 v = *(const float4*)(B + (size_t)(k0 + r + i * 16) * N + n0 + c4);
    tile[r + i * 16][c4 + 0] = v.x;
    tile[r + i * 16][c4 + 1] = v.y;
    tile[r + i * 16][c4 + 2] = v.z;
    tile[r + i * 16][c4 + 3] = v.w;
  }
  __syncthreads();
  const int nl = tid >> 3, kc = (tid & 7) * 8;
#pragma unroll
  for (int i = 0; i < 2; ++i) {
    const int n = nl + i * 32;
    short8 o;
#pragma unroll
    for (int e = 0; e < 8; ++e) o[e] = f2bf(tile[kc + e][n]);
    *(short8*)(Bt + (size_t)(n0 + n) * K + k0 + kc) = o;
  }
}

// ---------------- transpose + split cast (hi/lo) ----------------
__global__ __launch_bounds__(256) void transpose_split_cast(const float* __restrict__ B,
                                                            short* __restrict__ Bth,
                                                            short* __restrict__ Btl,
                                                            int K, int N) {
  __shared__ float tile[64][65];
  const int tid = threadIdx.x;
  const int k0 = blockIdx.y * 64, n0 = blockIdx.x * 64;
  const int r = tid >> 4, c4 = (tid & 15) * 4;
#pragma unroll
  for (int i = 0; i < 4; ++i) {
    float4 v = *(const float4*)(B + (size_t)(k0 + r + i * 16) * N + n0 + c4);
    tile[r + i * 16][c4 + 0] = v.x;
    tile[r + i * 16][c4 + 1] = v.y;
    tile[r + i * 16][c4 + 2] = v.z;
    tile[r + i * 16][c4 + 3] = v.w;
  }
  __syncthreads();
  const int nl = tid >> 3, kc = (tid & 7) * 8;
#pragma unroll
  for (int i = 0; i < 2; ++i) {
    const int n = nl + i * 32;
    short8 oh, ol;
#pragma unroll
    for (int e = 0; e < 8; ++e) {
      const float x = tile[kc + e][n];
      oh[e] = f2bf(x);
      ol[e] = f2bf(x - bf2f(oh[e]));
    }
    *(short8*)(Bth + (size_t)(n0 + n) * K + k0 + kc) = oh;
    *(short8*)(Btl + (size_t)(n0 + n) * K + k0 + kc) = ol;
  }
}

// ---------------- flat f32 -> bf16 cast ----------------
__global__ void cast_bf(const float* __restrict__ in, short* __restrict__ out, int n) {
  const int i = blockIdx.x * 256 + threadIdx.x;
  if (i < n) out[i] = f2bf(in[i]);
}

// ---------------- RMSNorm (fp32 + bf16 out) ----------------
__global__ __launch_bounds__(256) void rms_kernel(const float* __restrict__ in, int in_stride,
                                                  const float* __restrict__ w,
                                                  float* __restrict__ out,
                                                  short* __restrict__ out_bf, int C) {
  const int t = blockIdx.x, tid = threadIdx.x;
  const float* x = in + (size_t)t * in_stride;
  float ss = 0.f;
  for (int i = tid; i < C; i += 256) { float v = x[i]; ss = fmaf(v, v, ss); }
#pragma unroll
  for (int o = 32; o > 0; o >>= 1) ss += __shfl_xor(ss, o);
  __shared__ float red[4];
  if ((tid & 63) == 0) red[tid >> 6] = ss;
  __syncthreads();
  const float tot = red[0] + red[1] + red[2] + red[3];
  const float r = rsqrtf(tot / (float)C + 1e-6f);
  for (int i = tid; i < C; i += 256) {
    const float v = x[i] * r * w[i];
    out[(size_t)t * C + i] = v;
    out_bf[(size_t)t * C + i] = f2bf(v);
  }
}

// ---------------- LayerNorm in-place on (T,128) ----------------
__global__ __launch_bounds__(128) void ln_kernel(float* __restrict__ x,
                                                 const float* __restrict__ w,
                                                 const float* __restrict__ b) {
  const int t = blockIdx.x, i = threadIdx.x;
  float v = x[(size_t)t * 128 + i];
  float s = v;
#pragma unroll
  for (int o = 32; o > 0; o >>= 1) s += __shfl_xor(s, o);
  __shared__ float r1[2], r2[2];
  if ((i & 63) == 0) r1[i >> 6] = s;
  __syncthreads();
  const float m = (r1[0] + r1[1]) * (1.f / 128.f);
  const float dv = v - m;
  float sq = dv * dv;
#pragma unroll
  for (int o = 32; o > 0; o >>= 1) sq += __shfl_xor(sq, o);
  if ((i & 63) == 0) r2[i >> 6] = sq;
  __syncthreads();
  const float var = (r2[0] + r2[1]) * (1.f / 128.f);
  x[(size_t)t * 128 + i] = dv * rsqrtf(var + 1e-6f) * w[i] + b[i];
}

// ---------------- RoPE (interleaved pairs), fp32 ----------------
__global__ void rope_kernel(const float* __restrict__ src, int s_ts, int s_hs,
                            float* __restrict__ dst, int d_ts, int d_hs,
                            const int* __restrict__ pos) {
  const int t = blockIdx.x, h = blockIdx.y, i = threadIdx.x;
  const float* s = src + (size_t)t * s_ts + (size_t)h * s_hs;
  float* d = dst + (size_t)t * d_ts + (size_t)h * d_hs;
  const float x1 = s[2 * i], x2 = s[2 * i + 1];
  const float inv = powf(10000.f, -(float)i * (1.f / 32.f));
  const float ang = (float)pos[t] * inv;
  float sn, cs;
  sincosf(ang, &sn, &cs);
  d[2 * i]     = x1 * cs - x2 * sn;
  d[2 * i + 1] = x1 * sn + x2 * cs;
}

// ---------------- q rope + repack: qbuf[q][h][192] bf16 -> qh[h][q][192] ----------------
__global__ void q_rope_repack(const short* __restrict__ qbuf,
                              short* __restrict__ qhout,
                              const int* __restrict__ pos) {
  const int q = blockIdx.x, h = blockIdx.y;
  const int p = threadIdx.x;  // 96 pairs
  const short* s = qbuf + ((size_t)q * 32 + h) * 192;
  short* d = qhout + ((size_t)h * 1024 + q) * 192;
  float x1 = bf2f(s[2 * p]), x2 = bf2f(s[2 * p + 1]);
  if (p >= 64) {
    const int i = p - 64;
    const float inv = powf(10000.f, -(float)i * (1.f / 32.f));
    const float ang = (float)pos[q] * inv;
    float sn, cs;
    sincosf(ang, &sn, &cs);
    const float a = x1 * cs - x2 * sn, b = x1 * sn + x2 * cs;
    x1 = a; x2 = b;
  }
  d[2 * p]     = f2bf(x1);
  d[2 * p + 1] = f2bf(x2);
}

// ---------------- qi repack + split: qib[q][32][128] f32 -> qih_hi/lo [32][q][128] ----------------
__global__ __launch_bounds__(256) void qi_repack_split(const float* __restrict__ qib,
                                                       short* __restrict__ qhh,
                                                       short* __restrict__ qhl) {
  const int qt = blockIdx.x, h = blockIdx.y;
  const int tid = threadIdx.x;
#pragma unroll
  for (int i = 0; i < 8; ++i) {
    const int idx = tid + i * 256;           // 2048 float4 chunks
    const int q = idx >> 5, c = idx & 31;
    float4 v = *(const float4*)(qib + ((size_t)(qt * 64 + q) * 32 + h) * 128 + c * 4);
    float av[4] = {v.x, v.y, v.z, v.w};
    short4v hv, lv;
#pragma unroll
    for (int e = 0; e < 4; ++e) {
      hv[e] = f2bf(av[e]);
      lv[e] = f2bf(av[e] - bf2f(hv[e]));
    }
    const size_t off = ((size_t)h * 1024 + qt * 64 + q) * 128 + c * 4;
    *(short4v*)(qhh + off) = hv;
    *(short4v*)(qhl + off) = lv;
  }
}

// ---------------- kv repack: kvbuf[k][32][256] + kpe[k][64] -> kf[32][k][192], vt[32][128][1024] --------
__global__ __launch_bounds__(256) void kv_repack(const short* __restrict__ kvb,
                                                 const short* __restrict__ kpe,
                                                 short* __restrict__ kfout,
                                                 short* __restrict__ vtout) {
  const int kt = blockIdx.x, h = blockIdx.y;
  const int tid = threadIdx.x;
  const int k0 = kt * 64;
  __shared__ short vtile[64][136];
#pragma unroll
  for (int i = 0; i < 6; ++i) {
    const int idx = tid + i * 256;           // 1536 chunks
    const int row = idx / 24, c = idx - row * 24;
    short8 v = (c < 16) ? *(const short8*)(kvb + ((size_t)(k0 + row) * 32 + h) * 256 + c * 8)
                        : *(const short8*)(kpe + (size_t)(k0 + row) * 64 + (c - 16) * 8);
    *(short8*)(kfout + ((size_t)h * 1024 + k0 + row) * 192 + c * 8) = v;
  }
#pragma unroll
  for (int i = 0; i < 4; ++i) {
    const int idx = tid + i * 256;           // 1024 chunks
    const int row = idx >> 4, c = idx & 15;
    *(short8*)&vtile[row][c * 8] =
        *(const short8*)(kvb + ((size_t)(k0 + row) * 32 + h) * 256 + 128 + c * 8);
  }
  __syncthreads();
#pragma unroll
  for (int i = 0; i < 4; ++i) {
    const int idx = tid + i * 256;           // 1024 chunks
    const int d = idx >> 3, kc = idx & 7;
    short8 o;
#pragma unroll
    for (int e = 0; e < 8; ++e) o[e] = vtile[kc * 8 + e][d];
    *(short8*)(vtout + ((size_t)h * 128 + d) * 1024 + k0 + kc * 8) = o;
  }
}

// ---------------- MFMA indexer logits (bf16x3, 8 heads per z) ----------------
__global__ __launch_bounds__(256) void logits_mfma(const short* __restrict__ qih,
                                                   const short* __restrict__ qil,
                                                   const float* __restrict__ ki,
                                                   const float* __restrict__ wts,
                                                   float* __restrict__ part) {
  const int bk = blockIdx.x, bq = blockIdx.y, g = blockIdx.z;
  if (bk > bq) return;
  __shared__ short kih[64 * 136], kil[64 * 136];
  __shared__ float swts[64][8];
  const int tid = threadIdx.x;
  const int lane = tid & 63, wv = tid >> 6;
  const int wr = (wv >> 1) * 32, wc = (wv & 1) * 32;
  const int l15 = lane & 15, l4 = lane >> 4;
  const int q0 = bq * 64, k0 = bk * 64;
  {
    const int row = tid >> 2, seg = (tid & 3) * 32;
#pragma unroll
    for (int c = 0; c < 32; c += 8) {
      const float* kp = ki + (size_t)(k0 + row) * 128 + seg + c;
      float4 v0 = *(const float4*)kp;
      float4 v1 = *(const float4*)(kp + 4);
      float av[8] = {v0.x, v0.y, v0.z, v0.w, v1.x, v1.y, v1.z, v1.w};
      short8 h8, l8;
#pragma unroll
      for (int e = 0; e < 8; ++e) {
        h8[e] = f2bf(av[e]);
        l8[e] = f2bf(av[e] - bf2f(h8[e]));
      }
      *(short8*)&kih[row * 136 + seg + c] = h8;
      *(short8*)&kil[row * 136 + seg + c] = l8;
    }
  }
#pragma unroll
  for (int i = 0; i < 2; ++i) {
    const int idx = tid + i * 256;  // 512 entries
    swts[idx >> 3][idx & 7] = wts[(size_t)(q0 + (idx >> 3)) * 32 + g * 8 + (idx & 7)];
  }
  __syncthreads();
  short8 kbh[2][4], kbl[2][4];
#pragma unroll
  for (int ct = 0; ct < 2; ++ct)
#pragma unroll
    for (int ks = 0; ks < 4; ++ks) {
      kbh[ct][ks] = *(const short8*)&kih[(wc + ct * 16 + l15) * 136 + ks * 32 + l4 * 8];
      kbl[ct][ks] = *(const short8*)&kil[(wc + ct * 16 + l15) * 136 + ks * 32 + l4 * 8];
    }
  f32x4 lacc[2][2];
#pragma unroll
  for (int i = 0; i < 2; ++i)
#pragma unroll
    for (int j = 0; j < 2; ++j) lacc[i][j] = f32x4{0.f, 0.f, 0.f, 0.f};
  for (int hh = 0; hh < 8; ++hh) {
    const int h = g * 8 + hh;
    short8 qah[2][4], qal[2][4];
#pragma unroll
    for (int rt = 0; rt < 2; ++rt)
#pragma unroll
      for (int ks = 0; ks < 4; ++ks) {
        const size_t off = ((size_t)h * 1024 + q0 + wr + rt * 16 + l15) * 128 + ks * 32 + l4 * 8;
        qah[rt][ks] = *(const short8*)(qih + off);
        qal[rt][ks] = *(const short8*)(qil + off);
      }
    f32x4 hacc[2][2];
#pragma unroll
    for (int i = 0; i < 2; ++i)
#pragma unroll
      for (int j = 0; j < 2; ++j) hacc[i][j] = f32x4{0.f, 0.f, 0.f, 0.f};
#pragma unroll
    for (int ks = 0; ks < 4; ++ks)
#pragma unroll
      for (int rt = 0; rt < 2; ++rt)
#pragma unroll
        for (int ct = 0; ct < 2; ++ct) {
          hacc[rt][ct] = __builtin_amdgcn_mfma_f32_16x16x32_bf16(qah[rt][ks], kbh[ct][ks], hacc[rt][ct], 0, 0, 0);
          hacc[rt][ct] = __builtin_amdgcn_mfma_f32_16x16x32_bf16(qah[rt][ks], kbl[ct][ks], hacc[rt][ct], 0, 0, 0);
          hacc[rt][ct] = __builtin_amdgcn_mfma_f32_16x16x32_bf16(qal[rt][ks], kbh[ct][ks], hacc[rt][ct], 0, 0, 0);
        }
#pragma unroll
    for (int rt = 0; rt < 2; ++rt)
#pragma unroll
      for (int ct = 0; ct < 2; ++ct)
#pragma unroll
        for (int r = 0; r < 4; ++r) {
          const int row = wr + rt * 16 + l4 * 4 + r;
          const float w = swts[row][hh] * kWtsScale;
          lacc[rt][ct][r] = fmaf(w, fmaxf(hacc[rt][ct][r], 0.f), lacc[rt][ct][r]);
        }
  }
#pragma unroll
  for (int rt = 0; rt < 2; ++rt)
#pragma unroll
    for (int ct = 0; ct < 2; ++ct)
#pragma unroll
      for (int r = 0; r < 4; ++r)
        part[(size_t)g * TT * TT + (size_t)(q0 + wr + rt * 16 + l4 * 4 + r) * TT +
             (k0 + wc + ct * 16 + l15)] = lacc[rt][ct][r];
}

// ---------------- top-512 -> bitmask ----------------
__global__ __launch_bounds__(256) void topk_mask(const float* __restrict__ part,
                                                 unsigned* __restrict__ maskbuf) {
  const int q = blockIdx.x, tid = threadIdx.x;
  __shared__ unsigned u[TT];
  __shared__ unsigned char sel[TT];
  __shared__ int redi[4];
  const size_t NN = (size_t)TT * TT;
  for (int k = tid; k < TT; k += 256) {
    unsigned uv = 0u;
    if (k <= q) {
      const size_t o = (size_t)q * TT + k;
      const float s = part[o] + part[NN + o] + part[2 * NN + o] + part[3 * NN + o];
      unsigned bb = __float_as_uint(s);
      uv = (bb & 0x80000000u) ? ~bb : (bb | 0x80000000u);
    }
    u[k] = uv;
    sel[k] = 0;
  }
  __syncthreads();
  const int n = q + 1;
  if (n <= TOPKK) {
    if (tid < 32) {
      const int base = tid * 32;
      unsigned word = 0u;
      if (base + 31 <= q) word = 0xffffffffu;
      else if (base <= q) word = 0xffffffffu >> (31 - (q - base));
      maskbuf[(size_t)q * 32 + tid] = word;
    }
    return;
  }
  unsigned lo = 1u, hi = 0xFFFFFFFFu;
  while (lo < hi) {
    const unsigned mid = lo + ((hi - lo) >> 1) + ((hi - lo) & 1u);
    int c = 0;
    for (int k = tid; k < TT; k += 256) c += (u[k] >= mid) ? 1 : 0;
#pragma unroll
    for (int o = 32; o > 0; o >>= 1) c += __shfl_down(c, o);
    if ((tid & 63) == 0) redi[tid >> 6] = c;
    __syncthreads();
    const int ctot = redi[0] + redi[1] + redi[2] + redi[3];
    __syncthreads();
    if (ctot >= TOPKK) lo = mid; else hi = mid - 1u;
  }
  const unsigned ustar = lo;
  int c = 0;
  for (int k = tid; k < TT; k += 256) c += (u[k] > ustar) ? 1 : 0;
#pragma unroll
  for (int o = 32; o > 0; o >>= 1) c += __shfl_down(c, o);
  if ((tid & 63) == 0) redi[tid >> 6] = c;
  __syncthreads();
  const int nGreater = redi[0] + redi[1] + redi[2] + redi[3];
  for (int k = tid; k < TT; k += 256) sel[k] = (u[k] > ustar) ? 1 : 0;
  __syncthreads();
  if (tid == 0) {
    int need = TOPKK - nGreater;
    for (int k = 0; k <= q && need > 0; ++k)
      if (u[k] == ustar) { sel[k] = 1; --need; }
  }
  __syncthreads();
  if (tid < 32) {
    unsigned word = 0u;
#pragma unroll
    for (int b = 0; b < 32; ++b) word |= ((unsigned)sel[tid * 32 + b]) << b;
    maskbuf[(size_t)q * 32 + tid] = word;
  }
}

// ---------------- masked dense MFMA attention ----------------
// grid (h=32, yy=16 balanced-swizzled q-tiles of 64); 4 waves, wave = 16 q rows.
__global__ __launch_bounds__(256) void attn_mfma(const short* __restrict__ qh,
                                                 const short* __restrict__ kf,
                                                 const short* __restrict__ vt,
                                                 const unsigned* __restrict__ maskbuf,
                                                 short* __restrict__ ao) {
  const int h = blockIdx.x;
  const int yy = blockIdx.y;
  const int qt = (yy < 8) ? (yy * 2) : (31 - yy * 2);  // pair light+heavy tiles per CU
  const int tid = threadIdx.x;
  const int lane = tid & 63, w = tid >> 6;
  const int l15 = lane & 15, l4 = lane >> 4;
  const int q0 = qt * 64;
  __shared__ short kfs[64 * 200];
  __shared__ short vts[128 * 72];
  __shared__ short ps[4][16][72];
  __shared__ unsigned m32s[64][2];
  short8 qf[6];
#pragma unroll
  for (int ks = 0; ks < 6; ++ks)
    qf[ks] = *(const short8*)(qh + ((size_t)h * 1024 + q0 + w * 16 + l15) * 192 + ks * 32 + l4 * 8);
  f32x4 of[8];
#pragma unroll
  for (int dt = 0; dt < 8; ++dt) of[dt] = f32x4{0.f, 0.f, 0.f, 0.f};
  float m[4], l[4];
#pragma unroll
  for (int r = 0; r < 4; ++r) { m[r] = -INFINITY; l[r] = 0.f; }

  for (int kt = 0; kt <= qt; ++kt) {
    const int k0 = kt * 64;
    __syncthreads();
#pragma unroll
    for (int i = 0; i < 6; ++i) {
      const int idx = tid + i * 256;
      const int row = idx / 24, c = idx - row * 24;
      *(short8*)&kfs[row * 200 + c * 8] =
          *(const short8*)(kf + ((size_t)h * 1024 + k0 + row) * 192 + c * 8);
    }
#pragma unroll
    for (int i = 0; i < 4; ++i) {
      const int idx = tid + i * 256;
      const int row = idx >> 3, c = idx & 7;
      *(short8*)&vts[row * 72 + c * 8] =
          *(const short8*)(vt + ((size_t)h * 128 + row) * 1024 + k0 + c * 8);
    }
    if (tid < 128)
      m32s[tid >> 1][tid & 1] = maskbuf[(size_t)(q0 + (tid >> 1)) * 32 + (k0 >> 5) + (tid & 1)];
    __syncthreads();
    // QK^T
    f32x4 sacc[4];
#pragma unroll
    for (int j = 0; j < 4; ++j) sacc[j] = f32x4{0.f, 0.f, 0.f, 0.f};
#pragma unroll
    for (int ks = 0; ks < 6; ++ks)
#pragma unroll
      for (int j = 0; j < 4; ++j) {
        short8 kb = *(const short8*)&kfs[(j * 16 + l15) * 200 + ks * 32 + l4 * 8];
        sacc[j] = __builtin_amdgcn_mfma_f32_16x16x32_bf16(qf[ks], kb, sacc[j], 0, 0, 0);
      }
    // scale + mask
    float tmax[4] = {-INFINITY, -INFINITY, -INFINITY, -INFINITY};
#pragma unroll
    for (int j = 0; j < 4; ++j)
#pragma unroll
      for (int r = 0; r < 4; ++r) {
        const int kcol = j * 16 + l15;
        const unsigned um = m32s[w * 16 + l4 * 4 + r][kcol >> 5];
        float s = sacc[j][r] * kScaling;
        s = ((um >> (kcol & 31)) & 1u) ? s : -INFINITY;
        sacc[j][r] = s;
        tmax[r] = fmaxf(tmax[r], s);
      }
#pragma unroll
    for (int r = 0; r < 4; ++r) {
      tmax[r] = fmaxf(tmax[r], __shfl_xor(tmax[r], 1));
      tmax[r] = fmaxf(tmax[r], __shfl_xor(tmax[r], 2));
      tmax[r] = fmaxf(tmax[r], __shfl_xor(tmax[r], 4));
      tmax[r] = fmaxf(tmax[r], __shfl_xor(tmax[r], 8));
    }
    float f[4];
#pragma unroll
    for (int r = 0; r < 4; ++r) {
      const float mn = fmaxf(m[r], tmax[r]);
      f[r] = __expf(fmaxf(m[r], -1e30f) - fmaxf(mn, -1e30f));
      m[r] = mn;
      l[r] *= f[r];
    }
    // P = exp(S - m), row sums, store bf16
    float psum[4] = {0.f, 0.f, 0.f, 0.f};
#pragma unroll
    for (int j = 0; j < 4; ++j)
#pragma unroll
      for (int r = 0; r < 4; ++r) {
        const float p = __expf(sacc[j][r] - fmaxf(m[r], -1e30f));
        psum[r] += p;
        ps[w][l4 * 4 + r][j * 16 + l15] = f2bf(p);
      }
#pragma unroll
    for (int r = 0; r < 4; ++r) {
      psum[r] += __shfl_xor(psum[r], 1);
      psum[r] += __shfl_xor(psum[r], 2);
      psum[r] += __shfl_xor(psum[r], 4);
      psum[r] += __shfl_xor(psum[r], 8);
      l[r] += psum[r];
    }
#pragma unroll
    for (int dt = 0; dt < 8; ++dt)
#pragma unroll
      for (int r = 0; r < 4; ++r) of[dt][r] *= f[r];
    // PV
    short8 pa0 = *(const short8*)&ps[w][l15][l4 * 8];
    short8 pa1 = *(const short8*)&ps[w][l15][32 + l4 * 8];
#pragma unroll
    for (int dt = 0; dt < 8; ++dt) {
      short8 vb0 = *(const short8*)&vts[(dt * 16 + l15) * 72 + l4 * 8];
      short8 vb1 = *(const short8*)&vts[(dt * 16 + l15) * 72 + 32 + l4 * 8];
      of[dt] = __builtin_amdgcn_mfma_f32_16x16x32_bf16(pa0, vb0, of[dt], 0, 0, 0);
      of[dt] = __builtin_amdgcn_mfma_f32_16x16x32_bf16(pa1, vb1, of[dt], 0, 0, 0);
    }
  }
  // epilogue
#pragma unroll
  for (int r = 0; r < 4; ++r) {
    const float invl = 1.f / l[r];
#pragma unroll
    for (int dt = 0; dt < 8; ++dt)
      ao[(size_t)(q0 + w * 16 + l4 * 4 + r) * 4096 + h * 128 + dt * 16 + l15] =
          f2bf(of[dt][r] * invl);
  }
}

// ============================================================================
extern "C" void kernel_launch(void* const* d_in, const int* in_sizes, int n_in,
                              void* d_out, int out_size, void* d_ws, size_t ws_size,
                              hipStream_t stream) {
  const float* hidden     = (const float*)d_in[0];
  const int*   positions  = (const int*)d_in[1];
  const float* w_qkv_a    = (const float*)d_in[2];
  const float* q_a_ln_w   = (const float*)d_in[3];
  const float* w_q_b      = (const float*)d_in[4];
  const float* kv_a_ln_w  = (const float*)d_in[5];
  const float* w_kv_b     = (const float*)d_in[6];
  const float* w_o        = (const float*)d_in[7];
  const float* w_idx_qb   = (const float*)d_in[8];
  const float* w_idx_k    = (const float*)d_in[9];
  const float* idx_k_ln_w = (const float*)d_in[10];
  const float* idx_k_ln_b = (const float*)d_in[11];
  const float* w_idx_w    = (const float*)d_in[12];
  float* out = (float*)d_out;

  float* ws = (float*)d_ws;
  size_t off = 0;
  auto take = [&](size_t n) { float* p = ws + off; off += n; return p; };
  float* qkv     = take((size_t)TT * 2112);
  float* qcn     = take((size_t)TT * QLL);
  short* qcn_bf  = (short*)take((size_t)TT * QLL / 2);
  float* kvn     = take((size_t)TT * KLL);
  short* kvn_bf  = (short*)take((size_t)TT * KLL / 2);
  short* qbuf    = (short*)take((size_t)TT * NHH * 192 / 2);   // bf16 [q][h][192]
  short* kvbuf   = (short*)take((size_t)TT * NHH * 256 / 2);   // bf16 [k][h][256]
  float* kpe     = take((size_t)TT * 64);
  short* kpe_bf  = (short*)take((size_t)TT * 32);
  float* qib     = take((size_t)TT * INHH * IHDD);             // fp32 [q][32][128]
  float* kib     = take((size_t)TT * IHDD);
  float* wtsb    = take((size_t)TT * INHH);
  short* qhb     = (short*)take((size_t)NHH * TT * 192 / 2);   // bf16 [h][q][192]
  short* qih_h   = (short*)take((size_t)INHH * TT * 128 / 2);
  short* qih_l   = (short*)take((size_t)INHH * TT * 128 / 2);
  short* kfb     = (short*)take((size_t)NHH * TT * 192 / 2);   // bf16 [h][k][192]
  short* vtb     = (short*)take((size_t)NHH * 128 * TT / 2);   // bf16 [h][d][k]
  float* part4   = take((size_t)4 * TT * TT);
  unsigned* maskbuf = (unsigned*)take((size_t)TT * 32);
  short* wqkva_h = (short*)take((size_t)2112 * HH / 2);
  short* wqkva_l = (short*)take((size_t)2112 * HH / 2);
  short* widxqb_h = (short*)take((size_t)HH * QLL / 2);
  short* widxqb_l = (short*)take((size_t)HH * QLL / 2);
  short* wqb_t   = (short*)take((size_t)6144 * QLL / 2);
  short* wkvb_t  = (short*)take((size_t)8192 * KLL / 2);
  short* ao   = (short*)part4;      // alias: part4 dead after topk
  short* wo_t = wqkva_h;            // alias: wqkva dead after qkv_a gemm (spans h+l)

  const dim3 blk(256);
  // weight prep (wqkva needed first; wo_t transposed later into its space)
  transpose_split_cast<<<dim3(2112 / 64, HH / 64), blk, 0, stream>>>(w_qkv_a, wqkva_h, wqkva_l, HH, 2112);
  transpose_split_cast<<<dim3(HH / 64, QLL / 64), blk, 0, stream>>>(w_idx_qb, widxqb_h, widxqb_l, QLL, HH);
  transpose_cast<<<dim3(6144 / 64, QLL / 64), blk, 0, stream>>>(w_q_b, wqb_t, QLL, 6144);
  transpose_cast<<<dim3(8192 / 64, KLL / 64), blk, 0, stream>>>(w_kv_b, wkvb_t, KLL, 8192);
  // qkv_a (bf16x3: topk-critical precision)
  gemm_bf16x3<<<dim3(17, 16), blk, 0, stream>>>(hidden, wqkva_h, wqkva_l, qkv, TT, 2112, HH);
  // w_o transpose AFTER qkv_a gemm (aliases wqkva)
  transpose_cast<<<dim3(HH / 64, HH / 64), blk, 0, stream>>>(w_o, wo_t, HH, HH);
  // norms
  rms_kernel<<<TT, 256, 0, stream>>>(qkv, 2112, q_a_ln_w, qcn, qcn_bf, QLL);
  rms_kernel<<<TT, 256, 0, stream>>>(qkv + 1536, 2112, kv_a_ln_w, kvn, kvn_bf, KLL);
  // projections
  gemm_bf16<__hip_bfloat16><<<dim3(48, 8), blk, 0, stream>>>(qcn_bf, wqb_t, (__hip_bfloat16*)qbuf, TT, 6144, QLL);
  gemm_bf16<__hip_bfloat16><<<dim3(64, 8), blk, 0, stream>>>(kvn_bf, wkvb_t, (__hip_bfloat16*)kvbuf, TT, 8192, KLL);
  gemm_bf16x3<<<dim3(32, 16), blk, 0, stream>>>(qcn, widxqb_h, widxqb_l, qib, TT, HH, QLL);
  gemm_f32<<<dim3(1, 16), blk, 0, stream>>>(hidden, w_idx_k, kib, TT, 128, HH);
  gemm_f32<<<dim3(1, 16), blk, 0, stream>>>(hidden, w_idx_w, wtsb, TT, 32, HH);
  // layernorm + RoPE
  ln_kernel<<<TT, 128, 0, stream>>>(kib, idx_k_ln_w, idx_k_ln_b);
  rope_kernel<<<dim3(TT, INHH), 32, 0, stream>>>(qib, INHH * IHDD, IHDD, qib, INHH * IHDD, IHDD, positions);
  rope_kernel<<<dim3(TT, 1), 32, 0, stream>>>(qkv + 2048, 2112, 0, kpe, 64, 0, positions);
  rope_kernel<<<dim3(TT, 1), 32, 0, stream>>>(kib, IHDD, 0, kib, IHDD, 0, positions);
  cast_bf<<<dim3(TT * 64 / 256), blk, 0, stream>>>(kpe, kpe_bf, TT * 64);
  // repacks
  q_rope_repack<<<dim3(TT, NHH), 96, 0, stream>>>(qbuf, qhb, positions);
  qi_repack_split<<<dim3(16, INHH), blk, 0, stream>>>(qib, qih_h, qih_l);
  kv_repack<<<dim3(16, NHH), blk, 0, stream>>>(kvbuf, kpe_bf, kfb, vtb);
  // indexer logits (MFMA bf16x3; fp8-quant cancels: relu(x/s)*(w*s)==relu(x)*w)
  logits_mfma<<<dim3(16, 16, 4), blk, 0, stream>>>(qih_h, qih_l, kib, wtsb, part4);
  // top-512 -> bitmask
  topk_mask<<<dim3(TT), blk, 0, stream>>>(part4, maskbuf);
  // masked dense MFMA attention
  attn_mfma<<<dim3(NHH, 16), blk, 0, stream>>>(qhb, kfb, vtb, maskbuf, ao);
  // output projection
  gemm_bf16<float><<<dim3(32, 8), blk, 0, stream>>>(ao, wo_t, out, TT, HH, NHH * DVV);
}

// Round 4
// 736.447 us; speedup vs baseline: 6.1386x; 2.4690x over previous
//
#include <hip/hip_runtime.h>
#include <hip/hip_bf16.h>
#include <math.h>
#include <type_traits>

#define TT   1024
#define HH   4096
#define NHH  32
#define DNN  128
#define DRR  64
#define DVV  128
#define QLL  1536
#define KLL  512
#define INHH 32
#define IHDD 128
#define TOPKK 512
#define SKS  16            // k-splits for skinny projections
#define SKC  (HH / SKS)    // 256 k per split

typedef __attribute__((ext_vector_type(8))) short short8;
typedef __attribute__((ext_vector_type(4))) short short4v;
typedef __attribute__((ext_vector_type(4))) float f32x4;

static __device__ __constant__ float kScaling = 0.07216878364870322f;  // (DN+DR)^-0.5
static __device__ __constant__ float kWtsScale = 0.015625f;            // IHD^-.5 * INH^-.5

static __device__ __forceinline__ short f2bf(float f) {
  unsigned u = __float_as_uint(f);
  unsigned r = (u + 0x7fffu + ((u >> 16) & 1u)) >> 16;  // RNE
  return (short)r;
}
static __device__ __forceinline__ float bf2f(short s) {
  return __uint_as_float(((unsigned)(unsigned short)s) << 16);
}

// ---------------- fused skinny split-K: [kib | wtsb] = hidden @ [w_idx_k | w_idx_w] --------
// grid (16 m-tiles, SKS k-splits); partials part[ks][1024][160].
__global__ __launch_bounds__(256) void skinny_splitk(const float* __restrict__ A,
                                                     const float* __restrict__ B1,
                                                     const float* __restrict__ B2,
                                                     float* __restrict__ part) {
  __shared__ float As[8][64];
  __shared__ float Bs[8][160];
  const int tid = threadIdx.x;
  const int tx = tid & 15, ty = tid >> 4;
  const int bm = blockIdx.x * 64;
  const int kbase = blockIdx.y * SKC;
  float acc[4][10];
#pragma unroll
  for (int i = 0; i < 4; ++i)
#pragma unroll
    for (int j = 0; j < 10; ++j) acc[i][j] = 0.f;
  const int am = tid >> 1, aj = (tid & 1) * 4;
  for (int k0 = 0; k0 < SKC; k0 += 8) {
    __syncthreads();
    if (tid < 128) {
      float4 av = *(const float4*)(A + (size_t)(bm + am) * HH + kbase + k0 + aj);
      As[aj + 0][am] = av.x; As[aj + 1][am] = av.y;
      As[aj + 2][am] = av.z; As[aj + 3][am] = av.w;
    }
#pragma unroll
    for (int i = 0; i < 2; ++i) {
      const int idx = tid + i * 256;
      if (idx < 320) {
        const int row = idx / 40;
        const int c = (idx - row * 40) * 4;
        float4 bv;
        if (c < 128) bv = *(const float4*)(B1 + (size_t)(kbase + k0 + row) * 128 + c);
        else         bv = *(const float4*)(B2 + (size_t)(kbase + k0 + row) * 32 + (c - 128));
        *(float4*)&Bs[row][c] = bv;
      }
    }
    __syncthreads();
#pragma unroll
    for (int p = 0; p < 8; ++p) {
      float av[4];
#pragma unroll
      for (int i = 0; i < 4; ++i) av[i] = As[p][ty * 4 + i];
      float bv[10];
#pragma unroll
      for (int j = 0; j < 10; ++j) bv[j] = Bs[p][tx * 10 + j];
#pragma unroll
      for (int i = 0; i < 4; ++i)
#pragma unroll
        for (int j = 0; j < 10; ++j) acc[i][j] = fmaf(av[i], bv[j], acc[i][j]);
    }
  }
  float* dst = part + ((size_t)blockIdx.y * TT + bm) * 160;
#pragma unroll
  for (int i = 0; i < 4; ++i)
#pragma unroll
    for (int j = 0; j < 10; ++j)
      dst[(size_t)(ty * 4 + i) * 160 + tx * 10 + j] = acc[i][j];
}

// ---------------- deterministic split-K reduce ----------------
__global__ __launch_bounds__(256) void skinny_reduce(const float* __restrict__ part,
                                                     float* __restrict__ kib,
                                                     float* __restrict__ wtsb) {
  const int idx = blockIdx.x * 256 + threadIdx.x;  // 1024*160
  const int m = idx / 160, c = idx - m * 160;
  float s = 0.f;
#pragma unroll
  for (int ks = 0; ks < SKS; ++ks) s += part[((size_t)ks * TT + m) * 160 + c];
  if (c < 128) kib[(size_t)m * 128 + c] = s;
  else wtsb[(size_t)m * 32 + (c - 128)] = s;
}

// ---------------- plain bf16 MFMA GEMM: C = A @ Bt^T ----------------
template <typename CT>
__global__ __launch_bounds__(256) void gemm_bf16(const short* __restrict__ A,
                                                 const short* __restrict__ Bt,
                                                 CT* __restrict__ C,
                                                 int M, int N, int K) {
  __shared__ short As[128 * 72];
  __shared__ short Bs[128 * 72];
  const int tid = threadIdx.x;
  const int lane = tid & 63, wv = tid >> 6;
  const int wr = (wv >> 1) * 64, wc = (wv & 1) * 64;
  const int bm = blockIdx.y * 128, bn = blockIdx.x * 128;
  const int l15 = lane & 15, l4 = lane >> 4;
  f32x4 acc[4][4];
#pragma unroll
  for (int i = 0; i < 4; ++i)
#pragma unroll
    for (int j = 0; j < 4; ++j) acc[i][j] = f32x4{0.f, 0.f, 0.f, 0.f};
  for (int k0 = 0; k0 < K; k0 += 64) {
    __syncthreads();
#pragma unroll
    for (int i = 0; i < 4; ++i) {
      const int c = i * 256 + tid;
      const int m = c >> 3, kc = c & 7;
      short8 va = *(const short8*)(A + (size_t)(bm + m) * K + k0 + kc * 8);
      *(short8*)(&As[m * 72 + kc * 8]) = va;
      short8 vb = *(const short8*)(Bt + (size_t)(bn + m) * K + k0 + kc * 8);
      *(short8*)(&Bs[m * 72 + kc * 8]) = vb;
    }
    __syncthreads();
    short8 fa[4][2], fb[4][2];
#pragma unroll
    for (int f = 0; f < 4; ++f)
#pragma unroll
      for (int kk = 0; kk < 2; ++kk) {
        fa[f][kk] = *(const short8*)(&As[(wr + f * 16 + l15) * 72 + kk * 32 + l4 * 8]);
        fb[f][kk] = *(const short8*)(&Bs[(wc + f * 16 + l15) * 72 + kk * 32 + l4 * 8]);
      }
#pragma unroll
    for (int kk = 0; kk < 2; ++kk)
#pragma unroll
      for (int i = 0; i < 4; ++i)
#pragma unroll
        for (int j = 0; j < 4; ++j)
          acc[i][j] = __builtin_amdgcn_mfma_f32_16x16x32_bf16(fa[i][kk], fb[j][kk], acc[i][j], 0, 0, 0);
  }
#pragma unroll
  for (int i = 0; i < 4; ++i)
#pragma unroll
    for (int j = 0; j < 4; ++j)
#pragma unroll
      for (int r = 0; r < 4; ++r) {
        const int row = bm + wr + i * 16 + l4 * 4 + r;
        const int col = bn + wc + j * 16 + l15;
        const float v = acc[i][j][r];
        if constexpr (std::is_same<CT, float>::value) C[(size_t)row * N + col] = v;
        else C[(size_t)row * N + col] = __float2bfloat16(v);
      }
}

// ---------------- bf16x3 split GEMM: C = A(f32) @ Bt^T (hi+lo) ----------------
__global__ __launch_bounds__(256) void gemm_bf16x3(const float* __restrict__ A,
                                                   const short* __restrict__ Bth,
                                                   const short* __restrict__ Btl,
                                                   float* __restrict__ C,
                                                   int M, int N, int K) {
  __shared__ short Ah[64 * 40], Al[64 * 40], Bh[128 * 40], Bl[128 * 40];
  const int tid = threadIdx.x;
  const int lane = tid & 63, wv = tid >> 6;
  const int wr = (wv >> 1) * 32, wc = (wv & 1) * 64;
  const int l15 = lane & 15, l4 = lane >> 4;
  const int bm = blockIdx.y * 64, bn = blockIdx.x * 128;
  f32x4 acc[2][4];
#pragma unroll
  for (int i = 0; i < 2; ++i)
#pragma unroll
    for (int j = 0; j < 4; ++j) acc[i][j] = f32x4{0.f, 0.f, 0.f, 0.f};
  const int arow = tid >> 2, aseg = (tid & 3) * 8;
  const int brow = tid >> 1, bseg = (tid & 1) * 16;
  const bool bok = (bn + brow) < N;
  for (int k0 = 0; k0 < K; k0 += 32) {
    __syncthreads();
    {
      const float* ap = A + (size_t)(bm + arow) * K + k0 + aseg;
      float4 a0 = *(const float4*)ap;
      float4 a1 = *(const float4*)(ap + 4);
      float av[8] = {a0.x, a0.y, a0.z, a0.w, a1.x, a1.y, a1.z, a1.w};
      short8 h8, l8;
#pragma unroll
      for (int e = 0; e < 8; ++e) {
        h8[e] = f2bf(av[e]);
        l8[e] = f2bf(av[e] - bf2f(h8[e]));
      }
      *(short8*)&Ah[arow * 40 + aseg] = h8;
      *(short8*)&Al[arow * 40 + aseg] = l8;
    }
    if (bok) {
      const short* sh = Bth + (size_t)(bn + brow) * K + k0 + bseg;
      const short* sl = Btl + (size_t)(bn + brow) * K + k0 + bseg;
      *(short8*)&Bh[brow * 40 + bseg]     = *(const short8*)sh;
      *(short8*)&Bh[brow * 40 + bseg + 8] = *(const short8*)(sh + 8);
      *(short8*)&Bl[brow * 40 + bseg]     = *(const short8*)sl;
      *(short8*)&Bl[brow * 40 + bseg + 8] = *(const short8*)(sl + 8);
    }
    __syncthreads();
    short8 fah[2], fal[2], fbh[4], fbl[4];
#pragma unroll
    for (int rt = 0; rt < 2; ++rt) {
      fah[rt] = *(const short8*)&Ah[(wr + rt * 16 + l15) * 40 + l4 * 8];
      fal[rt] = *(const short8*)&Al[(wr + rt * 16 + l15) * 40 + l4 * 8];
    }
#pragma unroll
    for (int ct = 0; ct < 4; ++ct) {
      fbh[ct] = *(const short8*)&Bh[(wc + ct * 16 + l15) * 40 + l4 * 8];
      fbl[ct] = *(const short8*)&Bl[(wc + ct * 16 + l15) * 40 + l4 * 8];
    }
#pragma unroll
    for (int rt = 0; rt < 2; ++rt)
#pragma unroll
      for (int ct = 0; ct < 4; ++ct) {
        acc[rt][ct] = __builtin_amdgcn_mfma_f32_16x16x32_bf16(fah[rt], fbh[ct], acc[rt][ct], 0, 0, 0);
        acc[rt][ct] = __builtin_amdgcn_mfma_f32_16x16x32_bf16(fah[rt], fbl[ct], acc[rt][ct], 0, 0, 0);
        acc[rt][ct] = __builtin_amdgcn_mfma_f32_16x16x32_bf16(fal[rt], fbh[ct], acc[rt][ct], 0, 0, 0);
      }
  }
#pragma unroll
  for (int rt = 0; rt < 2; ++rt)
#pragma unroll
    for (int ct = 0; ct < 4; ++ct)
#pragma unroll
      for (int r = 0; r < 4; ++r) {
        const int row = bm + wr + rt * 16 + l4 * 4 + r;
        const int col = bn + wc + ct * 16 + l15;
        if (col < N) C[(size_t)row * N + col] = acc[rt][ct][r];
      }
}

// ---------------- transpose + cast: B[K][N] f32 -> Bt[N][K] bf16 ----------------
__global__ __launch_bounds__(256) void transpose_cast(const float* __restrict__ B,
                                                      short* __restrict__ Bt,
                                                      int K, int N) {
  __shared__ float tile[64][65];
  const int tid = threadIdx.x;
  const int k0 = blockIdx.y * 64, n0 = blockIdx.x * 64;
  const int r = tid >> 4, c4 = (tid & 15) * 4;
#pragma unroll
  for (int i = 0; i < 4; ++i) {
    float4 v = *(const float4*)(B + (size_t)(k0 + r + i * 16) * N + n0 + c4);
    tile[r + i * 16][c4 + 0] = v.x;
    tile[r + i * 16][c4 + 1] = v.y;
    tile[r + i * 16][c4 + 2] = v.z;
    tile[r + i * 16][c4 + 3] = v.w;
  }
  __syncthreads();
  const int nl = tid >> 3, kc = (tid & 7) * 8;
#pragma unroll
  for (int i = 0; i < 2; ++i) {
    const int n = nl + i * 32;
    short8 o;
#pragma unroll
    for (int e = 0; e < 8; ++e) o[e] = f2bf(tile[kc + e][n]);
    *(short8*)(Bt + (size_t)(n0 + n) * K + k0 + kc) = o;
  }
}

// ---------------- transpose + split cast (hi/lo) ----------------
__global__ __launch_bounds__(256) void transpose_split_cast(const float* __restrict__ B,
                                                            short* __restrict__ Bth,
                                                            short* __restrict__ Btl,
                                                            int K, int N) {
  __shared__ float tile[64][65];
  const int tid = threadIdx.x;
  const int k0 = blockIdx.y * 64, n0 = blockIdx.x * 64;
  const int r = tid >> 4, c4 = (tid & 15) * 4;
#pragma unroll
  for (int i = 0; i < 4; ++i) {
    float4 v = *(const float4*)(B + (size_t)(k0 + r + i * 16) * N + n0 + c4);
    tile[r + i * 16][c4 + 0] = v.x;
    tile[r + i * 16][c4 + 1] = v.y;
    tile[r + i * 16][c4 + 2] = v.z;
    tile[r + i * 16][c4 + 3] = v.w;
  }
  __syncthreads();
  const int nl = tid >> 3, kc = (tid & 7) * 8;
#pragma unroll
  for (int i = 0; i < 2; ++i) {
    const int n = nl + i * 32;
    short8 oh, ol;
#pragma unroll
    for (int e = 0; e < 8; ++e) {
      const float x = tile[kc + e][n];
      oh[e] = f2bf(x);
      ol[e] = f2bf(x - bf2f(oh[e]));
    }
    *(short8*)(Bth + (size_t)(n0 + n) * K + k0 + kc) = oh;
    *(short8*)(Btl + (size_t)(n0 + n) * K + k0 + kc) = ol;
  }
}

// ---------------- flat f32 -> bf16 cast ----------------
__global__ void cast_bf(const float* __restrict__ in, short* __restrict__ out, int n) {
  const int i = blockIdx.x * 256 + threadIdx.x;
  if (i < n) out[i] = f2bf(in[i]);
}

// ---------------- RMSNorm (fp32 + bf16 out) ----------------
__global__ __launch_bounds__(256) void rms_kernel(const float* __restrict__ in, int in_stride,
                                                  const float* __restrict__ w,
                                                  float* __restrict__ out,
                                                  short* __restrict__ out_bf, int C) {
  const int t = blockIdx.x, tid = threadIdx.x;
  const float* x = in + (size_t)t * in_stride;
  float ss = 0.f;
  for (int i = tid; i < C; i += 256) { float v = x[i]; ss = fmaf(v, v, ss); }
#pragma unroll
  for (int o = 32; o > 0; o >>= 1) ss += __shfl_xor(ss, o);
  __shared__ float red[4];
  if ((tid & 63) == 0) red[tid >> 6] = ss;
  __syncthreads();
  const float tot = red[0] + red[1] + red[2] + red[3];
  const float r = rsqrtf(tot / (float)C + 1e-6f);
  for (int i = tid; i < C; i += 256) {
    const float v = x[i] * r * w[i];
    out[(size_t)t * C + i] = v;
    out_bf[(size_t)t * C + i] = f2bf(v);
  }
}

// ---------------- LayerNorm in-place on (T,128) ----------------
__global__ __launch_bounds__(128) void ln_kernel(float* __restrict__ x,
                                                 const float* __restrict__ w,
                                                 const float* __restrict__ b) {
  const int t = blockIdx.x, i = threadIdx.x;
  float v = x[(size_t)t * 128 + i];
  float s = v;
#pragma unroll
  for (int o = 32; o > 0; o >>= 1) s += __shfl_xor(s, o);
  __shared__ float r1[2], r2[2];
  if ((i & 63) == 0) r1[i >> 6] = s;
  __syncthreads();
  const float m = (r1[0] + r1[1]) * (1.f / 128.f);
  const float dv = v - m;
  float sq = dv * dv;
#pragma unroll
  for (int o = 32; o > 0; o >>= 1) sq += __shfl_xor(sq, o);
  if ((i & 63) == 0) r2[i >> 6] = sq;
  __syncthreads();
  const float var = (r2[0] + r2[1]) * (1.f / 128.f);
  x[(size_t)t * 128 + i] = dv * rsqrtf(var + 1e-6f) * w[i] + b[i];
}

// ---------------- RoPE (interleaved pairs), fp32 ----------------
__global__ void rope_kernel(const float* __restrict__ src, int s_ts, int s_hs,
                            float* __restrict__ dst, int d_ts, int d_hs,
                            const int* __restrict__ pos) {
  const int t = blockIdx.x, h = blockIdx.y, i = threadIdx.x;
  const float* s = src + (size_t)t * s_ts + (size_t)h * s_hs;
  float* d = dst + (size_t)t * d_ts + (size_t)h * d_hs;
  const float x1 = s[2 * i], x2 = s[2 * i + 1];
  const float inv = powf(10000.f, -(float)i * (1.f / 32.f));
  const float ang = (float)pos[t] * inv;
  float sn, cs;
  sincosf(ang, &sn, &cs);
  d[2 * i]     = x1 * cs - x2 * sn;
  d[2 * i + 1] = x1 * sn + x2 * cs;
}

// ---------------- q rope + repack: qbuf[q][h][192] bf16 -> qh[h][q][192] ----------------
__global__ void q_rope_repack(const short* __restrict__ qbuf,
                              short* __restrict__ qhout,
                              const int* __restrict__ pos) {
  const int q = blockIdx.x, h = blockIdx.y;
  const int p = threadIdx.x;  // 96 pairs
  const short* s = qbuf + ((size_t)q * 32 + h) * 192;
  short* d = qhout + ((size_t)h * 1024 + q) * 192;
  float x1 = bf2f(s[2 * p]), x2 = bf2f(s[2 * p + 1]);
  if (p >= 64) {
    const int i = p - 64;
    const float inv = powf(10000.f, -(float)i * (1.f / 32.f));
    const float ang = (float)pos[q] * inv;
    float sn, cs;
    sincosf(ang, &sn, &cs);
    const float a = x1 * cs - x2 * sn, b = x1 * sn + x2 * cs;
    x1 = a; x2 = b;
  }
  d[2 * p]     = f2bf(x1);
  d[2 * p + 1] = f2bf(x2);
}

// ---------------- qi repack + split: qib[q][32][128] f32 -> qih_hi/lo [32][q][128] ----------------
__global__ __launch_bounds__(256) void qi_repack_split(const float* __restrict__ qib,
                                                       short* __restrict__ qhh,
                                                       short* __restrict__ qhl) {
  const int qt = blockIdx.x, h = blockIdx.y;
  const int tid = threadIdx.x;
#pragma unroll
  for (int i = 0; i < 8; ++i) {
    const int idx = tid + i * 256;           // 2048 float4 chunks
    const int q = idx >> 5, c = idx & 31;
    float4 v = *(const float4*)(qib + ((size_t)(qt * 64 + q) * 32 + h) * 128 + c * 4);
    float av[4] = {v.x, v.y, v.z, v.w};
    short4v hv, lv;
#pragma unroll
    for (int e = 0; e < 4; ++e) {
      hv[e] = f2bf(av[e]);
      lv[e] = f2bf(av[e] - bf2f(hv[e]));
    }
    const size_t off = ((size_t)h * 1024 + qt * 64 + q) * 128 + c * 4;
    *(short4v*)(qhh + off) = hv;
    *(short4v*)(qhl + off) = lv;
  }
}

// ---------------- kv repack: kvbuf[k][32][256] + kpe[k][64] -> kf[32][k][192], vt[32][128][1024] --------
__global__ __launch_bounds__(256) void kv_repack(const short* __restrict__ kvb,
                                                 const short* __restrict__ kpe,
                                                 short* __restrict__ kfout,
                                                 short* __restrict__ vtout) {
  const int kt = blockIdx.x, h = blockIdx.y;
  const int tid = threadIdx.x;
  const int k0 = kt * 64;
  __shared__ short vtile[64][136];
#pragma unroll
  for (int i = 0; i < 6; ++i) {
    const int idx = tid + i * 256;           // 1536 chunks
    const int row = idx / 24, c = idx - row * 24;
    short8 v = (c < 16) ? *(const short8*)(kvb + ((size_t)(k0 + row) * 32 + h) * 256 + c * 8)
                        : *(const short8*)(kpe + (size_t)(k0 + row) * 64 + (c - 16) * 8);
    *(short8*)(kfout + ((size_t)h * 1024 + k0 + row) * 192 + c * 8) = v;
  }
#pragma unroll
  for (int i = 0; i < 4; ++i) {
    const int idx = tid + i * 256;           // 1024 chunks
    const int row = idx >> 4, c = idx & 15;
    *(short8*)&vtile[row][c * 8] =
        *(const short8*)(kvb + ((size_t)(k0 + row) * 32 + h) * 256 + 128 + c * 8);
  }
  __syncthreads();
#pragma unroll
  for (int i = 0; i < 4; ++i) {
    const int idx = tid + i * 256;           // 1024 chunks
    const int d = idx >> 3, kc = idx & 7;
    short8 o;
#pragma unroll
    for (int e = 0; e < 8; ++e) o[e] = vtile[kc * 8 + e][d];
    *(short8*)(vtout + ((size_t)h * 128 + d) * 1024 + k0 + kc * 8) = o;
  }
}

// ---------------- MFMA indexer logits (bf16x3, 8 heads per z) ----------------
__global__ __launch_bounds__(256) void logits_mfma(const short* __restrict__ qih,
                                                   const short* __restrict__ qil,
                                                   const float* __restrict__ ki,
                                                   const float* __restrict__ wts,
                                                   float* __restrict__ part) {
  const int bk = blockIdx.x, bq = blockIdx.y, g = blockIdx.z;
  if (bk > bq) return;
  __shared__ short kih[64 * 136], kil[64 * 136];
  __shared__ float swts[64][8];
  const int tid = threadIdx.x;
  const int lane = tid & 63, wv = tid >> 6;
  const int wr = (wv >> 1) * 32, wc = (wv & 1) * 32;
  const int l15 = lane & 15, l4 = lane >> 4;
  const int q0 = bq * 64, k0 = bk * 64;
  {
    const int row = tid >> 2, seg = (tid & 3) * 32;
#pragma unroll
    for (int c = 0; c < 32; c += 8) {
      const float* kp = ki + (size_t)(k0 + row) * 128 + seg + c;
      float4 v0 = *(const float4*)kp;
      float4 v1 = *(const float4*)(kp + 4);
      float av[8] = {v0.x, v0.y, v0.z, v0.w, v1.x, v1.y, v1.z, v1.w};
      short8 h8, l8;
#pragma unroll
      for (int e = 0; e < 8; ++e) {
        h8[e] = f2bf(av[e]);
        l8[e] = f2bf(av[e] - bf2f(h8[e]));
      }
      *(short8*)&kih[row * 136 + seg + c] = h8;
      *(short8*)&kil[row * 136 + seg + c] = l8;
    }
  }
#pragma unroll
  for (int i = 0; i < 2; ++i) {
    const int idx = tid + i * 256;  // 512 entries
    swts[idx >> 3][idx & 7] = wts[(size_t)(q0 + (idx >> 3)) * 32 + g * 8 + (idx & 7)];
  }
  __syncthreads();
  short8 kbh[2][4], kbl[2][4];
#pragma unroll
  for (int ct = 0; ct < 2; ++ct)
#pragma unroll
    for (int ks = 0; ks < 4; ++ks) {
      kbh[ct][ks] = *(const short8*)&kih[(wc + ct * 16 + l15) * 136 + ks * 32 + l4 * 8];
      kbl[ct][ks] = *(const short8*)&kil[(wc + ct * 16 + l15) * 136 + ks * 32 + l4 * 8];
    }
  f32x4 lacc[2][2];
#pragma unroll
  for (int i = 0; i < 2; ++i)
#pragma unroll
    for (int j = 0; j < 2; ++j) lacc[i][j] = f32x4{0.f, 0.f, 0.f, 0.f};
  for (int hh = 0; hh < 8; ++hh) {
    const int h = g * 8 + hh;
    short8 qah[2][4], qal[2][4];
#pragma unroll
    for (int rt = 0; rt < 2; ++rt)
#pragma unroll
      for (int ks = 0; ks < 4; ++ks) {
        const size_t off = ((size_t)h * 1024 + q0 + wr + rt * 16 + l15) * 128 + ks * 32 + l4 * 8;
        qah[rt][ks] = *(const short8*)(qih + off);
        qal[rt][ks] = *(const short8*)(qil + off);
      }
    f32x4 hacc[2][2];
#pragma unroll
    for (int i = 0; i < 2; ++i)
#pragma unroll
      for (int j = 0; j < 2; ++j) hacc[i][j] = f32x4{0.f, 0.f, 0.f, 0.f};
#pragma unroll
    for (int ks = 0; ks < 4; ++ks)
#pragma unroll
      for (int rt = 0; rt < 2; ++rt)
#pragma unroll
        for (int ct = 0; ct < 2; ++ct) {
          hacc[rt][ct] = __builtin_amdgcn_mfma_f32_16x16x32_bf16(qah[rt][ks], kbh[ct][ks], hacc[rt][ct], 0, 0, 0);
          hacc[rt][ct] = __builtin_amdgcn_mfma_f32_16x16x32_bf16(qah[rt][ks], kbl[ct][ks], hacc[rt][ct], 0, 0, 0);
          hacc[rt][ct] = __builtin_amdgcn_mfma_f32_16x16x32_bf16(qal[rt][ks], kbh[ct][ks], hacc[rt][ct], 0, 0, 0);
        }
#pragma unroll
    for (int rt = 0; rt < 2; ++rt)
#pragma unroll
      for (int ct = 0; ct < 2; ++ct)
#pragma unroll
        for (int r = 0; r < 4; ++r) {
          const int row = wr + rt * 16 + l4 * 4 + r;
          const float w = swts[row][hh] * kWtsScale;
          lacc[rt][ct][r] = fmaf(w, fmaxf(hacc[rt][ct][r], 0.f), lacc[rt][ct][r]);
        }
  }
#pragma unroll
  for (int rt = 0; rt < 2; ++rt)
#pragma unroll
    for (int ct = 0; ct < 2; ++ct)
#pragma unroll
      for (int r = 0; r < 4; ++r)
        part[(size_t)g * TT * TT + (size_t)(q0 + wr + rt * 16 + l4 * 4 + r) * TT +
             (k0 + wc + ct * 16 + l15)] = lacc[rt][ct][r];
}

// ---------------- top-512 -> bitmask ----------------
__global__ __launch_bounds__(256) void topk_mask(const float* __restrict__ part,
                                                 unsigned* __restrict__ maskbuf) {
  const int q = blockIdx.x, tid = threadIdx.x;
  __shared__ unsigned u[TT];
  __shared__ unsigned char sel[TT];
  __shared__ int redi[4];
  const size_t NN = (size_t)TT * TT;
  for (int k = tid; k < TT; k += 256) {
    unsigned uv = 0u;
    if (k <= q) {
      const size_t o = (size_t)q * TT + k;
      const float s = part[o] + part[NN + o] + part[2 * NN + o] + part[3 * NN + o];
      unsigned bb = __float_as_uint(s);
      uv = (bb & 0x80000000u) ? ~bb : (bb | 0x80000000u);
    }
    u[k] = uv;
    sel[k] = 0;
  }
  __syncthreads();
  const int n = q + 1;
  if (n <= TOPKK) {
    if (tid < 32) {
      const int base = tid * 32;
      unsigned word = 0u;
      if (base + 31 <= q) word = 0xffffffffu;
      else if (base <= q) word = 0xffffffffu >> (31 - (q - base));
      maskbuf[(size_t)q * 32 + tid] = word;
    }
    return;
  }
  unsigned lo = 1u, hi = 0xFFFFFFFFu;
  while (lo < hi) {
    const unsigned mid = lo + ((hi - lo) >> 1) + ((hi - lo) & 1u);
    int c = 0;
    for (int k = tid; k < TT; k += 256) c += (u[k] >= mid) ? 1 : 0;
#pragma unroll
    for (int o = 32; o > 0; o >>= 1) c += __shfl_down(c, o);
    if ((tid & 63) == 0) redi[tid >> 6] = c;
    __syncthreads();
    const int ctot = redi[0] + redi[1] + redi[2] + redi[3];
    __syncthreads();
    if (ctot >= TOPKK) lo = mid; else hi = mid - 1u;
  }
  const unsigned ustar = lo;
  int c = 0;
  for (int k = tid; k < TT; k += 256) c += (u[k] > ustar) ? 1 : 0;
#pragma unroll
  for (int o = 32; o > 0; o >>= 1) c += __shfl_down(c, o);
  if ((tid & 63) == 0) redi[tid >> 6] = c;
  __syncthreads();
  const int nGreater = redi[0] + redi[1] + redi[2] + redi[3];
  for (int k = tid; k < TT; k += 256) sel[k] = (u[k] > ustar) ? 1 : 0;
  __syncthreads();
  if (tid == 0) {
    int need = TOPKK - nGreater;
    for (int k = 0; k <= q && need > 0; ++k)
      if (u[k] == ustar) { sel[k] = 1; --need; }
  }
  __syncthreads();
  if (tid < 32) {
    unsigned word = 0u;
#pragma unroll
    for (int b = 0; b < 32; ++b) word |= ((unsigned)sel[tid * 32 + b]) << b;
    maskbuf[(size_t)q * 32 + tid] = word;
  }
}

// ---------------- masked dense MFMA attention ----------------
// grid (h=32, yy=16 balanced-swizzled q-tiles of 64); 4 waves, wave = 16 q rows.
__global__ __launch_bounds__(256) void attn_mfma(const short* __restrict__ qh,
                                                 const short* __restrict__ kf,
                                                 const short* __restrict__ vt,
                                                 const unsigned* __restrict__ maskbuf,
                                                 short* __restrict__ ao) {
  const int h = blockIdx.x;
  const int yy = blockIdx.y;
  const int qt = (yy < 8) ? (yy * 2) : (31 - yy * 2);  // pair light+heavy tiles per CU
  const int tid = threadIdx.x;
  const int lane = tid & 63, w = tid >> 6;
  const int l15 = lane & 15, l4 = lane >> 4;
  const int q0 = qt * 64;
  __shared__ short kfs[64 * 200];
  __shared__ short vts[128 * 72];
  __shared__ short ps[4][16][72];
  __shared__ unsigned m32s[64][2];
  short8 qf[6];
#pragma unroll
  for (int ks = 0; ks < 6; ++ks)
    qf[ks] = *(const short8*)(qh + ((size_t)h * 1024 + q0 + w * 16 + l15) * 192 + ks * 32 + l4 * 8);
  f32x4 of[8];
#pragma unroll
  for (int dt = 0; dt < 8; ++dt) of[dt] = f32x4{0.f, 0.f, 0.f, 0.f};
  float m[4], l[4];
#pragma unroll
  for (int r = 0; r < 4; ++r) { m[r] = -INFINITY; l[r] = 0.f; }

  for (int kt = 0; kt <= qt; ++kt) {
    const int k0 = kt * 64;
    __syncthreads();
#pragma unroll
    for (int i = 0; i < 6; ++i) {
      const int idx = tid + i * 256;
      const int row = idx / 24, c = idx - row * 24;
      *(short8*)&kfs[row * 200 + c * 8] =
          *(const short8*)(kf + ((size_t)h * 1024 + k0 + row) * 192 + c * 8);
    }
#pragma unroll
    for (int i = 0; i < 4; ++i) {
      const int idx = tid + i * 256;
      const int row = idx >> 3, c = idx & 7;
      *(short8*)&vts[row * 72 + c * 8] =
          *(const short8*)(vt + ((size_t)h * 128 + row) * 1024 + k0 + c * 8);
    }
    if (tid < 128)
      m32s[tid >> 1][tid & 1] = maskbuf[(size_t)(q0 + (tid >> 1)) * 32 + (k0 >> 5) + (tid & 1)];
    __syncthreads();
    // QK^T
    f32x4 sacc[4];
#pragma unroll
    for (int j = 0; j < 4; ++j) sacc[j] = f32x4{0.f, 0.f, 0.f, 0.f};
#pragma unroll
    for (int ks = 0; ks < 6; ++ks)
#pragma unroll
      for (int j = 0; j < 4; ++j) {
        short8 kb = *(const short8*)&kfs[(j * 16 + l15) * 200 + ks * 32 + l4 * 8];
        sacc[j] = __builtin_amdgcn_mfma_f32_16x16x32_bf16(qf[ks], kb, sacc[j], 0, 0, 0);
      }
    // scale + mask
    float tmax[4] = {-INFINITY, -INFINITY, -INFINITY, -INFINITY};
#pragma unroll
    for (int j = 0; j < 4; ++j)
#pragma unroll
      for (int r = 0; r < 4; ++r) {
        const int kcol = j * 16 + l15;
        const unsigned um = m32s[w * 16 + l4 * 4 + r][kcol >> 5];
        float s = sacc[j][r] * kScaling;
        s = ((um >> (kcol & 31)) & 1u) ? s : -INFINITY;
        sacc[j][r] = s;
        tmax[r] = fmaxf(tmax[r], s);
      }
#pragma unroll
    for (int r = 0; r < 4; ++r) {
      tmax[r] = fmaxf(tmax[r], __shfl_xor(tmax[r], 1));
      tmax[r] = fmaxf(tmax[r], __shfl_xor(tmax[r], 2));
      tmax[r] = fmaxf(tmax[r], __shfl_xor(tmax[r], 4));
      tmax[r] = fmaxf(tmax[r], __shfl_xor(tmax[r], 8));
    }
    float f[4];
#pragma unroll
    for (int r = 0; r < 4; ++r) {
      const float mn = fmaxf(m[r], tmax[r]);
      f[r] = __expf(fmaxf(m[r], -1e30f) - fmaxf(mn, -1e30f));
      m[r] = mn;
      l[r] *= f[r];
    }
    // P = exp(S - m), row sums, store bf16
    float psum[4] = {0.f, 0.f, 0.f, 0.f};
#pragma unroll
    for (int j = 0; j < 4; ++j)
#pragma unroll
      for (int r = 0; r < 4; ++r) {
        const float p = __expf(sacc[j][r] - fmaxf(m[r], -1e30f));
        psum[r] += p;
        ps[w][l4 * 4 + r][j * 16 + l15] = f2bf(p);
      }
#pragma unroll
    for (int r = 0; r < 4; ++r) {
      psum[r] += __shfl_xor(psum[r], 1);
      psum[r] += __shfl_xor(psum[r], 2);
      psum[r] += __shfl_xor(psum[r], 4);
      psum[r] += __shfl_xor(psum[r], 8);
      l[r] += psum[r];
    }
#pragma unroll
    for (int dt = 0; dt < 8; ++dt)
#pragma unroll
      for (int r = 0; r < 4; ++r) of[dt][r] *= f[r];
    // PV
    short8 pa0 = *(const short8*)&ps[w][l15][l4 * 8];
    short8 pa1 = *(const short8*)&ps[w][l15][32 + l4 * 8];
#pragma unroll
    for (int dt = 0; dt < 8; ++dt) {
      short8 vb0 = *(const short8*)&vts[(dt * 16 + l15) * 72 + l4 * 8];
      short8 vb1 = *(const short8*)&vts[(dt * 16 + l15) * 72 + 32 + l4 * 8];
      of[dt] = __builtin_amdgcn_mfma_f32_16x16x32_bf16(pa0, vb0, of[dt], 0, 0, 0);
      of[dt] = __builtin_amdgcn_mfma_f32_16x16x32_bf16(pa1, vb1, of[dt], 0, 0, 0);
    }
  }
  // epilogue
#pragma unroll
  for (int r = 0; r < 4; ++r) {
    const float invl = 1.f / l[r];
#pragma unroll
    for (int dt = 0; dt < 8; ++dt)
      ao[(size_t)(q0 + w * 16 + l4 * 4 + r) * 4096 + h * 128 + dt * 16 + l15] =
          f2bf(of[dt][r] * invl);
  }
}

// ============================================================================
extern "C" void kernel_launch(void* const* d_in, const int* in_sizes, int n_in,
                              void* d_out, int out_size, void* d_ws, size_t ws_size,
                              hipStream_t stream) {
  const float* hidden     = (const float*)d_in[0];
  const int*   positions  = (const int*)d_in[1];
  const float* w_qkv_a    = (const float*)d_in[2];
  const float* q_a_ln_w   = (const float*)d_in[3];
  const float* w_q_b      = (const float*)d_in[4];
  const float* kv_a_ln_w  = (const float*)d_in[5];
  const float* w_kv_b     = (const float*)d_in[6];
  const float* w_o        = (const float*)d_in[7];
  const float* w_idx_qb   = (const float*)d_in[8];
  const float* w_idx_k    = (const float*)d_in[9];
  const float* idx_k_ln_w = (const float*)d_in[10];
  const float* idx_k_ln_b = (const float*)d_in[11];
  const float* w_idx_w    = (const float*)d_in[12];
  float* out = (float*)d_out;

  float* ws = (float*)d_ws;
  size_t off = 0;
  auto take = [&](size_t n) { float* p = ws + off; off += n; return p; };
  float* qkv     = take((size_t)TT * 2112);
  float* qcn     = take((size_t)TT * QLL);
  short* qcn_bf  = (short*)take((size_t)TT * QLL / 2);
  float* kvn     = take((size_t)TT * KLL);
  short* kvn_bf  = (short*)take((size_t)TT * KLL / 2);
  short* qbuf    = (short*)take((size_t)TT * NHH * 192 / 2);   // bf16 [q][h][192]
  short* kvbuf   = (short*)take((size_t)TT * NHH * 256 / 2);   // bf16 [k][h][256]
  float* kpe     = take((size_t)TT * 64);
  short* kpe_bf  = (short*)take((size_t)TT * 32);
  float* qib     = take((size_t)TT * INHH * IHDD);             // fp32 [q][32][128]
  float* kib     = take((size_t)TT * IHDD);
  float* wtsb    = take((size_t)TT * INHH);
  short* qhb     = (short*)take((size_t)NHH * TT * 192 / 2);   // bf16 [h][q][192]
  short* qih_h   = (short*)take((size_t)INHH * TT * 128 / 2);
  short* qih_l   = (short*)take((size_t)INHH * TT * 128 / 2);
  short* kfb     = (short*)take((size_t)NHH * TT * 192 / 2);   // bf16 [h][k][192]
  short* vtb     = (short*)take((size_t)NHH * 128 * TT / 2);   // bf16 [h][d][k]
  float* part4   = take((size_t)4 * TT * TT);
  unsigned* maskbuf = (unsigned*)take((size_t)TT * 32);
  short* wqkva_h = (short*)take((size_t)2112 * HH / 2);
  short* wqkva_l = (short*)take((size_t)2112 * HH / 2);
  short* widxqb_h = (short*)take((size_t)HH * QLL / 2);
  short* widxqb_l = (short*)take((size_t)HH * QLL / 2);
  short* wqb_t   = (short*)take((size_t)6144 * QLL / 2);
  short* wkvb_t  = (short*)take((size_t)8192 * KLL / 2);
  short* ao   = (short*)part4;      // alias: part4 dead after topk
  short* wo_t = wqkva_h;            // alias: wqkva dead after qkv_a gemm (spans h+l)
  float* skpart = part4;            // alias: SKS*1024*160 = 2.62M floats < 4M (part4 not yet live)

  const dim3 blk(256);
  // fused skinny projections (kib | wtsb) via split-K — part4 space is free until logits
  skinny_splitk<<<dim3(16, SKS), blk, 0, stream>>>(hidden, w_idx_k, w_idx_w, skpart);
  skinny_reduce<<<dim3(TT * 160 / 256), blk, 0, stream>>>(skpart, kib, wtsb);
  // weight prep (wqkva needed first; wo_t transposed later into its space)
  transpose_split_cast<<<dim3(2112 / 64, HH / 64), blk, 0, stream>>>(w_qkv_a, wqkva_h, wqkva_l, HH, 2112);
  transpose_split_cast<<<dim3(HH / 64, QLL / 64), blk, 0, stream>>>(w_idx_qb, widxqb_h, widxqb_l, QLL, HH);
  transpose_cast<<<dim3(6144 / 64, QLL / 64), blk, 0, stream>>>(w_q_b, wqb_t, QLL, 6144);
  transpose_cast<<<dim3(8192 / 64, KLL / 64), blk, 0, stream>>>(w_kv_b, wkvb_t, KLL, 8192);
  // qkv_a (bf16x3: topk-critical precision)
  gemm_bf16x3<<<dim3(17, 16), blk, 0, stream>>>(hidden, wqkva_h, wqkva_l, qkv, TT, 2112, HH);
  // w_o transpose AFTER qkv_a gemm (aliases wqkva)
  transpose_cast<<<dim3(HH / 64, HH / 64), blk, 0, stream>>>(w_o, wo_t, HH, HH);
  // norms
  rms_kernel<<<TT, 256, 0, stream>>>(qkv, 2112, q_a_ln_w, qcn, qcn_bf, QLL);
  rms_kernel<<<TT, 256, 0, stream>>>(qkv + 1536, 2112, kv_a_ln_w, kvn, kvn_bf, KLL);
  // projections
  gemm_bf16<__hip_bfloat16><<<dim3(48, 8), blk, 0, stream>>>(qcn_bf, wqb_t, (__hip_bfloat16*)qbuf, TT, 6144, QLL);
  gemm_bf16<__hip_bfloat16><<<dim3(64, 8), blk, 0, stream>>>(kvn_bf, wkvb_t, (__hip_bfloat16*)kvbuf, TT, 8192, KLL);
  gemm_bf16x3<<<dim3(32, 16), blk, 0, stream>>>(qcn, widxqb_h, widxqb_l, qib, TT, HH, QLL);
  // layernorm + RoPE
  ln_kernel<<<TT, 128, 0, stream>>>(kib, idx_k_ln_w, idx_k_ln_b);
  rope_kernel<<<dim3(TT, INHH), 32, 0, stream>>>(qib, INHH * IHDD, IHDD, qib, INHH * IHDD, IHDD, positions);
  rope_kernel<<<dim3(TT, 1), 32, 0, stream>>>(qkv + 2048, 2112, 0, kpe, 64, 0, positions);
  rope_kernel<<<dim3(TT, 1), 32, 0, stream>>>(kib, IHDD, 0, kib, IHDD, 0, positions);
  cast_bf<<<dim3(TT * 64 / 256), blk, 0, stream>>>(kpe, kpe_bf, TT * 64);
  // repacks
  q_rope_repack<<<dim3(TT, NHH), 96, 0, stream>>>(qbuf, qhb, positions);
  qi_repack_split<<<dim3(16, INHH), blk, 0, stream>>>(qib, qih_h, qih_l);
  kv_repack<<<dim3(16, NHH), blk, 0, stream>>>(kvbuf, kpe_bf, kfb, vtb);
  // indexer logits (MFMA bf16x3; fp8-quant cancels: relu(x/s)*(w*s)==relu(x)*w)
  logits_mfma<<<dim3(16, 16, 4), blk, 0, stream>>>(qih_h, qih_l, kib, wtsb, part4);
  // top-512 -> bitmask
  topk_mask<<<dim3(TT), blk, 0, stream>>>(part4, maskbuf);
  // masked dense MFMA attention
  attn_mfma<<<dim3(NHH, 16), blk, 0, stream>>>(qhb, kfb, vtb, maskbuf, ao);
  // output projection
  gemm_bf16<float><<<dim3(32, 8), blk, 0, stream>>>(ao, wo_t, out, TT, HH, NHH * DVV);
}

// Round 5
// 705.705 us; speedup vs baseline: 6.4060x; 1.0436x over previous
//
#include <hip/hip_runtime.h>
#include <hip/hip_bf16.h>
#include <math.h>
#include <type_traits>

#define TT   1024
#define HH   4096
#define NHH  32
#define DNN  128
#define DRR  64
#define DVV  128
#define QLL  1536
#define KLL  512
#define INHH 32
#define IHDD 128
#define TOPKK 512
#define SKS  16            // k-splits for skinny projections
#define SKC  (HH / SKS)    // 256 k per split
#define QKVN 2112
#define QKVNP 2176         // padded to 17*128

typedef __attribute__((ext_vector_type(8))) short short8;
typedef __attribute__((ext_vector_type(4))) short short4v;
typedef __attribute__((ext_vector_type(4))) float f32x4;

static __device__ __constant__ float kScaling = 0.07216878364870322f;  // (DN+DR)^-0.5
static __device__ __constant__ float kWtsScale = 0.015625f;            // IHD^-.5 * INH^-.5

static __device__ __forceinline__ short f2bf(float f) {
  unsigned u = __float_as_uint(f);
  unsigned r = (u + 0x7fffu + ((u >> 16) & 1u)) >> 16;  // RNE
  return (short)r;
}
static __device__ __forceinline__ float bf2f(short s) {
  return __uint_as_float(((unsigned)(unsigned short)s) << 16);
}

// ---------------- fused skinny split-K: [kib | wtsb] = hidden @ [w_idx_k | w_idx_w] --------
__global__ __launch_bounds__(256) void skinny_splitk(const float* __restrict__ A,
                                                     const float* __restrict__ B1,
                                                     const float* __restrict__ B2,
                                                     float* __restrict__ part) {
  __shared__ float As[8][64];
  __shared__ float Bs[8][160];
  const int tid = threadIdx.x;
  const int tx = tid & 15, ty = tid >> 4;
  const int bm = blockIdx.x * 64;
  const int kbase = blockIdx.y * SKC;
  float acc[4][10];
#pragma unroll
  for (int i = 0; i < 4; ++i)
#pragma unroll
    for (int j = 0; j < 10; ++j) acc[i][j] = 0.f;
  const int am = tid >> 1, aj = (tid & 1) * 4;
  for (int k0 = 0; k0 < SKC; k0 += 8) {
    __syncthreads();
    if (tid < 128) {
      float4 av = *(const float4*)(A + (size_t)(bm + am) * HH + kbase + k0 + aj);
      As[aj + 0][am] = av.x; As[aj + 1][am] = av.y;
      As[aj + 2][am] = av.z; As[aj + 3][am] = av.w;
    }
#pragma unroll
    for (int i = 0; i < 2; ++i) {
      const int idx = tid + i * 256;
      if (idx < 320) {
        const int row = idx / 40;
        const int c = (idx - row * 40) * 4;
        float4 bv;
        if (c < 128) bv = *(const float4*)(B1 + (size_t)(kbase + k0 + row) * 128 + c);
        else         bv = *(const float4*)(B2 + (size_t)(kbase + k0 + row) * 32 + (c - 128));
        *(float4*)&Bs[row][c] = bv;
      }
    }
    __syncthreads();
#pragma unroll
    for (int p = 0; p < 8; ++p) {
      float av[4];
#pragma unroll
      for (int i = 0; i < 4; ++i) av[i] = As[p][ty * 4 + i];
      float bv[10];
#pragma unroll
      for (int j = 0; j < 10; ++j) bv[j] = Bs[p][tx * 10 + j];
#pragma unroll
      for (int i = 0; i < 4; ++i)
#pragma unroll
        for (int j = 0; j < 10; ++j) acc[i][j] = fmaf(av[i], bv[j], acc[i][j]);
    }
  }
  float* dst = part + ((size_t)blockIdx.y * TT + bm) * 160;
#pragma unroll
  for (int i = 0; i < 4; ++i)
#pragma unroll
    for (int j = 0; j < 10; ++j)
      dst[(size_t)(ty * 4 + i) * 160 + tx * 10 + j] = acc[i][j];
}

__global__ __launch_bounds__(256) void skinny_reduce(const float* __restrict__ part,
                                                     float* __restrict__ kib,
                                                     float* __restrict__ wtsb) {
  const int idx = blockIdx.x * 256 + threadIdx.x;  // 1024*160
  const int m = idx / 160, c = idx - m * 160;
  float s = 0.f;
#pragma unroll
  for (int ks = 0; ks < SKS; ++ks) s += part[((size_t)ks * TT + m) * 160 + c];
  if (c < 128) kib[(size_t)m * 128 + c] = s;
  else wtsb[(size_t)m * 32 + (c - 128)] = s;
}

// ---------------- plain bf16 MFMA GEMM: C = A @ Bt^T ----------------
template <typename CT>
__global__ __launch_bounds__(256) void gemm_bf16(const short* __restrict__ A,
                                                 const short* __restrict__ Bt,
                                                 CT* __restrict__ C,
                                                 int M, int N, int K) {
  __shared__ short As[128 * 72];
  __shared__ short Bs[128 * 72];
  const int tid = threadIdx.x;
  const int lane = tid & 63, wv = tid >> 6;
  const int wr = (wv >> 1) * 64, wc = (wv & 1) * 64;
  const int bm = blockIdx.y * 128, bn = blockIdx.x * 128;
  const int l15 = lane & 15, l4 = lane >> 4;
  f32x4 acc[4][4];
#pragma unroll
  for (int i = 0; i < 4; ++i)
#pragma unroll
    for (int j = 0; j < 4; ++j) acc[i][j] = f32x4{0.f, 0.f, 0.f, 0.f};
  for (int k0 = 0; k0 < K; k0 += 64) {
    __syncthreads();
#pragma unroll
    for (int i = 0; i < 4; ++i) {
      const int c = i * 256 + tid;
      const int m = c >> 3, kc = c & 7;
      short8 va = *(const short8*)(A + (size_t)(bm + m) * K + k0 + kc * 8);
      *(short8*)(&As[m * 72 + kc * 8]) = va;
      short8 vb = *(const short8*)(Bt + (size_t)(bn + m) * K + k0 + kc * 8);
      *(short8*)(&Bs[m * 72 + kc * 8]) = vb;
    }
    __syncthreads();
    short8 fa[4][2], fb[4][2];
#pragma unroll
    for (int f = 0; f < 4; ++f)
#pragma unroll
      for (int kk = 0; kk < 2; ++kk) {
        fa[f][kk] = *(const short8*)(&As[(wr + f * 16 + l15) * 72 + kk * 32 + l4 * 8]);
        fb[f][kk] = *(const short8*)(&Bs[(wc + f * 16 + l15) * 72 + kk * 32 + l4 * 8]);
      }
#pragma unroll
    for (int kk = 0; kk < 2; ++kk)
#pragma unroll
      for (int i = 0; i < 4; ++i)
#pragma unroll
        for (int j = 0; j < 4; ++j)
          acc[i][j] = __builtin_amdgcn_mfma_f32_16x16x32_bf16(fa[i][kk], fb[j][kk], acc[i][j], 0, 0, 0);
  }
#pragma unroll
  for (int i = 0; i < 4; ++i)
#pragma unroll
    for (int j = 0; j < 4; ++j)
#pragma unroll
      for (int r = 0; r < 4; ++r) {
        const int row = bm + wr + i * 16 + l4 * 4 + r;
        const int col = bn + wc + j * 16 + l15;
        const float v = acc[i][j][r];
        if constexpr (std::is_same<CT, float>::value) C[(size_t)row * N + col] = v;
        else C[(size_t)row * N + col] = __float2bfloat16(v);
      }
}

// ---------------- pre-split bf16x3 GEMM with split-K ----------------
// part[z][M][Np] += A(hi/lo)[M,K-chunk] @ Bt(hi/lo)[Np,K-chunk]^T (3 products)
// 128x128 tile, BK=32, 4 waves 2x2. All operands bf16, staged as pure copies.
__global__ __launch_bounds__(256) void gemm3(const short* __restrict__ Ah,
                                             const short* __restrict__ Al,
                                             const short* __restrict__ Bth,
                                             const short* __restrict__ Btl,
                                             float* __restrict__ part,
                                             int M, int Np, int K, int kchunk) {
  __shared__ short AhS[128 * 40], AlS[128 * 40], BhS[128 * 40], BlS[128 * 40];
  const int tid = threadIdx.x;
  const int lane = tid & 63, wv = tid >> 6;
  const int wr = (wv >> 1) * 64, wc = (wv & 1) * 64;
  const int l15 = lane & 15, l4 = lane >> 4;
  const int bm = blockIdx.y * 128, bn = blockIdx.x * 128;
  const int kbeg = blockIdx.z * kchunk;
  f32x4 acc[4][4];
#pragma unroll
  for (int i = 0; i < 4; ++i)
#pragma unroll
    for (int j = 0; j < 4; ++j) acc[i][j] = f32x4{0.f, 0.f, 0.f, 0.f};
  const int srow = tid >> 2, sseg = (tid & 3) * 8;  // 64 rows per 256-thread pass
  for (int k0 = kbeg; k0 < kbeg + kchunk; k0 += 32) {
    __syncthreads();
#pragma unroll
    for (int i = 0; i < 2; ++i) {
      const int row = srow + i * 64;
      const size_t ga = (size_t)(bm + row) * K + k0 + sseg;
      const size_t gb = (size_t)(bn + row) * K + k0 + sseg;
      *(short8*)&AhS[row * 40 + sseg] = *(const short8*)(Ah + ga);
      *(short8*)&AlS[row * 40 + sseg] = *(const short8*)(Al + ga);
      *(short8*)&BhS[row * 40 + sseg] = *(const short8*)(Bth + gb);
      *(short8*)&BlS[row * 40 + sseg] = *(const short8*)(Btl + gb);
    }
    __syncthreads();
    short8 fah[4], fal[4];
#pragma unroll
    for (int rt = 0; rt < 4; ++rt) {
      fah[rt] = *(const short8*)&AhS[(wr + rt * 16 + l15) * 40 + l4 * 8];
      fal[rt] = *(const short8*)&AlS[(wr + rt * 16 + l15) * 40 + l4 * 8];
    }
#pragma unroll
    for (int ct = 0; ct < 4; ++ct) {
      short8 fbh = *(const short8*)&BhS[(wc + ct * 16 + l15) * 40 + l4 * 8];
      short8 fbl = *(const short8*)&BlS[(wc + ct * 16 + l15) * 40 + l4 * 8];
#pragma unroll
      for (int rt = 0; rt < 4; ++rt) {
        acc[rt][ct] = __builtin_amdgcn_mfma_f32_16x16x32_bf16(fah[rt], fbh, acc[rt][ct], 0, 0, 0);
        acc[rt][ct] = __builtin_amdgcn_mfma_f32_16x16x32_bf16(fah[rt], fbl, acc[rt][ct], 0, 0, 0);
        acc[rt][ct] = __builtin_amdgcn_mfma_f32_16x16x32_bf16(fal[rt], fbh, acc[rt][ct], 0, 0, 0);
      }
    }
  }
  float* dst = part + (size_t)blockIdx.z * M * Np;
#pragma unroll
  for (int rt = 0; rt < 4; ++rt)
#pragma unroll
    for (int ct = 0; ct < 4; ++ct)
#pragma unroll
      for (int r = 0; r < 4; ++r)
        dst[(size_t)(bm + wr + rt * 16 + l4 * 4 + r) * Np + bn + wc + ct * 16 + l15] =
            acc[rt][ct][r];
}

// ---------------- deterministic split-K reduce (padded -> compact) ----------------
__global__ __launch_bounds__(256) void reduce_splitk(const float* __restrict__ part,
                                                     float* __restrict__ C,
                                                     int M, int Np, int Nout, int ksplit) {
  const int c = blockIdx.x * 256 + threadIdx.x;
  const int m = blockIdx.y;
  if (c >= Nout) return;
  float s = 0.f;
  for (int z = 0; z < ksplit; ++z) s += part[((size_t)z * M + m) * Np + c];
  C[(size_t)m * Nout + c] = s;
}

// ---------------- f32 -> bf16 hi/lo split (flat) ----------------
__global__ __launch_bounds__(256) void split_cast(const float* __restrict__ in,
                                                  short* __restrict__ hi,
                                                  short* __restrict__ lo, int n4) {
  const int i = blockIdx.x * 256 + threadIdx.x;
  if (i >= n4) return;
  float4 v = *(const float4*)(in + (size_t)i * 4);
  float av[4] = {v.x, v.y, v.z, v.w};
  short4v h, l;
#pragma unroll
  for (int e = 0; e < 4; ++e) {
    h[e] = f2bf(av[e]);
    l[e] = f2bf(av[e] - bf2f(h[e]));
  }
  *(short4v*)(hi + (size_t)i * 4) = h;
  *(short4v*)(lo + (size_t)i * 4) = l;
}

// ---------------- transpose + cast: B[K][N] f32 -> Bt[N][K] bf16 ----------------
__global__ __launch_bounds__(256) void transpose_cast(const float* __restrict__ B,
                                                      short* __restrict__ Bt,
                                                      int K, int N) {
  __shared__ float tile[64][65];
  const int tid = threadIdx.x;
  const int k0 = blockIdx.y * 64, n0 = blockIdx.x * 64;
  const int r = tid >> 4, c4 = (tid & 15) * 4;
#pragma unroll
  for (int i = 0; i < 4; ++i) {
    float4 v = *(const float4*)(B + (size_t)(k0 + r + i * 16) * N + n0 + c4);
    tile[r + i * 16][c4 + 0] = v.x;
    tile[r + i * 16][c4 + 1] = v.y;
    tile[r + i * 16][c4 + 2] = v.z;
    tile[r + i * 16][c4 + 3] = v.w;
  }
  __syncthreads();
  const int nl = tid >> 3, kc = (tid & 7) * 8;
#pragma unroll
  for (int i = 0; i < 2; ++i) {
    const int n = nl + i * 32;
    short8 o;
#pragma unroll
    for (int e = 0; e < 8; ++e) o[e] = f2bf(tile[kc + e][n]);
    *(short8*)(Bt + (size_t)(n0 + n) * K + k0 + kc) = o;
  }
}

// ---------------- transpose + split cast (hi/lo), zero-fills pad rows n >= Nsrc ------
__global__ __launch_bounds__(256) void transpose_split_cast(const float* __restrict__ B,
                                                            short* __restrict__ Bth,
                                                            short* __restrict__ Btl,
                                                            int K, int Nsrc) {
  __shared__ float tile[64][65];
  const int tid = threadIdx.x;
  const int k0 = blockIdx.y * 64, n0 = blockIdx.x * 64;
  const int nl = tid >> 3, kc = (tid & 7) * 8;
  if (n0 >= Nsrc) {  // pad region: zero-fill
    short8 z = {0, 0, 0, 0, 0, 0, 0, 0};
#pragma unroll
    for (int i = 0; i < 2; ++i) {
      const int n = nl + i * 32;
      *(short8*)(Bth + (size_t)(n0 + n) * K + k0 + kc) = z;
      *(short8*)(Btl + (size_t)(n0 + n) * K + k0 + kc) = z;
    }
    return;
  }
  const int r = tid >> 4, c4 = (tid & 15) * 4;
#pragma unroll
  for (int i = 0; i < 4; ++i) {
    float4 v = *(const float4*)(B + (size_t)(k0 + r + i * 16) * Nsrc + n0 + c4);
    tile[r + i * 16][c4 + 0] = v.x;
    tile[r + i * 16][c4 + 1] = v.y;
    tile[r + i * 16][c4 + 2] = v.z;
    tile[r + i * 16][c4 + 3] = v.w;
  }
  __syncthreads();
#pragma unroll
  for (int i = 0; i < 2; ++i) {
    const int n = nl + i * 32;
    short8 oh, ol;
#pragma unroll
    for (int e = 0; e < 8; ++e) {
      const float x = tile[kc + e][n];
      oh[e] = f2bf(x);
      ol[e] = f2bf(x - bf2f(oh[e]));
    }
    *(short8*)(Bth + (size_t)(n0 + n) * K + k0 + kc) = oh;
    *(short8*)(Btl + (size_t)(n0 + n) * K + k0 + kc) = ol;
  }
}

// ---------------- flat f32 -> bf16 cast ----------------
__global__ void cast_bf(const float* __restrict__ in, short* __restrict__ out, int n) {
  const int i = blockIdx.x * 256 + threadIdx.x;
  if (i < n) out[i] = f2bf(in[i]);
}

// ---------------- RMSNorm (fp32 + bf16 hi [+ optional lo]) ----------------
__global__ __launch_bounds__(256) void rms_kernel(const float* __restrict__ in, int in_stride,
                                                  const float* __restrict__ w,
                                                  float* __restrict__ out,
                                                  short* __restrict__ out_bf,
                                                  short* __restrict__ out_lo, int C) {
  const int t = blockIdx.x, tid = threadIdx.x;
  const float* x = in + (size_t)t * in_stride;
  float ss = 0.f;
  for (int i = tid; i < C; i += 256) { float v = x[i]; ss = fmaf(v, v, ss); }
#pragma unroll
  for (int o = 32; o > 0; o >>= 1) ss += __shfl_xor(ss, o);
  __shared__ float red[4];
  if ((tid & 63) == 0) red[tid >> 6] = ss;
  __syncthreads();
  const float tot = red[0] + red[1] + red[2] + red[3];
  const float r = rsqrtf(tot / (float)C + 1e-6f);
  for (int i = tid; i < C; i += 256) {
    const float v = x[i] * r * w[i];
    out[(size_t)t * C + i] = v;
    const short h = f2bf(v);
    out_bf[(size_t)t * C + i] = h;
    if (out_lo) out_lo[(size_t)t * C + i] = f2bf(v - bf2f(h));
  }
}

// ---------------- LayerNorm in-place on (T,128) ----------------
__global__ __launch_bounds__(128) void ln_kernel(float* __restrict__ x,
                                                 const float* __restrict__ w,
                                                 const float* __restrict__ b) {
  const int t = blockIdx.x, i = threadIdx.x;
  float v = x[(size_t)t * 128 + i];
  float s = v;
#pragma unroll
  for (int o = 32; o > 0; o >>= 1) s += __shfl_xor(s, o);
  __shared__ float r1[2], r2[2];
  if ((i & 63) == 0) r1[i >> 6] = s;
  __syncthreads();
  const float m = (r1[0] + r1[1]) * (1.f / 128.f);
  const float dv = v - m;
  float sq = dv * dv;
#pragma unroll
  for (int o = 32; o > 0; o >>= 1) sq += __shfl_xor(sq, o);
  if ((i & 63) == 0) r2[i >> 6] = sq;
  __syncthreads();
  const float var = (r2[0] + r2[1]) * (1.f / 128.f);
  x[(size_t)t * 128 + i] = dv * rsqrtf(var + 1e-6f) * w[i] + b[i];
}

// ---------------- RoPE (interleaved pairs), fp32 ----------------
__global__ void rope_kernel(const float* __restrict__ src, int s_ts, int s_hs,
                            float* __restrict__ dst, int d_ts, int d_hs,
                            const int* __restrict__ pos) {
  const int t = blockIdx.x, h = blockIdx.y, i = threadIdx.x;
  const float* s = src + (size_t)t * s_ts + (size_t)h * s_hs;
  float* d = dst + (size_t)t * d_ts + (size_t)h * d_hs;
  const float x1 = s[2 * i], x2 = s[2 * i + 1];
  const float inv = powf(10000.f, -(float)i * (1.f / 32.f));
  const float ang = (float)pos[t] * inv;
  float sn, cs;
  sincosf(ang, &sn, &cs);
  d[2 * i]     = x1 * cs - x2 * sn;
  d[2 * i + 1] = x1 * sn + x2 * cs;
}

// ---------------- q rope + repack: qbuf[q][h][192] bf16 -> qh[h][q][192] ----------------
__global__ void q_rope_repack(const short* __restrict__ qbuf,
                              short* __restrict__ qhout,
                              const int* __restrict__ pos) {
  const int q = blockIdx.x, h = blockIdx.y;
  const int p = threadIdx.x;  // 96 pairs
  const short* s = qbuf + ((size_t)q * 32 + h) * 192;
  short* d = qhout + ((size_t)h * 1024 + q) * 192;
  float x1 = bf2f(s[2 * p]), x2 = bf2f(s[2 * p + 1]);
  if (p >= 64) {
    const int i = p - 64;
    const float inv = powf(10000.f, -(float)i * (1.f / 32.f));
    const float ang = (float)pos[q] * inv;
    float sn, cs;
    sincosf(ang, &sn, &cs);
    const float a = x1 * cs - x2 * sn, b = x1 * sn + x2 * cs;
    x1 = a; x2 = b;
  }
  d[2 * p]     = f2bf(x1);
  d[2 * p + 1] = f2bf(x2);
}

// ---------------- qi repack + split: qib[q][32][128] f32 -> qih_hi/lo [32][q][128] ----------------
__global__ __launch_bounds__(256) void qi_repack_split(const float* __restrict__ qib,
                                                       short* __restrict__ qhh,
                                                       short* __restrict__ qhl) {
  const int qt = blockIdx.x, h = blockIdx.y;
  const int tid = threadIdx.x;
#pragma unroll
  for (int i = 0; i < 8; ++i) {
    const int idx = tid + i * 256;           // 2048 float4 chunks
    const int q = idx >> 5, c = idx & 31;
    float4 v = *(const float4*)(qib + ((size_t)(qt * 64 + q) * 32 + h) * 128 + c * 4);
    float av[4] = {v.x, v.y, v.z, v.w};
    short4v hv, lv;
#pragma unroll
    for (int e = 0; e < 4; ++e) {
      hv[e] = f2bf(av[e]);
      lv[e] = f2bf(av[e] - bf2f(hv[e]));
    }
    const size_t off = ((size_t)h * 1024 + qt * 64 + q) * 128 + c * 4;
    *(short4v*)(qhh + off) = hv;
    *(short4v*)(qhl + off) = lv;
  }
}

// ---------------- kv repack ----------------
__global__ __launch_bounds__(256) void kv_repack(const short* __restrict__ kvb,
                                                 const short* __restrict__ kpe,
                                                 short* __restrict__ kfout,
                                                 short* __restrict__ vtout) {
  const int kt = blockIdx.x, h = blockIdx.y;
  const int tid = threadIdx.x;
  const int k0 = kt * 64;
  __shared__ short vtile[64][136];
#pragma unroll
  for (int i = 0; i < 6; ++i) {
    const int idx = tid + i * 256;           // 1536 chunks
    const int row = idx / 24, c = idx - row * 24;
    short8 v = (c < 16) ? *(const short8*)(kvb + ((size_t)(k0 + row) * 32 + h) * 256 + c * 8)
                        : *(const short8*)(kpe + (size_t)(k0 + row) * 64 + (c - 16) * 8);
    *(short8*)(kfout + ((size_t)h * 1024 + k0 + row) * 192 + c * 8) = v;
  }
#pragma unroll
  for (int i = 0; i < 4; ++i) {
    const int idx = tid + i * 256;           // 1024 chunks
    const int row = idx >> 4, c = idx & 15;
    *(short8*)&vtile[row][c * 8] =
        *(const short8*)(kvb + ((size_t)(k0 + row) * 32 + h) * 256 + 128 + c * 8);
  }
  __syncthreads();
#pragma unroll
  for (int i = 0; i < 4; ++i) {
    const int idx = tid + i * 256;           // 1024 chunks
    const int d = idx >> 3, kc = idx & 7;
    short8 o;
#pragma unroll
    for (int e = 0; e < 8; ++e) o[e] = vtile[kc * 8 + e][d];
    *(short8*)(vtout + ((size_t)h * 128 + d) * 1024 + k0 + kc * 8) = o;
  }
}

// ---------------- MFMA indexer logits (bf16x3, 8 heads per z) ----------------
__global__ __launch_bounds__(256) void logits_mfma(const short* __restrict__ qih,
                                                   const short* __restrict__ qil,
                                                   const float* __restrict__ ki,
                                                   const float* __restrict__ wts,
                                                   float* __restrict__ part) {
  const int bk = blockIdx.x, bq = blockIdx.y, g = blockIdx.z;
  if (bk > bq) return;
  __shared__ short kih[64 * 136], kil[64 * 136];
  __shared__ float swts[64][8];
  const int tid = threadIdx.x;
  const int lane = tid & 63, wv = tid >> 6;
  const int wr = (wv >> 1) * 32, wc = (wv & 1) * 32;
  const int l15 = lane & 15, l4 = lane >> 4;
  const int q0 = bq * 64, k0 = bk * 64;
  {
    const int row = tid >> 2, seg = (tid & 3) * 32;
#pragma unroll
    for (int c = 0; c < 32; c += 8) {
      const float* kp = ki + (size_t)(k0 + row) * 128 + seg + c;
      float4 v0 = *(const float4*)kp;
      float4 v1 = *(const float4*)(kp + 4);
      float av[8] = {v0.x, v0.y, v0.z, v0.w, v1.x, v1.y, v1.z, v1.w};
      short8 h8, l8;
#pragma unroll
      for (int e = 0; e < 8; ++e) {
        h8[e] = f2bf(av[e]);
        l8[e] = f2bf(av[e] - bf2f(h8[e]));
      }
      *(short8*)&kih[row * 136 + seg + c] = h8;
      *(short8*)&kil[row * 136 + seg + c] = l8;
    }
  }
#pragma unroll
  for (int i = 0; i < 2; ++i) {
    const int idx = tid + i * 256;  // 512 entries
    swts[idx >> 3][idx & 7] = wts[(size_t)(q0 + (idx >> 3)) * 32 + g * 8 + (idx & 7)];
  }
  __syncthreads();
  short8 kbh[2][4], kbl[2][4];
#pragma unroll
  for (int ct = 0; ct < 2; ++ct)
#pragma unroll
    for (int ks = 0; ks < 4; ++ks) {
      kbh[ct][ks] = *(const short8*)&kih[(wc + ct * 16 + l15) * 136 + ks * 32 + l4 * 8];
      kbl[ct][ks] = *(const short8*)&kil[(wc + ct * 16 + l15) * 136 + ks * 32 + l4 * 8];
    }
  f32x4 lacc[2][2];
#pragma unroll
  for (int i = 0; i < 2; ++i)
#pragma unroll
    for (int j = 0; j < 2; ++j) lacc[i][j] = f32x4{0.f, 0.f, 0.f, 0.f};
  for (int hh = 0; hh < 8; ++hh) {
    const int h = g * 8 + hh;
    short8 qah[2][4], qal[2][4];
#pragma unroll
    for (int rt = 0; rt < 2; ++rt)
#pragma unroll
      for (int ks = 0; ks < 4; ++ks) {
        const size_t off = ((size_t)h * 1024 + q0 + wr + rt * 16 + l15) * 128 + ks * 32 + l4 * 8;
        qah[rt][ks] = *(const short8*)(qih + off);
        qal[rt][ks] = *(const short8*)(qil + off);
      }
    f32x4 hacc[2][2];
#pragma unroll
    for (int i = 0; i < 2; ++i)
#pragma unroll
      for (int j = 0; j < 2; ++j) hacc[i][j] = f32x4{0.f, 0.f, 0.f, 0.f};
#pragma unroll
    for (int ks = 0; ks < 4; ++ks)
#pragma unroll
      for (int rt = 0; rt < 2; ++rt)
#pragma unroll
        for (int ct = 0; ct < 2; ++ct) {
          hacc[rt][ct] = __builtin_amdgcn_mfma_f32_16x16x32_bf16(qah[rt][ks], kbh[ct][ks], hacc[rt][ct], 0, 0, 0);
          hacc[rt][ct] = __builtin_amdgcn_mfma_f32_16x16x32_bf16(qah[rt][ks], kbl[ct][ks], hacc[rt][ct], 0, 0, 0);
          hacc[rt][ct] = __builtin_amdgcn_mfma_f32_16x16x32_bf16(qal[rt][ks], kbh[ct][ks], hacc[rt][ct], 0, 0, 0);
        }
#pragma unroll
    for (int rt = 0; rt < 2; ++rt)
#pragma unroll
      for (int ct = 0; ct < 2; ++ct)
#pragma unroll
        for (int r = 0; r < 4; ++r) {
          const int row = wr + rt * 16 + l4 * 4 + r;
          const float w = swts[row][hh] * kWtsScale;
          lacc[rt][ct][r] = fmaf(w, fmaxf(hacc[rt][ct][r], 0.f), lacc[rt][ct][r]);
        }
  }
#pragma unroll
  for (int rt = 0; rt < 2; ++rt)
#pragma unroll
    for (int ct = 0; ct < 2; ++ct)
#pragma unroll
      for (int r = 0; r < 4; ++r)
        part[(size_t)g * TT * TT + (size_t)(q0 + wr + rt * 16 + l4 * 4 + r) * TT +
             (k0 + wc + ct * 16 + l15)] = lacc[rt][ct][r];
}

// ---------------- top-512 -> bitmask ----------------
__global__ __launch_bounds__(256) void topk_mask(const float* __restrict__ part,
                                                 unsigned* __restrict__ maskbuf) {
  const int q = blockIdx.x, tid = threadIdx.x;
  __shared__ unsigned u[TT];
  __shared__ unsigned char sel[TT];
  __shared__ int redi[4];
  const size_t NN = (size_t)TT * TT;
  for (int k = tid; k < TT; k += 256) {
    unsigned uv = 0u;
    if (k <= q) {
      const size_t o = (size_t)q * TT + k;
      const float s = part[o] + part[NN + o] + part[2 * NN + o] + part[3 * NN + o];
      unsigned bb = __float_as_uint(s);
      uv = (bb & 0x80000000u) ? ~bb : (bb | 0x80000000u);
    }
    u[k] = uv;
    sel[k] = 0;
  }
  __syncthreads();
  const int n = q + 1;
  if (n <= TOPKK) {
    if (tid < 32) {
      const int base = tid * 32;
      unsigned word = 0u;
      if (base + 31 <= q) word = 0xffffffffu;
      else if (base <= q) word = 0xffffffffu >> (31 - (q - base));
      maskbuf[(size_t)q * 32 + tid] = word;
    }
    return;
  }
  unsigned lo = 1u, hi = 0xFFFFFFFFu;
  while (lo < hi) {
    const unsigned mid = lo + ((hi - lo) >> 1) + ((hi - lo) & 1u);
    int c = 0;
    for (int k = tid; k < TT; k += 256) c += (u[k] >= mid) ? 1 : 0;
#pragma unroll
    for (int o = 32; o > 0; o >>= 1) c += __shfl_down(c, o);
    if ((tid & 63) == 0) redi[tid >> 6] = c;
    __syncthreads();
    const int ctot = redi[0] + redi[1] + redi[2] + redi[3];
    __syncthreads();
    if (ctot >= TOPKK) lo = mid; else hi = mid - 1u;
  }
  const unsigned ustar = lo;
  int c = 0;
  for (int k = tid; k < TT; k += 256) c += (u[k] > ustar) ? 1 : 0;
#pragma unroll
  for (int o = 32; o > 0; o >>= 1) c += __shfl_down(c, o);
  if ((tid & 63) == 0) redi[tid >> 6] = c;
  __syncthreads();
  const int nGreater = redi[0] + redi[1] + redi[2] + redi[3];
  for (int k = tid; k < TT; k += 256) sel[k] = (u[k] > ustar) ? 1 : 0;
  __syncthreads();
  if (tid == 0) {
    int need = TOPKK - nGreater;
    for (int k = 0; k <= q && need > 0; ++k)
      if (u[k] == ustar) { sel[k] = 1; --need; }
  }
  __syncthreads();
  if (tid < 32) {
    unsigned word = 0u;
#pragma unroll
    for (int b = 0; b < 32; ++b) word |= ((unsigned)sel[tid * 32 + b]) << b;
    maskbuf[(size_t)q * 32 + tid] = word;
  }
}

// ---------------- masked dense MFMA attention ----------------
__global__ __launch_bounds__(256) void attn_mfma(const short* __restrict__ qh,
                                                 const short* __restrict__ kf,
                                                 const short* __restrict__ vt,
                                                 const unsigned* __restrict__ maskbuf,
                                                 short* __restrict__ ao) {
  const int h = blockIdx.x;
  const int yy = blockIdx.y;
  const int qt = (yy < 8) ? (yy * 2) : (31 - yy * 2);  // pair light+heavy tiles per CU
  const int tid = threadIdx.x;
  const int lane = tid & 63, w = tid >> 6;
  const int l15 = lane & 15, l4 = lane >> 4;
  const int q0 = qt * 64;
  __shared__ short kfs[64 * 200];
  __shared__ short vts[128 * 72];
  __shared__ short ps[4][16][72];
  __shared__ unsigned m32s[64][2];
  short8 qf[6];
#pragma unroll
  for (int ks = 0; ks < 6; ++ks)
    qf[ks] = *(const short8*)(qh + ((size_t)h * 1024 + q0 + w * 16 + l15) * 192 + ks * 32 + l4 * 8);
  f32x4 of[8];
#pragma unroll
  for (int dt = 0; dt < 8; ++dt) of[dt] = f32x4{0.f, 0.f, 0.f, 0.f};
  float m[4], l[4];
#pragma unroll
  for (int r = 0; r < 4; ++r) { m[r] = -INFINITY; l[r] = 0.f; }

  for (int kt = 0; kt <= qt; ++kt) {
    const int k0 = kt * 64;
    __syncthreads();
#pragma unroll
    for (int i = 0; i < 6; ++i) {
      const int idx = tid + i * 256;
      const int row = idx / 24, c = idx - row * 24;
      *(short8*)&kfs[row * 200 + c * 8] =
          *(const short8*)(kf + ((size_t)h * 1024 + k0 + row) * 192 + c * 8);
    }
#pragma unroll
    for (int i = 0; i < 4; ++i) {
      const int idx = tid + i * 256;
      const int row = idx >> 3, c = idx & 7;
      *(short8*)&vts[row * 72 + c * 8] =
          *(const short8*)(vt + ((size_t)h * 128 + row) * 1024 + k0 + c * 8);
    }
    if (tid < 128)
      m32s[tid >> 1][tid & 1] = maskbuf[(size_t)(q0 + (tid >> 1)) * 32 + (k0 >> 5) + (tid & 1)];
    __syncthreads();
    // QK^T
    f32x4 sacc[4];
#pragma unroll
    for (int j = 0; j < 4; ++j) sacc[j] = f32x4{0.f, 0.f, 0.f, 0.f};
#pragma unroll
    for (int ks = 0; ks < 6; ++ks)
#pragma unroll
      for (int j = 0; j < 4; ++j) {
        short8 kb = *(const short8*)&kfs[(j * 16 + l15) * 200 + ks * 32 + l4 * 8];
        sacc[j] = __builtin_amdgcn_mfma_f32_16x16x32_bf16(qf[ks], kb, sacc[j], 0, 0, 0);
      }
    // scale + mask
    float tmax[4] = {-INFINITY, -INFINITY, -INFINITY, -INFINITY};
#pragma unroll
    for (int j = 0; j < 4; ++j)
#pragma unroll
      for (int r = 0; r < 4; ++r) {
        const int kcol = j * 16 + l15;
        const unsigned um = m32s[w * 16 + l4 * 4 + r][kcol >> 5];
        float s = sacc[j][r] * kScaling;
        s = ((um >> (kcol & 31)) & 1u) ? s : -INFINITY;
        sacc[j][r] = s;
        tmax[r] = fmaxf(tmax[r], s);
      }
#pragma unroll
    for (int r = 0; r < 4; ++r) {
      tmax[r] = fmaxf(tmax[r], __shfl_xor(tmax[r], 1));
      tmax[r] = fmaxf(tmax[r], __shfl_xor(tmax[r], 2));
      tmax[r] = fmaxf(tmax[r], __shfl_xor(tmax[r], 4));
      tmax[r] = fmaxf(tmax[r], __shfl_xor(tmax[r], 8));
    }
    float f[4];
#pragma unroll
    for (int r = 0; r < 4; ++r) {
      const float mn = fmaxf(m[r], tmax[r]);
      f[r] = __expf(fmaxf(m[r], -1e30f) - fmaxf(mn, -1e30f));
      m[r] = mn;
      l[r] *= f[r];
    }
    float psum[4] = {0.f, 0.f, 0.f, 0.f};
#pragma unroll
    for (int j = 0; j < 4; ++j)
#pragma unroll
      for (int r = 0; r < 4; ++r) {
        const float p = __expf(sacc[j][r] - fmaxf(m[r], -1e30f));
        psum[r] += p;
        ps[w][l4 * 4 + r][j * 16 + l15] = f2bf(p);
      }
#pragma unroll
    for (int r = 0; r < 4; ++r) {
      psum[r] += __shfl_xor(psum[r], 1);
      psum[r] += __shfl_xor(psum[r], 2);
      psum[r] += __shfl_xor(psum[r], 4);
      psum[r] += __shfl_xor(psum[r], 8);
      l[r] += psum[r];
    }
#pragma unroll
    for (int dt = 0; dt < 8; ++dt)
#pragma unroll
      for (int r = 0; r < 4; ++r) of[dt][r] *= f[r];
    // PV
    short8 pa0 = *(const short8*)&ps[w][l15][l4 * 8];
    short8 pa1 = *(const short8*)&ps[w][l15][32 + l4 * 8];
#pragma unroll
    for (int dt = 0; dt < 8; ++dt) {
      short8 vb0 = *(const short8*)&vts[(dt * 16 + l15) * 72 + l4 * 8];
      short8 vb1 = *(const short8*)&vts[(dt * 16 + l15) * 72 + 32 + l4 * 8];
      of[dt] = __builtin_amdgcn_mfma_f32_16x16x32_bf16(pa0, vb0, of[dt], 0, 0, 0);
      of[dt] = __builtin_amdgcn_mfma_f32_16x16x32_bf16(pa1, vb1, of[dt], 0, 0, 0);
    }
  }
  // epilogue
#pragma unroll
  for (int r = 0; r < 4; ++r) {
    const float invl = 1.f / l[r];
#pragma unroll
    for (int dt = 0; dt < 8; ++dt)
      ao[(size_t)(q0 + w * 16 + l4 * 4 + r) * 4096 + h * 128 + dt * 16 + l15] =
          f2bf(of[dt][r] * invl);
  }
}

// ============================================================================
extern "C" void kernel_launch(void* const* d_in, const int* in_sizes, int n_in,
                              void* d_out, int out_size, void* d_ws, size_t ws_size,
                              hipStream_t stream) {
  const float* hidden     = (const float*)d_in[0];
  const int*   positions  = (const int*)d_in[1];
  const float* w_qkv_a    = (const float*)d_in[2];
  const float* q_a_ln_w   = (const float*)d_in[3];
  const float* w_q_b      = (const float*)d_in[4];
  const float* kv_a_ln_w  = (const float*)d_in[5];
  const float* w_kv_b     = (const float*)d_in[6];
  const float* w_o        = (const float*)d_in[7];
  const float* w_idx_qb   = (const float*)d_in[8];
  const float* w_idx_k    = (const float*)d_in[9];
  const float* idx_k_ln_w = (const float*)d_in[10];
  const float* idx_k_ln_b = (const float*)d_in[11];
  const float* w_idx_w    = (const float*)d_in[12];
  float* out = (float*)d_out;

  float* ws = (float*)d_ws;
  size_t off = 0;
  auto take = [&](size_t n) { float* p = ws + off; off += n; return p; };
  float* qkv     = take((size_t)TT * QKVN);
  float* qcn     = take((size_t)TT * QLL);
  short* qcn_bf  = (short*)take((size_t)TT * QLL / 2);
  short* qcn_lo  = (short*)take((size_t)TT * QLL / 2);
  float* kvn     = take((size_t)TT * KLL);
  short* kvn_bf  = (short*)take((size_t)TT * KLL / 2);
  short* qbuf    = (short*)take((size_t)TT * NHH * 192 / 2);   // bf16 [q][h][192]
  short* kvbuf   = (short*)take((size_t)TT * NHH * 256 / 2);   // bf16 [k][h][256]
  float* kpe     = take((size_t)TT * 64);
  short* kpe_bf  = (short*)take((size_t)TT * 32);
  float* qib     = take((size_t)TT * INHH * IHDD);             // fp32 [q][32][128]
  float* kib     = take((size_t)TT * IHDD);
  float* wtsb    = take((size_t)TT * INHH);
  short* qhb     = (short*)take((size_t)NHH * TT * 192 / 2);   // bf16 [h][q][192]
  short* qih_h   = (short*)take((size_t)INHH * TT * 128 / 2);
  short* qih_l   = (short*)take((size_t)INHH * TT * 128 / 2);
  short* kfb     = (short*)take((size_t)NHH * TT * 192 / 2);   // bf16 [h][k][192]
  short* vtb     = (short*)take((size_t)NHH * 128 * TT / 2);   // bf16 [h][d][k]
  float* part4   = take((size_t)4 * TT * TT);
  unsigned* maskbuf = (unsigned*)take((size_t)TT * 32);
  short* hid_h   = (short*)take((size_t)TT * HH / 2);
  short* hid_l   = (short*)take((size_t)TT * HH / 2);
  short* wqkva_h = (short*)take((size_t)QKVNP * HH / 2);       // padded rows
  short* wqkva_l = (short*)take((size_t)QKVNP * HH / 2);
  short* widxqb_h = (short*)take((size_t)HH * QLL / 2);
  short* widxqb_l = (short*)take((size_t)HH * QLL / 2);
  short* wqb_t   = (short*)take((size_t)6144 * QLL / 2);
  short* wkvb_t  = (short*)take((size_t)8192 * KLL / 2);
  short* ao   = (short*)part4;      // alias: part4 dead after topk
  short* wo_t = wqkva_h;            // alias: wqkva h+l dead after qkv_a gemm
  float* skpart = part4;            // alias: SKS*1024*160 = 2.62M < 4M (part4 not yet live)
  float* qkvpart = (float*)qbuf;    // alias: 4*1024*2176 = 8.9M < qbuf..qib span (11.6M)
  float* idxpart = (float*)qhb;     // alias: 2*1024*4096 = 8.4M < qhb..kfb span (10.5M)

  const dim3 blk(256);
  // fused skinny projections (kib | wtsb) via split-K
  skinny_splitk<<<dim3(16, SKS), blk, 0, stream>>>(hidden, w_idx_k, w_idx_w, skpart);
  skinny_reduce<<<dim3(TT * 160 / 256), blk, 0, stream>>>(skpart, kib, wtsb);
  // input/weight splits
  split_cast<<<dim3(TT * HH / 4 / 256), blk, 0, stream>>>(hidden, hid_h, hid_l, TT * HH / 4);
  transpose_split_cast<<<dim3(QKVNP / 64, HH / 64), blk, 0, stream>>>(w_qkv_a, wqkva_h, wqkva_l, HH, QKVN);
  transpose_split_cast<<<dim3(HH / 64, QLL / 64), blk, 0, stream>>>(w_idx_qb, widxqb_h, widxqb_l, QLL, HH);
  transpose_cast<<<dim3(6144 / 64, QLL / 64), blk, 0, stream>>>(w_q_b, wqb_t, QLL, 6144);
  transpose_cast<<<dim3(8192 / 64, KLL / 64), blk, 0, stream>>>(w_kv_b, wkvb_t, KLL, 8192);
  // qkv_a: bf16x3 split-K (topk-critical precision)
  gemm3<<<dim3(QKVNP / 128, 8, 4), blk, 0, stream>>>(hid_h, hid_l, wqkva_h, wqkva_l,
                                                     qkvpart, TT, QKVNP, HH, HH / 4);
  reduce_splitk<<<dim3((QKVN + 255) / 256, TT), blk, 0, stream>>>(qkvpart, qkv, TT, QKVNP, QKVN, 4);
  // w_o transpose AFTER qkv_a gemm (aliases wqkva)
  transpose_cast<<<dim3(HH / 64, HH / 64), blk, 0, stream>>>(w_o, wo_t, HH, HH);
  // norms (qcn also emits lo split for idx_qb's A operand)
  rms_kernel<<<TT, 256, 0, stream>>>(qkv, QKVN, q_a_ln_w, qcn, qcn_bf, qcn_lo, QLL);
  rms_kernel<<<TT, 256, 0, stream>>>(qkv + 1536, QKVN, kv_a_ln_w, kvn, kvn_bf, nullptr, KLL);
  // idx_qb: bf16x3 split-K (uses qhb-region scratch; qhb written later)
  gemm3<<<dim3(HH / 128, 8, 2), blk, 0, stream>>>(qcn_bf, qcn_lo, widxqb_h, widxqb_l,
                                                  idxpart, TT, HH, QLL, QLL / 2);
  reduce_splitk<<<dim3(HH / 256, TT), blk, 0, stream>>>(idxpart, qib, TT, HH, HH, 2);
  // smooth projections (write qbuf/kvbuf; qkvpart dead)
  gemm_bf16<__hip_bfloat16><<<dim3(48, 8), blk, 0, stream>>>(qcn_bf, wqb_t, (__hip_bfloat16*)qbuf, TT, 6144, QLL);
  gemm_bf16<__hip_bfloat16><<<dim3(64, 8), blk, 0, stream>>>(kvn_bf, wkvb_t, (__hip_bfloat16*)kvbuf, TT, 8192, KLL);
  // layernorm + RoPE
  ln_kernel<<<TT, 128, 0, stream>>>(kib, idx_k_ln_w, idx_k_ln_b);
  rope_kernel<<<dim3(TT, INHH), 32, 0, stream>>>(qib, INHH * IHDD, IHDD, qib, INHH * IHDD, IHDD, positions);
  rope_kernel<<<dim3(TT, 1), 32, 0, stream>>>(qkv + 2048, QKVN, 0, kpe, 64, 0, positions);
  rope_kernel<<<dim3(TT, 1), 32, 0, stream>>>(kib, IHDD, 0, kib, IHDD, 0, positions);
  cast_bf<<<dim3(TT * 64 / 256), blk, 0, stream>>>(kpe, kpe_bf, TT * 64);
  // repacks (qhb written here; idxpart dead)
  q_rope_repack<<<dim3(TT, NHH), 96, 0, stream>>>(qbuf, qhb, positions);
  qi_repack_split<<<dim3(16, INHH), blk, 0, stream>>>(qib, qih_h, qih_l);
  kv_repack<<<dim3(16, NHH), blk, 0, stream>>>(kvbuf, kpe_bf, kfb, vtb);
  // indexer logits (MFMA bf16x3; fp8-quant cancels: relu(x/s)*(w*s)==relu(x)*w)
  logits_mfma<<<dim3(16, 16, 4), blk, 0, stream>>>(qih_h, qih_l, kib, wtsb, part4);
  // top-512 -> bitmask
  topk_mask<<<dim3(TT), blk, 0, stream>>>(part4, maskbuf);
  // masked dense MFMA attention
  attn_mfma<<<dim3(NHH, 16), blk, 0, stream>>>(qhb, kfb, vtb, maskbuf, ao);
  // output projection
  gemm_bf16<float><<<dim3(32, 8), blk, 0, stream>>>(ao, wo_t, out, TT, HH, NHH * DVV);
}

// Round 6
// 693.773 us; speedup vs baseline: 6.5162x; 1.0172x over previous
//
#include <hip/hip_runtime.h>
#include <hip/hip_bf16.h>
#include <math.h>
#include <type_traits>

#define TT   1024
#define HH   4096
#define NHH  32
#define DNN  128
#define DRR  64
#define DVV  128
#define QLL  1536
#define KLL  512
#define INHH 32
#define IHDD 128
#define TOPKK 512
#define SKS  16            // k-splits for skinny projections
#define SKC  (HH / SKS)    // 256 k per split
#define QKVN 2112
#define QKVNP 2176         // padded to 17*128

typedef __attribute__((ext_vector_type(8))) short short8;
typedef __attribute__((ext_vector_type(4))) short short4v;
typedef __attribute__((ext_vector_type(4))) float f32x4;

static __device__ __constant__ float kScaling = 0.07216878364870322f;  // (DN+DR)^-0.5
static __device__ __constant__ float kWtsScale = 0.015625f;            // IHD^-.5 * INH^-.5

static __device__ __forceinline__ short f2bf(float f) {
  unsigned u = __float_as_uint(f);
  unsigned r = (u + 0x7fffu + ((u >> 16) & 1u)) >> 16;  // RNE
  return (short)r;
}
static __device__ __forceinline__ float bf2f(short s) {
  return __uint_as_float(((unsigned)(unsigned short)s) << 16);
}
// async global->LDS, 16B per lane; lds dest must be wave-uniform base + lane*16
static __device__ __forceinline__ void gl16(const void* g, void* l) {
  __builtin_amdgcn_global_load_lds(
      (const __attribute__((address_space(1))) unsigned int*)g,
      (__attribute__((address_space(3))) unsigned int*)l, 16, 0, 0);
}

// ---------------- fused skinny split-K: [kib | wtsb] = hidden @ [w_idx_k | w_idx_w] --------
__global__ __launch_bounds__(256) void skinny_splitk(const float* __restrict__ A,
                                                     const float* __restrict__ B1,
                                                     const float* __restrict__ B2,
                                                     float* __restrict__ part) {
  __shared__ float As[8][64];
  __shared__ float Bs[8][160];
  const int tid = threadIdx.x;
  const int tx = tid & 15, ty = tid >> 4;
  const int bm = blockIdx.x * 64;
  const int kbase = blockIdx.y * SKC;
  float acc[4][10];
#pragma unroll
  for (int i = 0; i < 4; ++i)
#pragma unroll
    for (int j = 0; j < 10; ++j) acc[i][j] = 0.f;
  const int am = tid >> 1, aj = (tid & 1) * 4;
  for (int k0 = 0; k0 < SKC; k0 += 8) {
    __syncthreads();
    if (tid < 128) {
      float4 av = *(const float4*)(A + (size_t)(bm + am) * HH + kbase + k0 + aj);
      As[aj + 0][am] = av.x; As[aj + 1][am] = av.y;
      As[aj + 2][am] = av.z; As[aj + 3][am] = av.w;
    }
#pragma unroll
    for (int i = 0; i < 2; ++i) {
      const int idx = tid + i * 256;
      if (idx < 320) {
        const int row = idx / 40;
        const int c = (idx - row * 40) * 4;
        float4 bv;
        if (c < 128) bv = *(const float4*)(B1 + (size_t)(kbase + k0 + row) * 128 + c);
        else         bv = *(const float4*)(B2 + (size_t)(kbase + k0 + row) * 32 + (c - 128));
        *(float4*)&Bs[row][c] = bv;
      }
    }
    __syncthreads();
#pragma unroll
    for (int p = 0; p < 8; ++p) {
      float av[4];
#pragma unroll
      for (int i = 0; i < 4; ++i) av[i] = As[p][ty * 4 + i];
      float bv[10];
#pragma unroll
      for (int j = 0; j < 10; ++j) bv[j] = Bs[p][tx * 10 + j];
#pragma unroll
      for (int i = 0; i < 4; ++i)
#pragma unroll
        for (int j = 0; j < 10; ++j) acc[i][j] = fmaf(av[i], bv[j], acc[i][j]);
    }
  }
  float* dst = part + ((size_t)blockIdx.y * TT + bm) * 160;
#pragma unroll
  for (int i = 0; i < 4; ++i)
#pragma unroll
    for (int j = 0; j < 10; ++j)
      dst[(size_t)(ty * 4 + i) * 160 + tx * 10 + j] = acc[i][j];
}

__global__ __launch_bounds__(256) void skinny_reduce(const float* __restrict__ part,
                                                     float* __restrict__ kib,
                                                     float* __restrict__ wtsb) {
  const int idx = blockIdx.x * 256 + threadIdx.x;  // 1024*160
  const int m = idx / 160, c = idx - m * 160;
  float s = 0.f;
#pragma unroll
  for (int ks = 0; ks < SKS; ++ks) s += part[((size_t)ks * TT + m) * 160 + c];
  if (c < 128) kib[(size_t)m * 128 + c] = s;
  else wtsb[(size_t)m * 32 + (c - 128)] = s;
}

// ---------------- plain bf16 MFMA GEMM: C = A @ Bt^T (global_load_lds staging) ---------
// 128x128 tile, BK=64, linear LDS [128][64] per operand.
template <typename CT>
__global__ __launch_bounds__(256) void gemm_bf16(const short* __restrict__ A,
                                                 const short* __restrict__ Bt,
                                                 CT* __restrict__ C,
                                                 int M, int N, int K) {
  __shared__ short As[128 * 64];
  __shared__ short Bs[128 * 64];
  const int tid = threadIdx.x;
  const int lane = tid & 63, wv = tid >> 6;
  const int wr = (wv >> 1) * 64, wc = (wv & 1) * 64;
  const int bm = blockIdx.y * 128, bn = blockIdx.x * 128;
  const int l15 = lane & 15, l4 = lane >> 4;
  const int r0 = tid >> 3;          // 0..31
  const int c8 = (tid & 7) * 8;     // 0..56
  f32x4 acc[4][4];
#pragma unroll
  for (int i = 0; i < 4; ++i)
#pragma unroll
    for (int j = 0; j < 4; ++j) acc[i][j] = f32x4{0.f, 0.f, 0.f, 0.f};
  for (int k0 = 0; k0 < K; k0 += 64) {
    __syncthreads();
#pragma unroll
    for (int i = 0; i < 4; ++i) {
      const int row = r0 + i * 32;
      gl16(A + (size_t)(bm + row) * K + k0 + c8, &As[(tid + i * 256) * 8]);
      gl16(Bt + (size_t)(bn + row) * K + k0 + c8, &Bs[(tid + i * 256) * 8]);
    }
    __syncthreads();
    short8 fa[4][2], fb[4][2];
#pragma unroll
    for (int f = 0; f < 4; ++f)
#pragma unroll
      for (int kk = 0; kk < 2; ++kk) {
        fa[f][kk] = *(const short8*)(&As[(wr + f * 16 + l15) * 64 + kk * 32 + l4 * 8]);
        fb[f][kk] = *(const short8*)(&Bs[(wc + f * 16 + l15) * 64 + kk * 32 + l4 * 8]);
      }
#pragma unroll
    for (int kk = 0; kk < 2; ++kk)
#pragma unroll
      for (int i = 0; i < 4; ++i)
#pragma unroll
        for (int j = 0; j < 4; ++j)
          acc[i][j] = __builtin_amdgcn_mfma_f32_16x16x32_bf16(fa[i][kk], fb[j][kk], acc[i][j], 0, 0, 0);
  }
#pragma unroll
  for (int i = 0; i < 4; ++i)
#pragma unroll
    for (int j = 0; j < 4; ++j)
#pragma unroll
      for (int r = 0; r < 4; ++r) {
        const int row = bm + wr + i * 16 + l4 * 4 + r;
        const int col = bn + wc + j * 16 + l15;
        const float v = acc[i][j][r];
        if constexpr (std::is_same<CT, float>::value) C[(size_t)row * N + col] = v;
        else C[(size_t)row * N + col] = __float2bfloat16(v);
      }
}

// ---------------- pre-split bf16x3 GEMM with split-K (global_load_lds staging) ---------
// 128x128 tile, BK=32, linear LDS [128][32] per operand-half.
__global__ __launch_bounds__(256) void gemm3(const short* __restrict__ Ah,
                                             const short* __restrict__ Al,
                                             const short* __restrict__ Bth,
                                             const short* __restrict__ Btl,
                                             float* __restrict__ part,
                                             int M, int Np, int K, int kchunk) {
  __shared__ short AhS[128 * 32], AlS[128 * 32], BhS[128 * 32], BlS[128 * 32];
  const int tid = threadIdx.x;
  const int lane = tid & 63, wv = tid >> 6;
  const int wr = (wv >> 1) * 64, wc = (wv & 1) * 64;
  const int l15 = lane & 15, l4 = lane >> 4;
  const int bm = blockIdx.y * 128, bn = blockIdx.x * 128;
  const int kbeg = blockIdx.z * kchunk;
  const int r0 = tid >> 2;          // 0..63
  const int c8 = (tid & 3) * 8;     // 0,8,16,24
  f32x4 acc[4][4];
#pragma unroll
  for (int i = 0; i < 4; ++i)
#pragma unroll
    for (int j = 0; j < 4; ++j) acc[i][j] = f32x4{0.f, 0.f, 0.f, 0.f};
  for (int k0 = kbeg; k0 < kbeg + kchunk; k0 += 32) {
    __syncthreads();
    {
      const size_t ga0 = (size_t)(bm + r0) * K + k0 + c8;
      const size_t ga1 = (size_t)(bm + 64 + r0) * K + k0 + c8;
      const size_t gb0 = (size_t)(bn + r0) * K + k0 + c8;
      const size_t gb1 = (size_t)(bn + 64 + r0) * K + k0 + c8;
      gl16(Ah + ga0, &AhS[tid * 8]);
      gl16(Ah + ga1, &AhS[2048 + tid * 8]);
      gl16(Al + ga0, &AlS[tid * 8]);
      gl16(Al + ga1, &AlS[2048 + tid * 8]);
      gl16(Bth + gb0, &BhS[tid * 8]);
      gl16(Bth + gb1, &BhS[2048 + tid * 8]);
      gl16(Btl + gb0, &BlS[tid * 8]);
      gl16(Btl + gb1, &BlS[2048 + tid * 8]);
    }
    __syncthreads();
    short8 fah[4], fal[4];
#pragma unroll
    for (int rt = 0; rt < 4; ++rt) {
      fah[rt] = *(const short8*)&AhS[(wr + rt * 16 + l15) * 32 + l4 * 8];
      fal[rt] = *(const short8*)&AlS[(wr + rt * 16 + l15) * 32 + l4 * 8];
    }
#pragma unroll
    for (int ct = 0; ct < 4; ++ct) {
      short8 fbh = *(const short8*)&BhS[(wc + ct * 16 + l15) * 32 + l4 * 8];
      short8 fbl = *(const short8*)&BlS[(wc + ct * 16 + l15) * 32 + l4 * 8];
#pragma unroll
      for (int rt = 0; rt < 4; ++rt) {
        acc[rt][ct] = __builtin_amdgcn_mfma_f32_16x16x32_bf16(fah[rt], fbh, acc[rt][ct], 0, 0, 0);
        acc[rt][ct] = __builtin_amdgcn_mfma_f32_16x16x32_bf16(fah[rt], fbl, acc[rt][ct], 0, 0, 0);
        acc[rt][ct] = __builtin_amdgcn_mfma_f32_16x16x32_bf16(fal[rt], fbh, acc[rt][ct], 0, 0, 0);
      }
    }
  }
  float* dst = part + (size_t)blockIdx.z * M * Np;
#pragma unroll
  for (int rt = 0; rt < 4; ++rt)
#pragma unroll
    for (int ct = 0; ct < 4; ++ct)
#pragma unroll
      for (int r = 0; r < 4; ++r)
        dst[(size_t)(bm + wr + rt * 16 + l4 * 4 + r) * Np + bn + wc + ct * 16 + l15] =
            acc[rt][ct][r];
}

// ---------------- deterministic split-K reduce (padded -> compact) ----------------
__global__ __launch_bounds__(256) void reduce_splitk(const float* __restrict__ part,
                                                     float* __restrict__ C,
                                                     int M, int Np, int Nout, int ksplit) {
  const int c = blockIdx.x * 256 + threadIdx.x;
  const int m = blockIdx.y;
  if (c >= Nout) return;
  float s = 0.f;
  for (int z = 0; z < ksplit; ++z) s += part[((size_t)z * M + m) * Np + c];
  C[(size_t)m * Nout + c] = s;
}

// ---------------- f32 -> bf16 hi/lo split (flat) ----------------
__global__ __launch_bounds__(256) void split_cast(const float* __restrict__ in,
                                                  short* __restrict__ hi,
                                                  short* __restrict__ lo, int n4) {
  const int i = blockIdx.x * 256 + threadIdx.x;
  if (i >= n4) return;
  float4 v = *(const float4*)(in + (size_t)i * 4);
  float av[4] = {v.x, v.y, v.z, v.w};
  short4v h, l;
#pragma unroll
  for (int e = 0; e < 4; ++e) {
    h[e] = f2bf(av[e]);
    l[e] = f2bf(av[e] - bf2f(h[e]));
  }
  *(short4v*)(hi + (size_t)i * 4) = h;
  *(short4v*)(lo + (size_t)i * 4) = l;
}

// ---------------- transpose + cast: B[K][N] f32 -> Bt[N][K] bf16 ----------------
__global__ __launch_bounds__(256) void transpose_cast(const float* __restrict__ B,
                                                      short* __restrict__ Bt,
                                                      int K, int N) {
  __shared__ float tile[64][65];
  const int tid = threadIdx.x;
  const int k0 = blockIdx.y * 64, n0 = blockIdx.x * 64;
  const int r = tid >> 4, c4 = (tid & 15) * 4;
#pragma unroll
  for (int i = 0; i < 4; ++i) {
    float4 v = *(const float4*)(B + (size_t)(k0 + r + i * 16) * N + n0 + c4);
    tile[r + i * 16][c4 + 0] = v.x;
    tile[r + i * 16][c4 + 1] = v.y;
    tile[r + i * 16][c4 + 2] = v.z;
    tile[r + i * 16][c4 + 3] = v.w;
  }
  __syncthreads();
  const int nl = tid >> 3, kc = (tid & 7) * 8;
#pragma unroll
  for (int i = 0; i < 2; ++i) {
    const int n = nl + i * 32;
    short8 o;
#pragma unroll
    for (int e = 0; e < 8; ++e) o[e] = f2bf(tile[kc + e][n]);
    *(short8*)(Bt + (size_t)(n0 + n) * K + k0 + kc) = o;
  }
}

// ---------------- transpose + split cast (hi/lo), zero-fills pad rows n >= Nsrc ------
__global__ __launch_bounds__(256) void transpose_split_cast(const float* __restrict__ B,
                                                            short* __restrict__ Bth,
                                                            short* __restrict__ Btl,
                                                            int K, int Nsrc) {
  __shared__ float tile[64][65];
  const int tid = threadIdx.x;
  const int k0 = blockIdx.y * 64, n0 = blockIdx.x * 64;
  const int nl = tid >> 3, kc = (tid & 7) * 8;
  if (n0 >= Nsrc) {  // pad region: zero-fill
    short8 z = {0, 0, 0, 0, 0, 0, 0, 0};
#pragma unroll
    for (int i = 0; i < 2; ++i) {
      const int n = nl + i * 32;
      *(short8*)(Bth + (size_t)(n0 + n) * K + k0 + kc) = z;
      *(short8*)(Btl + (size_t)(n0 + n) * K + k0 + kc) = z;
    }
    return;
  }
  const int r = tid >> 4, c4 = (tid & 15) * 4;
#pragma unroll
  for (int i = 0; i < 4; ++i) {
    float4 v = *(const float4*)(B + (size_t)(k0 + r + i * 16) * Nsrc + n0 + c4);
    tile[r + i * 16][c4 + 0] = v.x;
    tile[r + i * 16][c4 + 1] = v.y;
    tile[r + i * 16][c4 + 2] = v.z;
    tile[r + i * 16][c4 + 3] = v.w;
  }
  __syncthreads();
#pragma unroll
  for (int i = 0; i < 2; ++i) {
    const int n = nl + i * 32;
    short8 oh, ol;
#pragma unroll
    for (int e = 0; e < 8; ++e) {
      const float x = tile[kc + e][n];
      oh[e] = f2bf(x);
      ol[e] = f2bf(x - bf2f(oh[e]));
    }
    *(short8*)(Bth + (size_t)(n0 + n) * K + k0 + kc) = oh;
    *(short8*)(Btl + (size_t)(n0 + n) * K + k0 + kc) = ol;
  }
}

// ---------------- flat f32 -> bf16 cast ----------------
__global__ void cast_bf(const float* __restrict__ in, short* __restrict__ out, int n) {
  const int i = blockIdx.x * 256 + threadIdx.x;
  if (i < n) out[i] = f2bf(in[i]);
}

// ---------------- RMSNorm (fp32 + bf16 hi [+ optional lo]) ----------------
__global__ __launch_bounds__(256) void rms_kernel(const float* __restrict__ in, int in_stride,
                                                  const float* __restrict__ w,
                                                  float* __restrict__ out,
                                                  short* __restrict__ out_bf,
                                                  short* __restrict__ out_lo, int C) {
  const int t = blockIdx.x, tid = threadIdx.x;
  const float* x = in + (size_t)t * in_stride;
  float ss = 0.f;
  for (int i = tid; i < C; i += 256) { float v = x[i]; ss = fmaf(v, v, ss); }
#pragma unroll
  for (int o = 32; o > 0; o >>= 1) ss += __shfl_xor(ss, o);
  __shared__ float red[4];
  if ((tid & 63) == 0) red[tid >> 6] = ss;
  __syncthreads();
  const float tot = red[0] + red[1] + red[2] + red[3];
  const float r = rsqrtf(tot / (float)C + 1e-6f);
  for (int i = tid; i < C; i += 256) {
    const float v = x[i] * r * w[i];
    out[(size_t)t * C + i] = v;
    const short h = f2bf(v);
    out_bf[(size_t)t * C + i] = h;
    if (out_lo) out_lo[(size_t)t * C + i] = f2bf(v - bf2f(h));
  }
}

// ---------------- LayerNorm in-place on (T,128) ----------------
__global__ __launch_bounds__(128) void ln_kernel(float* __restrict__ x,
                                                 const float* __restrict__ w,
                                                 const float* __restrict__ b) {
  const int t = blockIdx.x, i = threadIdx.x;
  float v = x[(size_t)t * 128 + i];
  float s = v;
#pragma unroll
  for (int o = 32; o > 0; o >>= 1) s += __shfl_xor(s, o);
  __shared__ float r1[2], r2[2];
  if ((i & 63) == 0) r1[i >> 6] = s;
  __syncthreads();
  const float m = (r1[0] + r1[1]) * (1.f / 128.f);
  const float dv = v - m;
  float sq = dv * dv;
#pragma unroll
  for (int o = 32; o > 0; o >>= 1) sq += __shfl_xor(sq, o);
  if ((i & 63) == 0) r2[i >> 6] = sq;
  __syncthreads();
  const float var = (r2[0] + r2[1]) * (1.f / 128.f);
  x[(size_t)t * 128 + i] = dv * rsqrtf(var + 1e-6f) * w[i] + b[i];
}

// ---------------- RoPE (interleaved pairs), fp32 ----------------
__global__ void rope_kernel(const float* __restrict__ src, int s_ts, int s_hs,
                            float* __restrict__ dst, int d_ts, int d_hs,
                            const int* __restrict__ pos) {
  const int t = blockIdx.x, h = blockIdx.y, i = threadIdx.x;
  const float* s = src + (size_t)t * s_ts + (size_t)h * s_hs;
  float* d = dst + (size_t)t * d_ts + (size_t)h * d_hs;
  const float x1 = s[2 * i], x2 = s[2 * i + 1];
  const float inv = powf(10000.f, -(float)i * (1.f / 32.f));
  const float ang = (float)pos[t] * inv;
  float sn, cs;
  sincosf(ang, &sn, &cs);
  d[2 * i]     = x1 * cs - x2 * sn;
  d[2 * i + 1] = x1 * sn + x2 * cs;
}

// ---------------- q rope + repack: qbuf[q][h][192] bf16 -> qh[h][q][192] ----------------
__global__ void q_rope_repack(const short* __restrict__ qbuf,
                              short* __restrict__ qhout,
                              const int* __restrict__ pos) {
  const int q = blockIdx.x, h = blockIdx.y;
  const int p = threadIdx.x;  // 96 pairs
  const short* s = qbuf + ((size_t)q * 32 + h) * 192;
  short* d = qhout + ((size_t)h * 1024 + q) * 192;
  float x1 = bf2f(s[2 * p]), x2 = bf2f(s[2 * p + 1]);
  if (p >= 64) {
    const int i = p - 64;
    const float inv = powf(10000.f, -(float)i * (1.f / 32.f));
    const float ang = (float)pos[q] * inv;
    float sn, cs;
    sincosf(ang, &sn, &cs);
    const float a = x1 * cs - x2 * sn, b = x1 * sn + x2 * cs;
    x1 = a; x2 = b;
  }
  d[2 * p]     = f2bf(x1);
  d[2 * p + 1] = f2bf(x2);
}

// ---------------- qi repack + split: qib[q][32][128] f32 -> qih_hi/lo [32][q][128] ----------------
__global__ __launch_bounds__(256) void qi_repack_split(const float* __restrict__ qib,
                                                       short* __restrict__ qhh,
                                                       short* __restrict__ qhl) {
  const int qt = blockIdx.x, h = blockIdx.y;
  const int tid = threadIdx.x;
#pragma unroll
  for (int i = 0; i < 8; ++i) {
    const int idx = tid + i * 256;           // 2048 float4 chunks
    const int q = idx >> 5, c = idx & 31;
    float4 v = *(const float4*)(qib + ((size_t)(qt * 64 + q) * 32 + h) * 128 + c * 4);
    float av[4] = {v.x, v.y, v.z, v.w};
    short4v hv, lv;
#pragma unroll
    for (int e = 0; e < 4; ++e) {
      hv[e] = f2bf(av[e]);
      lv[e] = f2bf(av[e] - bf2f(hv[e]));
    }
    const size_t off = ((size_t)h * 1024 + qt * 64 + q) * 128 + c * 4;
    *(short4v*)(qhh + off) = hv;
    *(short4v*)(qhl + off) = lv;
  }
}

// ---------------- kv repack ----------------
__global__ __launch_bounds__(256) void kv_repack(const short* __restrict__ kvb,
                                                 const short* __restrict__ kpe,
                                                 short* __restrict__ kfout,
                                                 short* __restrict__ vtout) {
  const int kt = blockIdx.x, h = blockIdx.y;
  const int tid = threadIdx.x;
  const int k0 = kt * 64;
  __shared__ short vtile[64][136];
#pragma unroll
  for (int i = 0; i < 6; ++i) {
    const int idx = tid + i * 256;           // 1536 chunks
    const int row = idx / 24, c = idx - row * 24;
    short8 v = (c < 16) ? *(const short8*)(kvb + ((size_t)(k0 + row) * 32 + h) * 256 + c * 8)
                        : *(const short8*)(kpe + (size_t)(k0 + row) * 64 + (c - 16) * 8);
    *(short8*)(kfout + ((size_t)h * 1024 + k0 + row) * 192 + c * 8) = v;
  }
#pragma unroll
  for (int i = 0; i < 4; ++i) {
    const int idx = tid + i * 256;           // 1024 chunks
    const int row = idx >> 4, c = idx & 15;
    *(short8*)&vtile[row][c * 8] =
        *(const short8*)(kvb + ((size_t)(k0 + row) * 32 + h) * 256 + 128 + c * 8);
  }
  __syncthreads();
#pragma unroll
  for (int i = 0; i < 4; ++i) {
    const int idx = tid + i * 256;           // 1024 chunks
    const int d = idx >> 3, kc = idx & 7;
    short8 o;
#pragma unroll
    for (int e = 0; e < 8; ++e) o[e] = vtile[kc * 8 + e][d];
    *(short8*)(vtout + ((size_t)h * 128 + d) * 1024 + k0 + kc * 8) = o;
  }
}

// ---------------- MFMA indexer logits (bf16x3, 8 heads per z, pre-split K) -----------
__global__ __launch_bounds__(256) void logits_mfma(const short* __restrict__ qih,
                                                   const short* __restrict__ qil,
                                                   const short* __restrict__ kih_g,
                                                   const short* __restrict__ kil_g,
                                                   const float* __restrict__ wts,
                                                   float* __restrict__ part) {
  const int bk = blockIdx.x, bq = blockIdx.y, g = blockIdx.z;
  if (bk > bq) return;
  __shared__ short kih[64 * 128], kil[64 * 128];
  __shared__ float swts[64][8];
  const int tid = threadIdx.x;
  const int lane = tid & 63, wv = tid >> 6;
  const int wr = (wv >> 1) * 32, wc = (wv & 1) * 32;
  const int l15 = lane & 15, l4 = lane >> 4;
  const int q0 = bq * 64, k0 = bk * 64;
  {
    const int r0 = tid >> 4;          // 0..15
    const int c8 = (tid & 15) * 8;    // 0..120
#pragma unroll
    for (int i = 0; i < 4; ++i) {
      const int row = r0 + i * 16;
      gl16(kih_g + (size_t)(k0 + row) * 128 + c8, &kih[(tid + i * 256) * 8]);
      gl16(kil_g + (size_t)(k0 + row) * 128 + c8, &kil[(tid + i * 256) * 8]);
    }
  }
#pragma unroll
  for (int i = 0; i < 2; ++i) {
    const int idx = tid + i * 256;  // 512 entries
    swts[idx >> 3][idx & 7] = wts[(size_t)(q0 + (idx >> 3)) * 32 + g * 8 + (idx & 7)];
  }
  __syncthreads();
  short8 kbh[2][4], kbl[2][4];
#pragma unroll
  for (int ct = 0; ct < 2; ++ct)
#pragma unroll
    for (int ks = 0; ks < 4; ++ks) {
      kbh[ct][ks] = *(const short8*)&kih[(wc + ct * 16 + l15) * 128 + ks * 32 + l4 * 8];
      kbl[ct][ks] = *(const short8*)&kil[(wc + ct * 16 + l15) * 128 + ks * 32 + l4 * 8];
    }
  f32x4 lacc[2][2];
#pragma unroll
  for (int i = 0; i < 2; ++i)
#pragma unroll
    for (int j = 0; j < 2; ++j) lacc[i][j] = f32x4{0.f, 0.f, 0.f, 0.f};
  for (int hh = 0; hh < 8; ++hh) {
    const int h = g * 8 + hh;
    short8 qah[2][4], qal[2][4];
#pragma unroll
    for (int rt = 0; rt < 2; ++rt)
#pragma unroll
      for (int ks = 0; ks < 4; ++ks) {
        const size_t off = ((size_t)h * 1024 + q0 + wr + rt * 16 + l15) * 128 + ks * 32 + l4 * 8;
        qah[rt][ks] = *(const short8*)(qih + off);
        qal[rt][ks] = *(const short8*)(qil + off);
      }
    f32x4 hacc[2][2];
#pragma unroll
    for (int i = 0; i < 2; ++i)
#pragma unroll
      for (int j = 0; j < 2; ++j) hacc[i][j] = f32x4{0.f, 0.f, 0.f, 0.f};
#pragma unroll
    for (int ks = 0; ks < 4; ++ks)
#pragma unroll
      for (int rt = 0; rt < 2; ++rt)
#pragma unroll
        for (int ct = 0; ct < 2; ++ct) {
          hacc[rt][ct] = __builtin_amdgcn_mfma_f32_16x16x32_bf16(qah[rt][ks], kbh[ct][ks], hacc[rt][ct], 0, 0, 0);
          hacc[rt][ct] = __builtin_amdgcn_mfma_f32_16x16x32_bf16(qah[rt][ks], kbl[ct][ks], hacc[rt][ct], 0, 0, 0);
          hacc[rt][ct] = __builtin_amdgcn_mfma_f32_16x16x32_bf16(qal[rt][ks], kbh[ct][ks], hacc[rt][ct], 0, 0, 0);
        }
#pragma unroll
    for (int rt = 0; rt < 2; ++rt)
#pragma unroll
      for (int ct = 0; ct < 2; ++ct)
#pragma unroll
        for (int r = 0; r < 4; ++r) {
          const int row = wr + rt * 16 + l4 * 4 + r;
          const float w = swts[row][hh] * kWtsScale;
          lacc[rt][ct][r] = fmaf(w, fmaxf(hacc[rt][ct][r], 0.f), lacc[rt][ct][r]);
        }
  }
#pragma unroll
  for (int rt = 0; rt < 2; ++rt)
#pragma unroll
    for (int ct = 0; ct < 2; ++ct)
#pragma unroll
      for (int r = 0; r < 4; ++r)
        part[(size_t)g * TT * TT + (size_t)(q0 + wr + rt * 16 + l4 * 4 + r) * TT +
             (k0 + wc + ct * 16 + l15)] = lacc[rt][ct][r];
}

// ---------------- top-512 -> bitmask ----------------
__global__ __launch_bounds__(256) void topk_mask(const float* __restrict__ part,
                                                 unsigned* __restrict__ maskbuf) {
  const int q = blockIdx.x, tid = threadIdx.x;
  __shared__ unsigned u[TT];
  __shared__ unsigned char sel[TT];
  __shared__ int redi[4];
  const size_t NN = (size_t)TT * TT;
  for (int k = tid; k < TT; k += 256) {
    unsigned uv = 0u;
    if (k <= q) {
      const size_t o = (size_t)q * TT + k;
      const float s = part[o] + part[NN + o] + part[2 * NN + o] + part[3 * NN + o];
      unsigned bb = __float_as_uint(s);
      uv = (bb & 0x80000000u) ? ~bb : (bb | 0x80000000u);
    }
    u[k] = uv;
    sel[k] = 0;
  }
  __syncthreads();
  const int n = q + 1;
  if (n <= TOPKK) {
    if (tid < 32) {
      const int base = tid * 32;
      unsigned word = 0u;
      if (base + 31 <= q) word = 0xffffffffu;
      else if (base <= q) word = 0xffffffffu >> (31 - (q - base));
      maskbuf[(size_t)q * 32 + tid] = word;
    }
    return;
  }
  unsigned lo = 1u, hi = 0xFFFFFFFFu;
  while (lo < hi) {
    const unsigned mid = lo + ((hi - lo) >> 1) + ((hi - lo) & 1u);
    int c = 0;
    for (int k = tid; k < TT; k += 256) c += (u[k] >= mid) ? 1 : 0;
#pragma unroll
    for (int o = 32; o > 0; o >>= 1) c += __shfl_down(c, o);
    if ((tid & 63) == 0) redi[tid >> 6] = c;
    __syncthreads();
    const int ctot = redi[0] + redi[1] + redi[2] + redi[3];
    __syncthreads();
    if (ctot >= TOPKK) lo = mid; else hi = mid - 1u;
  }
  const unsigned ustar = lo;
  int c = 0;
  for (int k = tid; k < TT; k += 256) c += (u[k] > ustar) ? 1 : 0;
#pragma unroll
  for (int o = 32; o > 0; o >>= 1) c += __shfl_down(c, o);
  if ((tid & 63) == 0) redi[tid >> 6] = c;
  __syncthreads();
  const int nGreater = redi[0] + redi[1] + redi[2] + redi[3];
  for (int k = tid; k < TT; k += 256) sel[k] = (u[k] > ustar) ? 1 : 0;
  __syncthreads();
  if (tid == 0) {
    int need = TOPKK - nGreater;
    for (int k = 0; k <= q && need > 0; ++k)
      if (u[k] == ustar) { sel[k] = 1; --need; }
  }
  __syncthreads();
  if (tid < 32) {
    unsigned word = 0u;
#pragma unroll
    for (int b = 0; b < 32; ++b) word |= ((unsigned)sel[tid * 32 + b]) << b;
    maskbuf[(size_t)q * 32 + tid] = word;
  }
}

// ---------------- masked dense MFMA attention ----------------
__global__ __launch_bounds__(256) void attn_mfma(const short* __restrict__ qh,
                                                 const short* __restrict__ kf,
                                                 const short* __restrict__ vt,
                                                 const unsigned* __restrict__ maskbuf,
                                                 short* __restrict__ ao) {
  const int h = blockIdx.x;
  const int yy = blockIdx.y;
  const int qt = (yy < 8) ? (yy * 2) : (31 - yy * 2);  // pair light+heavy tiles per CU
  const int tid = threadIdx.x;
  const int lane = tid & 63, w = tid >> 6;
  const int l15 = lane & 15, l4 = lane >> 4;
  const int q0 = qt * 64;
  __shared__ short kfs[64 * 200];
  __shared__ short vts[128 * 72];
  __shared__ short ps[4][16][72];
  __shared__ unsigned m32s[64][2];
  short8 qf[6];
#pragma unroll
  for (int ks = 0; ks < 6; ++ks)
    qf[ks] = *(const short8*)(qh + ((size_t)h * 1024 + q0 + w * 16 + l15) * 192 + ks * 32 + l4 * 8);
  f32x4 of[8];
#pragma unroll
  for (int dt = 0; dt < 8; ++dt) of[dt] = f32x4{0.f, 0.f, 0.f, 0.f};
  float m[4], l[4];
#pragma unroll
  for (int r = 0; r < 4; ++r) { m[r] = -INFINITY; l[r] = 0.f; }

  for (int kt = 0; kt <= qt; ++kt) {
    const int k0 = kt * 64;
    __syncthreads();
#pragma unroll
    for (int i = 0; i < 6; ++i) {
      const int idx = tid + i * 256;
      const int row = idx / 24, c = idx - row * 24;
      *(short8*)&kfs[row * 200 + c * 8] =
          *(const short8*)(kf + ((size_t)h * 1024 + k0 + row) * 192 + c * 8);
    }
#pragma unroll
    for (int i = 0; i < 4; ++i) {
      const int idx = tid + i * 256;
      const int row = idx >> 3, c = idx & 7;
      *(short8*)&vts[row * 72 + c * 8] =
          *(const short8*)(vt + ((size_t)h * 128 + row) * 1024 + k0 + c * 8);
    }
    if (tid < 128)
      m32s[tid >> 1][tid & 1] = maskbuf[(size_t)(q0 + (tid >> 1)) * 32 + (k0 >> 5) + (tid & 1)];
    __syncthreads();
    // QK^T
    f32x4 sacc[4];
#pragma unroll
    for (int j = 0; j < 4; ++j) sacc[j] = f32x4{0.f, 0.f, 0.f, 0.f};
#pragma unroll
    for (int ks = 0; ks < 6; ++ks)
#pragma unroll
      for (int j = 0; j < 4; ++j) {
        short8 kb = *(const short8*)&kfs[(j * 16 + l15) * 200 + ks * 32 + l4 * 8];
        sacc[j] = __builtin_amdgcn_mfma_f32_16x16x32_bf16(qf[ks], kb, sacc[j], 0, 0, 0);
      }
    // scale + mask
    float tmax[4] = {-INFINITY, -INFINITY, -INFINITY, -INFINITY};
#pragma unroll
    for (int j = 0; j < 4; ++j)
#pragma unroll
      for (int r = 0; r < 4; ++r) {
        const int kcol = j * 16 + l15;
        const unsigned um = m32s[w * 16 + l4 * 4 + r][kcol >> 5];
        float s = sacc[j][r] * kScaling;
        s = ((um >> (kcol & 31)) & 1u) ? s : -INFINITY;
        sacc[j][r] = s;
        tmax[r] = fmaxf(tmax[r], s);
      }
#pragma unroll
    for (int r = 0; r < 4; ++r) {
      tmax[r] = fmaxf(tmax[r], __shfl_xor(tmax[r], 1));
      tmax[r] = fmaxf(tmax[r], __shfl_xor(tmax[r], 2));
      tmax[r] = fmaxf(tmax[r], __shfl_xor(tmax[r], 4));
      tmax[r] = fmaxf(tmax[r], __shfl_xor(tmax[r], 8));
    }
    float f[4];
#pragma unroll
    for (int r = 0; r < 4; ++r) {
      const float mn = fmaxf(m[r], tmax[r]);
      f[r] = __expf(fmaxf(m[r], -1e30f) - fmaxf(mn, -1e30f));
      m[r] = mn;
      l[r] *= f[r];
    }
    float psum[4] = {0.f, 0.f, 0.f, 0.f};
#pragma unroll
    for (int j = 0; j < 4; ++j)
#pragma unroll
      for (int r = 0; r < 4; ++r) {
        const float p = __expf(sacc[j][r] - fmaxf(m[r], -1e30f));
        psum[r] += p;
        ps[w][l4 * 4 + r][j * 16 + l15] = f2bf(p);
      }
#pragma unroll
    for (int r = 0; r < 4; ++r) {
      psum[r] += __shfl_xor(psum[r], 1);
      psum[r] += __shfl_xor(psum[r], 2);
      psum[r] += __shfl_xor(psum[r], 4);
      psum[r] += __shfl_xor(psum[r], 8);
      l[r] += psum[r];
    }
#pragma unroll
    for (int dt = 0; dt < 8; ++dt)
#pragma unroll
      for (int r = 0; r < 4; ++r) of[dt][r] *= f[r];
    // PV
    short8 pa0 = *(const short8*)&ps[w][l15][l4 * 8];
    short8 pa1 = *(const short8*)&ps[w][l15][32 + l4 * 8];
#pragma unroll
    for (int dt = 0; dt < 8; ++dt) {
      short8 vb0 = *(const short8*)&vts[(dt * 16 + l15) * 72 + l4 * 8];
      short8 vb1 = *(const short8*)&vts[(dt * 16 + l15) * 72 + 32 + l4 * 8];
      of[dt] = __builtin_amdgcn_mfma_f32_16x16x32_bf16(pa0, vb0, of[dt], 0, 0, 0);
      of[dt] = __builtin_amdgcn_mfma_f32_16x16x32_bf16(pa1, vb1, of[dt], 0, 0, 0);
    }
  }
  // epilogue
#pragma unroll
  for (int r = 0; r < 4; ++r) {
    const float invl = 1.f / l[r];
#pragma unroll
    for (int dt = 0; dt < 8; ++dt)
      ao[(size_t)(q0 + w * 16 + l4 * 4 + r) * 4096 + h * 128 + dt * 16 + l15] =
          f2bf(of[dt][r] * invl);
  }
}

// ============================================================================
extern "C" void kernel_launch(void* const* d_in, const int* in_sizes, int n_in,
                              void* d_out, int out_size, void* d_ws, size_t ws_size,
                              hipStream_t stream) {
  const float* hidden     = (const float*)d_in[0];
  const int*   positions  = (const int*)d_in[1];
  const float* w_qkv_a    = (const float*)d_in[2];
  const float* q_a_ln_w   = (const float*)d_in[3];
  const float* w_q_b      = (const float*)d_in[4];
  const float* kv_a_ln_w  = (const float*)d_in[5];
  const float* w_kv_b     = (const float*)d_in[6];
  const float* w_o        = (const float*)d_in[7];
  const float* w_idx_qb   = (const float*)d_in[8];
  const float* w_idx_k    = (const float*)d_in[9];
  const float* idx_k_ln_w = (const float*)d_in[10];
  const float* idx_k_ln_b = (const float*)d_in[11];
  const float* w_idx_w    = (const float*)d_in[12];
  float* out = (float*)d_out;

  float* ws = (float*)d_ws;
  size_t off = 0;
  auto take = [&](size_t n) { float* p = ws + off; off += n; return p; };
  float* qkv     = take((size_t)TT * QKVN);
  float* qcn     = take((size_t)TT * QLL);
  short* qcn_bf  = (short*)take((size_t)TT * QLL / 2);
  short* qcn_lo  = (short*)take((size_t)TT * QLL / 2);
  float* kvn     = take((size_t)TT * KLL);
  short* kvn_bf  = (short*)take((size_t)TT * KLL / 2);
  short* qbuf    = (short*)take((size_t)TT * NHH * 192 / 2);   // bf16 [q][h][192]
  short* kvbuf   = (short*)take((size_t)TT * NHH * 256 / 2);   // bf16 [k][h][256]
  float* kpe     = take((size_t)TT * 64);
  short* kpe_bf  = (short*)take((size_t)TT * 32);
  float* qib     = take((size_t)TT * INHH * IHDD);             // fp32 [q][32][128]
  float* kib     = take((size_t)TT * IHDD);
  float* wtsb    = take((size_t)TT * INHH);
  short* kih_g   = (short*)take((size_t)TT * IHDD / 2);        // pre-split ki hi
  short* kil_g   = (short*)take((size_t)TT * IHDD / 2);        // pre-split ki lo
  short* qhb     = (short*)take((size_t)NHH * TT * 192 / 2);   // bf16 [h][q][192]
  short* qih_h   = (short*)take((size_t)INHH * TT * 128 / 2);
  short* qih_l   = (short*)take((size_t)INHH * TT * 128 / 2);
  short* kfb     = (short*)take((size_t)NHH * TT * 192 / 2);   // bf16 [h][k][192]
  short* vtb     = (short*)take((size_t)NHH * 128 * TT / 2);   // bf16 [h][d][k]
  float* part4   = take((size_t)4 * TT * TT);
  unsigned* maskbuf = (unsigned*)take((size_t)TT * 32);
  short* hid_h   = (short*)take((size_t)TT * HH / 2);
  short* hid_l   = (short*)take((size_t)TT * HH / 2);
  short* wqkva_h = (short*)take((size_t)QKVNP * HH / 2);       // padded rows
  short* wqkva_l = (short*)take((size_t)QKVNP * HH / 2);
  short* widxqb_h = (short*)take((size_t)HH * QLL / 2);
  short* widxqb_l = (short*)take((size_t)HH * QLL / 2);
  short* wqb_t   = (short*)take((size_t)6144 * QLL / 2);
  short* wkvb_t  = (short*)take((size_t)8192 * KLL / 2);
  short* ao   = (short*)part4;      // alias: part4 dead after topk
  short* wo_t = wqkva_h;            // alias: wqkva h+l dead after qkv_a gemm
  float* skpart = part4;            // alias: SKS*1024*160 = 2.62M < 4M (part4 not yet live)
  float* qkvpart = (float*)qbuf;    // alias: 2*1024*2176 = 4.45M < qbuf..qib span
  float* idxpart = (float*)qhb;     // alias: 2*1024*4096 = 8.4M < qhb..kfb span

  const dim3 blk(256);
  // fused skinny projections (kib | wtsb) via split-K
  skinny_splitk<<<dim3(16, SKS), blk, 0, stream>>>(hidden, w_idx_k, w_idx_w, skpart);
  skinny_reduce<<<dim3(TT * 160 / 256), blk, 0, stream>>>(skpart, kib, wtsb);
  // input/weight splits
  split_cast<<<dim3(TT * HH / 4 / 256), blk, 0, stream>>>(hidden, hid_h, hid_l, TT * HH / 4);
  transpose_split_cast<<<dim3(QKVNP / 64, HH / 64), blk, 0, stream>>>(w_qkv_a, wqkva_h, wqkva_l, HH, QKVN);
  transpose_split_cast<<<dim3(HH / 64, QLL / 64), blk, 0, stream>>>(w_idx_qb, widxqb_h, widxqb_l, QLL, HH);
  transpose_cast<<<dim3(6144 / 64, QLL / 64), blk, 0, stream>>>(w_q_b, wqb_t, QLL, 6144);
  transpose_cast<<<dim3(8192 / 64, KLL / 64), blk, 0, stream>>>(w_kv_b, wkvb_t, KLL, 8192);
  // qkv_a: bf16x3 split-K z=2 (topk-critical precision)
  gemm3<<<dim3(QKVNP / 128, 8, 2), blk, 0, stream>>>(hid_h, hid_l, wqkva_h, wqkva_l,
                                                     qkvpart, TT, QKVNP, HH, HH / 2);
  reduce_splitk<<<dim3((QKVN + 255) / 256, TT), blk, 0, stream>>>(qkvpart, qkv, TT, QKVNP, QKVN, 2);
  // w_o transpose AFTER qkv_a gemm (aliases wqkva)
  transpose_cast<<<dim3(HH / 64, HH / 64), blk, 0, stream>>>(w_o, wo_t, HH, HH);
  // norms (qcn also emits lo split for idx_qb's A operand)
  rms_kernel<<<TT, 256, 0, stream>>>(qkv, QKVN, q_a_ln_w, qcn, qcn_bf, qcn_lo, QLL);
  rms_kernel<<<TT, 256, 0, stream>>>(qkv + 1536, QKVN, kv_a_ln_w, kvn, kvn_bf, nullptr, KLL);
  // idx_qb: bf16x3 split-K z=2 (scratch aliases qhb region, written later)
  gemm3<<<dim3(HH / 128, 8, 2), blk, 0, stream>>>(qcn_bf, qcn_lo, widxqb_h, widxqb_l,
                                                  idxpart, TT, HH, QLL, QLL / 2);
  reduce_splitk<<<dim3(HH / 256, TT), blk, 0, stream>>>(idxpart, qib, TT, HH, HH, 2);
  // smooth projections (write qbuf/kvbuf; qkvpart dead)
  gemm_bf16<__hip_bfloat16><<<dim3(48, 8), blk, 0, stream>>>(qcn_bf, wqb_t, (__hip_bfloat16*)qbuf, TT, 6144, QLL);
  gemm_bf16<__hip_bfloat16><<<dim3(64, 8), blk, 0, stream>>>(kvn_bf, wkvb_t, (__hip_bfloat16*)kvbuf, TT, 8192, KLL);
  // layernorm + RoPE
  ln_kernel<<<TT, 128, 0, stream>>>(kib, idx_k_ln_w, idx_k_ln_b);
  rope_kernel<<<dim3(TT, INHH), 32, 0, stream>>>(qib, INHH * IHDD, IHDD, qib, INHH * IHDD, IHDD, positions);
  rope_kernel<<<dim3(TT, 1), 32, 0, stream>>>(qkv + 2048, QKVN, 0, kpe, 64, 0, positions);
  rope_kernel<<<dim3(TT, 1), 32, 0, stream>>>(kib, IHDD, 0, kib, IHDD, 0, positions);
  cast_bf<<<dim3(TT * 64 / 256), blk, 0, stream>>>(kpe, kpe_bf, TT * 64);
  split_cast<<<dim3(TT * IHDD / 4 / 256), blk, 0, stream>>>(kib, kih_g, kil_g, TT * IHDD / 4);
  // repacks (qhb written here; idxpart dead)
  q_rope_repack<<<dim3(TT, NHH), 96, 0, stream>>>(qbuf, qhb, positions);
  qi_repack_split<<<dim3(16, INHH), blk, 0, stream>>>(qib, qih_h, qih_l);
  kv_repack<<<dim3(16, NHH), blk, 0, stream>>>(kvbuf, kpe_bf, kfb, vtb);
  // indexer logits (MFMA bf16x3; fp8-quant cancels: relu(x/s)*(w*s)==relu(x)*w)
  logits_mfma<<<dim3(16, 16, 4), blk, 0, stream>>>(qih_h, qih_l, kih_g, kil_g, wtsb, part4);
  // top-512 -> bitmask
  topk_mask<<<dim3(TT), blk, 0, stream>>>(part4, maskbuf);
  // masked dense MFMA attention
  attn_mfma<<<dim3(NHH, 16), blk, 0, stream>>>(qhb, kfb, vtb, maskbuf, ao);
  // output projection
  gemm_bf16<float><<<dim3(32, 8), blk, 0, stream>>>(ao, wo_t, out, TT, HH, NHH * DVV);
}